// Round 7
// baseline (725.699 us; speedup 1.0000x reference)
//
#include <hip/hip_runtime.h>
#include <hip/hip_bf16.h>

#define DEV static __device__ __forceinline__

DEV float sigm(float x) { return 1.f / (1.f + __expf(-x)); }

typedef __attribute__((ext_vector_type(8))) short s8;   // 8 bf16 (4 VGPRs)
typedef __attribute__((ext_vector_type(4))) float f4;   // 4 fp32 acc

DEV unsigned short f2bf(float f) {  // RNE float->bf16 bits (finite inputs)
  unsigned u = __float_as_uint(f);
  return (unsigned short)((u + 0x7FFFu + ((u >> 16) & 1u)) >> 16);
}
DEV float bf2f(unsigned short h) { return __uint_as_float(((unsigned)h) << 16); }

// Edge tables from ADJ nonzeros: (src, dst) pairs in np.nonzero order
__constant__ int d_esrc[10] = {0,1,1,1,2,2,3,4,4,5};
__constant__ int d_inc[6][3] = {{1,-1,-1},{0,4,7},{2,6,-1},{5,-1,-1},{3,9,-1},{8,-1,-1}};
__constant__ int d_ne[6] = {1,3,2,1,2,1};

// Deformable tile geometry: 32x8 px, halo 4 -> 16 x 40 data, stride 41.
#define TW 32
#define TH 8
#define SW 41
#define SDC 40
#define SH 16
#define SN 656

// ---------------------------------------------------------------------------
// Pair-interleaved weight prep: channel pairs adjacent for float2 MLP.
//   src: [e][OC][C][3][3]
//   chan_major=1: [e][C/2][9][2*OC]    (offconv2 window weights)
//   chan_major=0: [e][9][C/2][2*OC]    (dfconv main einsum weights)
// ---------------------------------------------------------------------------
__global__ void prep_wp(const float* __restrict__ src, float* __restrict__ dst,
                        int OC, int C, int chan_major, int total) {
  int i = blockIdx.x * 256 + threadIdx.x;
  if (i >= total) return;
  int t = i % 9; int n = i / 9;
  int c = n % C; n /= C;
  int oc = n % OC; int e = n / OC;
  int cg = c >> 1, par = c & 1;
  int idx;
  if (chan_major)
    idx = ((e * (C / 2) + cg) * 9 + t) * (2 * OC) + 2 * oc + par;
  else
    idx = ((e * 9 + t) * (C / 2) + cg) * (2 * OC) + 2 * oc + par;
  dst[idx] = src[i];
}

// ---------------------------------------------------------------------------
// A-fragment prep for offconv1 MFMA: W1[e][27][266][9] -> bf16 hi/lo frags.
// ---------------------------------------------------------------------------
__global__ void aprep1_k(const float* __restrict__ ow1,
                         unsigned short* __restrict__ dst) {
  int i = blockIdx.x * 256 + threadIdx.x;     // 10*133*2*64 = 170240
  int lane = i & 63;
  int tile = (i >> 6) & 1;
  int cg = (i >> 7) % 133;
  int e = (i >> 7) / 133;
  int m = lane & 15, quad = lane >> 4;
  int oc = tile * 16 + m;
  unsigned short* out = dst + ((e * 133 + cg) * 2 + tile) * 1024 + lane * 16;
#pragma unroll
  for (int j = 0; j < 8; ++j) {
    int k = quad * 8 + j;
    int csel = k >> 4, t = k & 15;
    int c = 2 * cg + csel;
    float w = (oc < 27 && t < 9) ? ow1[((e * 27 + oc) * 266 + c) * 9 + t] : 0.f;
    unsigned short h = f2bf(w);
    float fl = w - bf2f(h);
    out[j] = h;
    out[8 + j] = f2bf(fl);
  }
}

// o1 = bias broadcast; h1a = 0.
__global__ void init_k(const float* __restrict__ ob, float* __restrict__ o1,
                       float* __restrict__ h1a) {
  int i = blockIdx.x * 256 + threadIdx.x;
  if (i < 2488320) o1[i] = ob[i / 9216];
  else h1a[i - 2488320] = 0.f;
}

// o2 = bias broadcast; h2 = 0.
__global__ void init2_k(const float* __restrict__ ob, float* __restrict__ o2,
                        float* __restrict__ h2) {
  int i = blockIdx.x * 256 + threadIdx.x;
  if (i < 2488320) o2[i] = ob[i / 9216];
  else h2[i - 2488320] = 0.f;
}

// Staging address for deformable halo-4 window (clamped), element i of 16x41.
DEV int stage_goff(int i, int ty0, int tx0) {
  int r = i / SW, cl = i % SW;
  cl = min(cl, SDC - 1);
  int gy = min(max(ty0 - 4 + r, 0), 95);
  int gx = min(max(tx0 - 4 + cl, 0), 95);
  return gy * 96 + gx;
}

// ---------------------------------------------------------------------------
// Offset conv 1 via MFMA (unchanged from r6). grid (10, 36, 4).
// ---------------------------------------------------------------------------
#define OSWB 35
#define OSEC 384
#define OBUF 896

__global__ __launch_bounds__(256) void offconv1_mfma_k(
    const float* __restrict__ pfea, const float* __restrict__ xp,
    const unsigned short* __restrict__ aw, float* __restrict__ o1) {
  __shared__ float sbuf[2][OBUF];
  const int e = blockIdx.x, m = blockIdx.y, z = blockIdx.z;
  const int tid = threadIdx.x;
  const int lane = tid & 63, wv = tid >> 6;
  const int quad = lane >> 4, n16 = lane & 15;
  const int tx0 = (m % 3) * 32, ty0 = (m / 3) * 8;
  const float* xpe = xp + d_esrc[e] * 10 * 9216;
  const int cg_lo = (z * 133) / 4, cg_hi = ((z + 1) * 133) / 4;

  int g[3]; bool oks[3];
#pragma unroll
  for (int i = 0; i < 3; ++i) {
    int s = tid + i * 256;
    int sec = s / OSEC, off = s - sec * OSEC;
    int r = off / OSWB, cl = off % OSWB;
    int gy = ty0 - 1 + r, gx = tx0 - 1 + cl;
    bool ok = (off < 350) && (cl < 34) && (gy >= 0) && (gy < 96) &&
              (gx >= 0) && (gx < 96);
    oks[i] = ok;
    g[i] = sec * 9216 + (ok ? (gy * 96 + gx) : 0);
  }
  if (tid < OBUF - 768) { sbuf[0][768 + tid] = 0.f; sbuf[1][768 + tid] = 0.f; }

  const int tbase = (quad & 1) * 8;
  const int csel = quad >> 1;
  int bdelta[8];
#pragma unroll
  for (int j = 0; j < 8; ++j) {
    int t = tbase + j;
    int dy = t / 3 - 1, dx = t % 3 - 1;
    bdelta[j] = csel * OSEC + dy * OSWB + dx;
  }
  int bidx[4];
#pragma unroll
  for (int nt = 0; nt < 4; ++nt) {
    int r = 2 * wv + (nt >> 1), h = nt & 1;
    bidx[nt] = (r + 1) * OSWB + (h * 16 + n16 + 1);
  }

  f4 acc[4][2] = {};

  int c0 = 2 * cg_lo;
  const float* base = (c0 < 256) ? (pfea + c0 * 9216) : (xpe + (c0 - 256) * 9216);
  float pv0 = oks[0] ? base[g[0]] : 0.f;
  float pv1 = oks[1] ? base[g[1]] : 0.f;
  float pv2 = oks[2] ? base[g[2]] : 0.f;

  int bsel = 0;
  for (int cg = cg_lo; cg < cg_hi; ++cg, bsel ^= 1) {
    float* buf = sbuf[bsel];
    buf[tid] = pv0; buf[tid + 256] = pv1; buf[tid + 512] = pv2;
    if (cg + 1 < cg_hi) {
      int c0n = 2 * (cg + 1);
      const float* nb = (c0n < 256) ? (pfea + c0n * 9216)
                                    : (xpe + (c0n - 256) * 9216);
      pv0 = oks[0] ? nb[g[0]] : 0.f;
      pv1 = oks[1] ? nb[g[1]] : 0.f;
      pv2 = oks[2] ? nb[g[2]] : 0.f;
    }
    const unsigned short* apc = aw + (e * 133 + cg) * 2048 + lane * 16;
    s8 Ah0 = *(const s8*)(apc);
    s8 Al0 = *(const s8*)(apc + 8);
    s8 Ah1 = *(const s8*)(apc + 1024);
    s8 Al1 = *(const s8*)(apc + 1024 + 8);
    __syncthreads();
#pragma unroll
    for (int nt = 0; nt < 4; ++nt) {
      union { s8 v; unsigned short u[8]; } Bh, Bl;
#pragma unroll
      for (int j = 0; j < 8; ++j) {
        float v = buf[bidx[nt] + bdelta[j]];
        unsigned short h = f2bf(v);
        Bh.u[j] = h;
        Bl.u[j] = f2bf(v - bf2f(h));
      }
      acc[nt][0] = __builtin_amdgcn_mfma_f32_16x16x32_bf16(Ah0, Bh.v, acc[nt][0], 0, 0, 0);
      acc[nt][0] = __builtin_amdgcn_mfma_f32_16x16x32_bf16(Ah0, Bl.v, acc[nt][0], 0, 0, 0);
      acc[nt][0] = __builtin_amdgcn_mfma_f32_16x16x32_bf16(Al0, Bh.v, acc[nt][0], 0, 0, 0);
      acc[nt][1] = __builtin_amdgcn_mfma_f32_16x16x32_bf16(Ah1, Bh.v, acc[nt][1], 0, 0, 0);
      acc[nt][1] = __builtin_amdgcn_mfma_f32_16x16x32_bf16(Ah1, Bl.v, acc[nt][1], 0, 0, 0);
      acc[nt][1] = __builtin_amdgcn_mfma_f32_16x16x32_bf16(Al1, Bh.v, acc[nt][1], 0, 0, 0);
    }
  }
#pragma unroll
  for (int nt = 0; nt < 4; ++nt) {
    int y = ty0 + 2 * wv + (nt >> 1);
    int xx = tx0 + (nt & 1) * 16 + n16;
    int p = y * 96 + xx;
#pragma unroll
    for (int t2 = 0; t2 < 2; ++t2)
#pragma unroll
      for (int r = 0; r < 4; ++r) {
        int oc = t2 * 16 + quad * 4 + r;
        if (oc < 27)
          atomicAdd(&o1[(e * 27 + oc) * 9216 + p], acc[nt][t2][r]);
      }
  }
}

// ---------------------------------------------------------------------------
// Deformable main conv 1: float2 channel-pair LDS staging (ds_read_b64
// bilinear corners), pair-interleaved weights. split z=8 by pairs, atomic.
// grid (10, 36, 8)
// ---------------------------------------------------------------------------
#define IMG1(c) (((c) < 256) ? (pfea + (c) * 9216) : (xpe + ((c) - 256) * 9216))

__global__ __launch_bounds__(256) void dfmain1_k(
    const float* __restrict__ pfea, const float* __restrict__ xp,
    const float* __restrict__ o1, const float* __restrict__ wm,
    float* __restrict__ hacc) {
  __shared__ float2 sbuf[2][SN];
  const int e = blockIdx.x, m = blockIdx.y, z = blockIdx.z;
  const int tid = threadIdx.x;
  const int tx = tid % TW, ty = tid / TW;
  const int tx0 = (m % 3) * TW, ty0 = (m / 3) * TH;
  const int y = ty0 + ty, x = tx0 + tx;
  const int p = y * 96 + x;
  const float* xpe = xp + d_esrc[e] * 10 * 9216;
  const int cg_lo = (z * 133) / 8, cg_hi = ((z + 1) * 133) / 8;

  const int g0 = stage_goff(tid, ty0, tx0);
  const int g1 = stage_goff(tid + 256, ty0, tx0);
  const int g2 = (tid < SN - 512) ? stage_goff(tid + 512, ty0, tx0) : 0;

  int iob[9]; float cw[9][4];
  bool oob = false;
#pragma unroll
  for (int k = 0; k < 9; ++k) {
    float offy = o1[(e * 27 + 2 * k) * 9216 + p];
    float offx = o1[(e * 27 + 2 * k + 1) * 9216 + p];
    float mk = sigm(o1[(e * 27 + 18 + k) * 9216 + p]);
    float py = (float)(y + k / 3 - 1) + offy;
    float px = (float)(x + k % 3 - 1) + offx;
    float fy = floorf(py), fx = floorf(px);
    float wy = py - fy, wx = px - fx;
    int iy = (int)fy, ix = (int)fx;
#pragma unroll
    for (int dy = 0; dy < 2; ++dy)
#pragma unroll
      for (int dx = 0; dx < 2; ++dx) {
        bool ok = (iy + dy >= 0) && (iy + dy < 96) && (ix + dx >= 0) && (ix + dx < 96);
        cw[k][dy * 2 + dx] =
            (ok ? mk : 0.f) * (dy ? wy : (1.f - wy)) * (dx ? wx : (1.f - wx));
      }
    int ir = iy - (ty0 - 4), ic = ix - (tx0 - 4);
    oob |= ((unsigned)ir > (unsigned)(SH - 2)) | ((unsigned)ic > (unsigned)(SDC - 2));
    iob[k] = min(max(ir, 0), SH - 2) * SW + min(max(ic, 0), SDC - 2);
  }

  float acc[20];
#pragma unroll
  for (int oc = 0; oc < 20; ++oc) acc[oc] = 0.f;

  const float* iaA = IMG1(2 * cg_lo);
  const float* iaB = IMG1(2 * cg_lo + 1);
  float2 pv0 = make_float2(iaA[g0], iaB[g0]);
  float2 pv1 = make_float2(iaA[g1], iaB[g1]);
  float2 pv2 = (tid < SN - 512) ? make_float2(iaA[g2], iaB[g2])
                                : make_float2(0.f, 0.f);

  int bsel = 0;
  for (int cg = cg_lo; cg < cg_hi; ++cg, bsel ^= 1) {
    float2* buf = sbuf[bsel];
    buf[tid] = pv0; buf[tid + 256] = pv1;
    if (tid < SN - 512) buf[tid + 512] = pv2;
    if (cg + 1 < cg_hi) {
      const float* naA = IMG1(2 * cg + 2);
      const float* naB = IMG1(2 * cg + 3);
      pv0 = make_float2(naA[g0], naB[g0]);
      pv1 = make_float2(naA[g1], naB[g1]);
      if (tid < SN - 512) pv2 = make_float2(naA[g2], naB[g2]);
    }
    __syncthreads();
#pragma unroll
    for (int k = 0; k < 9; ++k) {
      const float2* bk = buf + iob[k];
      float2 b00 = bk[0], b01 = bk[1], b10 = bk[SW], b11 = bk[SW + 1];
      float sx = cw[k][0] * b00.x + cw[k][1] * b01.x +
                 cw[k][2] * b10.x + cw[k][3] * b11.x;
      float sy = cw[k][0] * b00.y + cw[k][1] * b01.y +
                 cw[k][2] * b10.y + cw[k][3] * b11.y;
      const float* wc = wm + ((e * 9 + k) * 133 + cg) * 40;  // pair-interleaved
#pragma unroll
      for (int oc = 0; oc < 20; ++oc)
        acc[oc] = fmaf(sx, wc[2 * oc], fmaf(sy, wc[2 * oc + 1], acc[oc]));
    }
  }

  // Per-lane slow path: offsets escaped the halo.
  if (oob) {
#pragma unroll
    for (int oc = 0; oc < 20; ++oc) acc[oc] = 0.f;
    for (int k = 0; k < 9; ++k) {
      float offy = o1[(e * 27 + 2 * k) * 9216 + p];
      float offx = o1[(e * 27 + 2 * k + 1) * 9216 + p];
      float mk = sigm(o1[(e * 27 + 18 + k) * 9216 + p]);
      float py = (float)(y + k / 3 - 1) + offy;
      float px = (float)(x + k % 3 - 1) + offx;
      float fy = floorf(py), fx = floorf(px);
      float wy = py - fy, wx = px - fx;
      int iy = (int)fy, ix = (int)fx;
      int go[4]; float gw[4];
#pragma unroll
      for (int dy = 0; dy < 2; ++dy)
#pragma unroll
        for (int dx = 0; dx < 2; ++dx) {
          bool ok = (iy + dy >= 0) && (iy + dy < 96) && (ix + dx >= 0) && (ix + dx < 96);
          int yc = min(max(iy + dy, 0), 95), xc = min(max(ix + dx, 0), 95);
          go[dy * 2 + dx] = yc * 96 + xc;
          gw[dy * 2 + dx] =
              (ok ? mk : 0.f) * (dy ? wy : (1.f - wy)) * (dx ? wx : (1.f - wx));
        }
      for (int c = 2 * cg_lo; c < 2 * cg_hi; ++c) {
        const float* ptr = IMG1(c);
        float sv = gw[0] * ptr[go[0]] + gw[1] * ptr[go[1]] +
                   gw[2] * ptr[go[2]] + gw[3] * ptr[go[3]];
        const float* wc = wm + ((e * 9 + k) * 133 + (c >> 1)) * 40 + (c & 1);
#pragma unroll
        for (int oc = 0; oc < 20; ++oc)
          acc[oc] = fmaf(sv, wc[2 * oc], acc[oc]);
      }
    }
  }
#pragma unroll
  for (int oc = 0; oc < 20; ++oc)
    atomicAdd(&hacc[(e * 20 + oc) * 9216 + p], acc[oc]);
}

// ---------------------------------------------------------------------------
// Offset conv 2: float2 pair staging with fused affine+relu; pair weights.
// split z=2 (10 ch = 5 pairs each), atomic into bias-inited o2. grid (10,36,2)
// ---------------------------------------------------------------------------
__global__ __launch_bounds__(256) void offconv2_k(
    const float* __restrict__ h1a, const float* __restrict__ wf,
    const float* __restrict__ s1, const float* __restrict__ b1,
    float* __restrict__ o2) {
  __shared__ float2 sbuf[2][SN];
  const int e = blockIdx.x, m = blockIdx.y;
  const int cg_lo = blockIdx.z * 5;
  const int tid = threadIdx.x;
  const int tx = tid % TW, ty = tid / TW;
  const int tx0 = (m % 3) * TW, ty0 = (m / 3) * TH;
  const int y = ty0 + ty, x = tx0 + tx;
  const int p = y * 96 + x;
  const float* base = h1a + e * 20 * 9216;

  const int g0 = stage_goff(tid, ty0, tx0);
  const int g1 = stage_goff(tid + 256, ty0, tx0);
  const int g2 = (tid < SN - 512) ? stage_goff(tid + 512, ty0, tx0) : 0;

  float vmask[9];
#pragma unroll
  for (int t = 0; t < 9; ++t) {
    int yy = y + t / 3 - 1, xx = x + t % 3 - 1;
    vmask[t] = ((yy >= 0) && (yy < 96) && (xx >= 0) && (xx < 96)) ? 1.f : 0.f;
  }
  const int vbase = (ty + 3) * SW + (tx + 3);

  float acc[27];
#pragma unroll
  for (int oc = 0; oc < 27; ++oc) acc[oc] = 0.f;

  const float* iaA = base + 2 * cg_lo * 9216;
  const float* iaB = iaA + 9216;
  float2 pv0 = make_float2(iaA[g0], iaB[g0]);
  float2 pv1 = make_float2(iaA[g1], iaB[g1]);
  float2 pv2 = (tid < SN - 512) ? make_float2(iaA[g2], iaB[g2])
                                : make_float2(0.f, 0.f);

  int bsel = 0;
  for (int cg = cg_lo; cg < cg_lo + 5; ++cg, bsel ^= 1) {
    float sa = s1[e * 20 + 2 * cg], ba = b1[e * 20 + 2 * cg];
    float sb = s1[e * 20 + 2 * cg + 1], bb2 = b1[e * 20 + 2 * cg + 1];
    float2* buf = sbuf[bsel];
    buf[tid] = make_float2(fmaxf(fmaf(sa, pv0.x, ba), 0.f),
                           fmaxf(fmaf(sb, pv0.y, bb2), 0.f));
    buf[tid + 256] = make_float2(fmaxf(fmaf(sa, pv1.x, ba), 0.f),
                                 fmaxf(fmaf(sb, pv1.y, bb2), 0.f));
    if (tid < SN - 512)
      buf[tid + 512] = make_float2(fmaxf(fmaf(sa, pv2.x, ba), 0.f),
                                   fmaxf(fmaf(sb, pv2.y, bb2), 0.f));
    if (cg + 1 < cg_lo + 5) {
      const float* naA = base + (2 * cg + 2) * 9216;
      const float* naB = naA + 9216;
      pv0 = make_float2(naA[g0], naB[g0]);
      pv1 = make_float2(naA[g1], naB[g1]);
      if (tid < SN - 512) pv2 = make_float2(naA[g2], naB[g2]);
    }
    __syncthreads();
#pragma unroll
    for (int t = 0; t < 9; ++t) {
      float2 v = buf[vbase + (t / 3) * SW + (t % 3)];
      float vx = vmask[t] * v.x, vy = vmask[t] * v.y;
      const float* wc = wf + ((e * 10 + cg) * 9 + t) * 54;  // pair-interleaved
#pragma unroll
      for (int oc = 0; oc < 27; ++oc)
        acc[oc] = fmaf(vx, wc[2 * oc], fmaf(vy, wc[2 * oc + 1], acc[oc]));
    }
  }
#pragma unroll
  for (int oc = 0; oc < 27; ++oc)
    atomicAdd(&o2[(e * 27 + oc) * 9216 + p], acc[oc]);
}

// ---------------------------------------------------------------------------
// Deformable main conv 2: float2 pair staging (affine+relu fused); pair
// weights; split z=2, atomic raw into zero-inited h2. grid (10, 36, 2)
// ---------------------------------------------------------------------------
__global__ __launch_bounds__(256) void dfmain2_k(
    const float* __restrict__ h1a, const float* __restrict__ o2,
    const float* __restrict__ wm, const float* __restrict__ s1,
    const float* __restrict__ b1, float* __restrict__ hout) {
  __shared__ float2 sbuf[2][SN];
  const int e = blockIdx.x, m = blockIdx.y;
  const int cg_lo = blockIdx.z * 5;
  const int tid = threadIdx.x;
  const int tx = tid % TW, ty = tid / TW;
  const int tx0 = (m % 3) * TW, ty0 = (m / 3) * TH;
  const int y = ty0 + ty, x = tx0 + tx;
  const int p = y * 96 + x;
  const float* base = h1a + e * 20 * 9216;

  const int g0 = stage_goff(tid, ty0, tx0);
  const int g1 = stage_goff(tid + 256, ty0, tx0);
  const int g2 = (tid < SN - 512) ? stage_goff(tid + 512, ty0, tx0) : 0;

  int iob[9]; float cw[9][4];
  bool oob = false;
#pragma unroll
  for (int k = 0; k < 9; ++k) {
    float offy = o2[(e * 27 + 2 * k) * 9216 + p];
    float offx = o2[(e * 27 + 2 * k + 1) * 9216 + p];
    float mk = sigm(o2[(e * 27 + 18 + k) * 9216 + p]);
    float py = (float)(y + k / 3 - 1) + offy;
    float px = (float)(x + k % 3 - 1) + offx;
    float fy = floorf(py), fx = floorf(px);
    float wy = py - fy, wx = px - fx;
    int iy = (int)fy, ix = (int)fx;
#pragma unroll
    for (int dy = 0; dy < 2; ++dy)
#pragma unroll
      for (int dx = 0; dx < 2; ++dx) {
        bool ok = (iy + dy >= 0) && (iy + dy < 96) && (ix + dx >= 0) && (ix + dx < 96);
        cw[k][dy * 2 + dx] =
            (ok ? mk : 0.f) * (dy ? wy : (1.f - wy)) * (dx ? wx : (1.f - wx));
      }
    int ir = iy - (ty0 - 4), ic = ix - (tx0 - 4);
    oob |= ((unsigned)ir > (unsigned)(SH - 2)) | ((unsigned)ic > (unsigned)(SDC - 2));
    iob[k] = min(max(ir, 0), SH - 2) * SW + min(max(ic, 0), SDC - 2);
  }

  float acc[10];
#pragma unroll
  for (int oc = 0; oc < 10; ++oc) acc[oc] = 0.f;

  const float* iaA = base + 2 * cg_lo * 9216;
  const float* iaB = iaA + 9216;
  float2 pv0 = make_float2(iaA[g0], iaB[g0]);
  float2 pv1 = make_float2(iaA[g1], iaB[g1]);
  float2 pv2 = (tid < SN - 512) ? make_float2(iaA[g2], iaB[g2])
                                : make_float2(0.f, 0.f);

  int bsel = 0;
  for (int cg = cg_lo; cg < cg_lo + 5; ++cg, bsel ^= 1) {
    float sa = s1[e * 20 + 2 * cg], ba = b1[e * 20 + 2 * cg];
    float sb = s1[e * 20 + 2 * cg + 1], bb2 = b1[e * 20 + 2 * cg + 1];
    float2* buf = sbuf[bsel];
    buf[tid] = make_float2(fmaxf(fmaf(sa, pv0.x, ba), 0.f),
                           fmaxf(fmaf(sb, pv0.y, bb2), 0.f));
    buf[tid + 256] = make_float2(fmaxf(fmaf(sa, pv1.x, ba), 0.f),
                                 fmaxf(fmaf(sb, pv1.y, bb2), 0.f));
    if (tid < SN - 512)
      buf[tid + 512] = make_float2(fmaxf(fmaf(sa, pv2.x, ba), 0.f),
                                   fmaxf(fmaf(sb, pv2.y, bb2), 0.f));
    if (cg + 1 < cg_lo + 5) {
      const float* naA = base + (2 * cg + 2) * 9216;
      const float* naB = naA + 9216;
      pv0 = make_float2(naA[g0], naB[g0]);
      pv1 = make_float2(naA[g1], naB[g1]);
      if (tid < SN - 512) pv2 = make_float2(naA[g2], naB[g2]);
    }
    __syncthreads();
#pragma unroll
    for (int k = 0; k < 9; ++k) {
      const float2* bk = buf + iob[k];
      float2 b00 = bk[0], b01 = bk[1], b10 = bk[SW], b11 = bk[SW + 1];
      float sx = cw[k][0] * b00.x + cw[k][1] * b01.x +
                 cw[k][2] * b10.x + cw[k][3] * b11.x;
      float sy = cw[k][0] * b00.y + cw[k][1] * b01.y +
                 cw[k][2] * b10.y + cw[k][3] * b11.y;
      const float* wc = wm + ((e * 9 + k) * 10 + cg) * 20;  // pair-interleaved
#pragma unroll
      for (int oc = 0; oc < 10; ++oc)
        acc[oc] = fmaf(sx, wc[2 * oc], fmaf(sy, wc[2 * oc + 1], acc[oc]));
    }
  }

  if (oob) {
#pragma unroll
    for (int oc = 0; oc < 10; ++oc) acc[oc] = 0.f;
    for (int k = 0; k < 9; ++k) {
      float offy = o2[(e * 27 + 2 * k) * 9216 + p];
      float offx = o2[(e * 27 + 2 * k + 1) * 9216 + p];
      float mk = sigm(o2[(e * 27 + 18 + k) * 9216 + p]);
      float py = (float)(y + k / 3 - 1) + offy;
      float px = (float)(x + k % 3 - 1) + offx;
      float fy = floorf(py), fx = floorf(px);
      float wy = py - fy, wx = px - fx;
      int iy = (int)fy, ix = (int)fx;
      int go[4]; float gw[4];
#pragma unroll
      for (int dy = 0; dy < 2; ++dy)
#pragma unroll
        for (int dx = 0; dx < 2; ++dx) {
          bool ok = (iy + dy >= 0) && (iy + dy < 96) && (ix + dx >= 0) && (ix + dx < 96);
          int yc = min(max(iy + dy, 0), 95), xc = min(max(ix + dx, 0), 95);
          go[dy * 2 + dx] = yc * 96 + xc;
          gw[dy * 2 + dx] =
              (ok ? mk : 0.f) * (dy ? wy : (1.f - wy)) * (dx ? wx : (1.f - wx));
        }
      for (int c = 2 * cg_lo; c < 2 * cg_lo + 10; ++c) {
        float sc = s1[e * 20 + c], bc = b1[e * 20 + c];
        const float* ptr = base + c * 9216;
        float v0 = fmaxf(fmaf(sc, ptr[go[0]], bc), 0.f);
        float v1 = fmaxf(fmaf(sc, ptr[go[1]], bc), 0.f);
        float v2 = fmaxf(fmaf(sc, ptr[go[2]], bc), 0.f);
        float v3 = fmaxf(fmaf(sc, ptr[go[3]], bc), 0.f);
        float sv = gw[0] * v0 + gw[1] * v1 + gw[2] * v2 + gw[3] * v3;
        const float* wc = wm + ((e * 9 + k) * 10 + (c >> 1)) * 20 + (c & 1);
#pragma unroll
        for (int oc = 0; oc < 10; ++oc)
          acc[oc] = fmaf(sv, wc[2 * oc], acc[oc]);
      }
    }
  }
#pragma unroll
  for (int oc = 0; oc < 10; ++oc)
    atomicAdd(&hout[(e * 10 + oc) * 9216 + p], acc[oc]);
}

// 1x1 conv p_fea (256ch) -> accfh[j][10][9216], split-K atomic. grid (36,6,4)
__global__ __launch_bounds__(256) void conv_fh_k(
    const float* __restrict__ pfea, const float* __restrict__ wfh,
    float* __restrict__ accfh) {
  const int j = blockIdx.y;
  const int z = blockIdx.z;
  const int p = blockIdx.x * 256 + threadIdx.x;
  const int c_lo = z * 64;
  float acc[10];
#pragma unroll
  for (int c = 0; c < 10; ++c) acc[c] = 0.f;
  for (int ci = c_lo; ci < c_lo + 64; ci += 4) {
    float pv0 = pfea[ci * 9216 + p];
    float pv1 = pfea[(ci + 1) * 9216 + p];
    float pv2 = pfea[(ci + 2) * 9216 + p];
    float pv3 = pfea[(ci + 3) * 9216 + p];
#pragma unroll
    for (int c = 0; c < 10; ++c) {
      acc[c] = fmaf(pv0, wfh[(j * 10 + c) * 256 + ci], acc[c]);
      acc[c] = fmaf(pv1, wfh[(j * 10 + c) * 256 + ci + 1], acc[c]);
      acc[c] = fmaf(pv2, wfh[(j * 10 + c) * 256 + ci + 2], acc[c]);
      acc[c] = fmaf(pv3, wfh[(j * 10 + c) * 256 + ci + 3], acc[c]);
    }
  }
#pragma unroll
  for (int c = 0; c < 10; ++c)
    atomicAdd(&accfh[(j * 10 + c) * 9216 + p], acc[c]);
}

// ---------------------------------------------------------------------------
// Fused node-message + GRU stage; applies h2 affine (s2,b2)+relu inline.
// grid (36, 6)
// ---------------------------------------------------------------------------
__global__ __launch_bounds__(256) void msggru_k(
    const float* __restrict__ xp, const float* __restrict__ xh,
    const float* __restrict__ h2, const float* __restrict__ accfh,
    const float* __restrict__ s2, const float* __restrict__ b2g,
    const float* __restrict__ aw, const float* __restrict__ ab,
    const float* __restrict__ bw, const float* __restrict__ bb,
    const float* __restrict__ w1, const float* __restrict__ s1,
    const float* __restrict__ b1, const float* __restrict__ w2,
    const float* __restrict__ b2, const float* __restrict__ sfh,
    const float* __restrict__ bfh,
    const float* __restrict__ wih1, const float* __restrict__ bih1,
    const float* __restrict__ bhh1, const float* __restrict__ wih2,
    const float* __restrict__ bih2, const float* __restrict__ bhh2,
    float* __restrict__ out_m, float* __restrict__ out_x) {
  const int j = blockIdx.y;
  const int p = blockIdx.x * 256 + threadIdx.x;
  float xj[10];
#pragma unroll
  for (int c = 0; c < 10; ++c) xj[c] = xp[(j * 10 + c) * 9216 + p];
  float xpp[10];
  int ne = d_ne[j];
  for (int ei = 0; ei < ne; ++ei) {
    int e = d_inc[j][ei];
    int a2 = d_esrc[e];
    float sA = ab[e];
#pragma unroll
    for (int c = 0; c < 10; ++c)
      sA = fmaf(xp[(a2 * 10 + c) * 9216 + p], aw[e * 10 + c], sA);
    float sB = bb[e];
#pragma unroll
    for (int c = 0; c < 10; ++c) sB = fmaf(xj[c], bw[e * 10 + c], sB);
    float f = (1.f - sigm(sA)) * sigm(sB);
#pragma unroll
    for (int c = 0; c < 10; ++c) {
      float raw = h2[(e * 10 + c) * 9216 + p];
      float hv = fmaxf(fmaf(s2[e * 10 + c], raw, b2g[e * 10 + c]), 0.f);
      float mm = f * hv;
      xpp[c] = (ei == 0) ? mm : fmaxf(xpp[c], mm);
    }
  }
  const float* hf = xh + ((j < 4) ? 0 : 1) * 10 * 9216;
  float cat[20];
#pragma unroll
  for (int c = 0; c < 10; ++c) cat[c] = hf[c * 9216 + p];
#pragma unroll
  for (int c = 0; c < 10; ++c) cat[10 + c] = xj[c];
  float at = b2[j];
#pragma unroll
  for (int oc = 0; oc < 20; ++oc) {
    float t = 0.f;
#pragma unroll
    for (int c = 0; c < 20; ++c)
      t = fmaf(cat[c], w1[(j * 20 + oc) * 20 + c], t);
    float av = fmaxf(s1[j * 20 + oc] * t + b1[j * 20 + oc], 0.f);
    at = fmaf(av, w2[j * 20 + oc], at);
  }
  at = sigm(at);
  float msg[10];
#pragma unroll
  for (int c = 0; c < 10; ++c) {
    float xhp = fmaxf(sfh[j * 10 + c] * (at * accfh[(j * 10 + c) * 9216 + p]) +
                          bfh[j * 10 + c], 0.f);
    msg[c] = xpp[c] + xhp;
    out_m[(j * 10 + c) * 9216 + p] = msg[c];
  }
  float gi[30];
#pragma unroll
  for (int r = 0; r < 30; ++r) gi[r] = bih1[j * 30 + r];
#pragma unroll
  for (int c = 0; c < 10; ++c) {
    float v = xj[c];
#pragma unroll
    for (int r = 0; r < 30; ++r)
      gi[r] = fmaf(v, wih1[(j * 30 + r) * 20 + c], gi[r]);
  }
#pragma unroll
  for (int c = 0; c < 10; ++c) {
    float v = msg[c];
#pragma unroll
    for (int r = 0; r < 30; ++r)
      gi[r] = fmaf(v, wih1[(j * 30 + r) * 20 + 10 + c], gi[r]);
  }
  float h1v[10];
#pragma unroll
  for (int c = 0; c < 10; ++c) {
    float r = sigm(gi[c] + bhh1[j * 30 + c]);
    float z = sigm(gi[10 + c] + bhh1[j * 30 + 10 + c]);
    float n = tanhf(gi[20 + c] + r * bhh1[j * 30 + 20 + c]);
    h1v[c] = (1.f - z) * n;
  }
  float g2v[30];
#pragma unroll
  for (int r = 0; r < 30; ++r) g2v[r] = bih2[j * 30 + r];
#pragma unroll
  for (int c = 0; c < 10; ++c) {
    float v = h1v[c];
#pragma unroll
    for (int r = 0; r < 30; ++r)
      g2v[r] = fmaf(v, wih2[(j * 30 + r) * 10 + c], g2v[r]);
  }
#pragma unroll
  for (int c = 0; c < 10; ++c) {
    float r = sigm(g2v[c] + bhh2[j * 30 + c]);
    float z = sigm(g2v[10 + c] + bhh2[j * 30 + 10 + c]);
    float n = tanhf(g2v[20 + c] + r * bhh2[j * 30 + 20 + c]);
    out_x[(j * 10 + c) * 9216 + p] = (1.f - z) * n;
  }
}

extern "C" void kernel_launch(void* const* d_in, const int* in_sizes, int n_in,
                              void* d_out, int out_size, void* d_ws, size_t ws_size,
                              hipStream_t stream) {
  const float* pfea   = (const float*)d_in[0];
  const float* xp     = (const float*)d_in[1];
  const float* xh     = (const float*)d_in[2];
  const float* dp_ow1 = (const float*)d_in[3];
  const float* dp_ob1 = (const float*)d_in[4];
  const float* dp_w1  = (const float*)d_in[5];
  const float* dp_s1  = (const float*)d_in[6];
  const float* dp_b1  = (const float*)d_in[7];
  const float* dp_ow2 = (const float*)d_in[8];
  const float* dp_ob2 = (const float*)d_in[9];
  const float* dp_w2  = (const float*)d_in[10];
  const float* dp_s2  = (const float*)d_in[11];
  const float* dp_b2  = (const float*)d_in[12];
  const float* dp_aw  = (const float*)d_in[13];
  const float* dp_ab  = (const float*)d_in[14];
  const float* dp_bw  = (const float*)d_in[15];
  const float* dp_bb  = (const float*)d_in[16];
  const float* dc_w1  = (const float*)d_in[17];
  const float* dc_s1  = (const float*)d_in[18];
  const float* dc_b1  = (const float*)d_in[19];
  const float* dc_w2  = (const float*)d_in[20];
  const float* dc_b2  = (const float*)d_in[21];
  const float* dc_wfh = (const float*)d_in[22];
  const float* dc_sfh = (const float*)d_in[23];
  const float* dc_bfh = (const float*)d_in[24];
  const float* g_wih1 = (const float*)d_in[25];
  const float* g_bih1 = (const float*)d_in[26];
  const float* g_bhh1 = (const float*)d_in[28];
  const float* g_wih2 = (const float*)d_in[29];
  const float* g_bih2 = (const float*)d_in[30];
  const float* g_bhh2 = (const float*)d_in[32];

  float* ws = (float*)d_ws;
  unsigned short* aw1 = (unsigned short*)ws;   // phase 1 (1,361,920 f)
  float* accfh = ws;                           // phase 2
  float* h2    = ws + 552960;
  float* wf2 = ws + 1474560;    // 48600  (pair-interleaved)
  float* wm1 = wf2 + 48600;     // 478800 (pair-interleaved)
  float* wm2 = wm1 + 478800;    // 18000  (pair-interleaved)
  float* o1  = wm2 + 18000;     // 2488320 (o2 aliases after dfmain1)
  float* o2  = o1;
  float* h1a = o1 + 2488320;    // 1843200
  // total: 6,351,480 floats = 25.4 MB

  float* out_x = (float*)d_out;        // xp_out: 6*10*9216
  float* out_m = out_x + 552960;       // msgs:   6*10*9216

  prep_wp<<<dim3(190), 256, 0, stream>>>(dp_ow2, wf2, 27, 20, 1, 48600);
  prep_wp<<<dim3(1871), 256, 0, stream>>>(dp_w1, wm1, 20, 266, 0, 478800);
  prep_wp<<<dim3(71), 256, 0, stream>>>(dp_w2, wm2, 10, 20, 0, 18000);
  aprep1_k<<<dim3(665), 256, 0, stream>>>(dp_ow1, aw1);

  init_k<<<dim3(16920), 256, 0, stream>>>(dp_ob1, o1, h1a);

  dim3 blk(256);
  offconv1_mfma_k<<<dim3(10, 36, 4), blk, 0, stream>>>(pfea, xp, aw1, o1);
  dfmain1_k<<<dim3(10, 36, 8), blk, 0, stream>>>(pfea, xp, o1, wm1, h1a);

  init2_k<<<dim3(13320), 256, 0, stream>>>(dp_ob2, o2, h2);
  offconv2_k<<<dim3(10, 36, 2), blk, 0, stream>>>(h1a, wf2, dp_s1, dp_b1, o2);
  dfmain2_k<<<dim3(10, 36, 2), blk, 0, stream>>>(h1a, o2, wm2, dp_s1, dp_b1, h2);

  hipMemsetAsync(accfh, 0, 552960 * sizeof(float), stream);
  conv_fh_k<<<dim3(36, 6, 4), blk, 0, stream>>>(pfea, dc_wfh, accfh);

  msggru_k<<<dim3(36, 6), blk, 0, stream>>>(
      xp, xh, h2, accfh, dp_s2, dp_b2, dp_aw, dp_ab, dp_bw, dp_bb,
      dc_w1, dc_s1, dc_b1, dc_w2, dc_b2, dc_sfh, dc_bfh,
      g_wih1, g_bih1, g_bhh1, g_wih2, g_bih2, g_bhh2, out_m, out_x);
}

// Round 8
// 617.875 us; speedup vs baseline: 1.1745x; 1.1745x over previous
//
#include <hip/hip_runtime.h>
#include <hip/hip_bf16.h>

#define DEV static __device__ __forceinline__

DEV float sigm(float x) { return 1.f / (1.f + __expf(-x)); }

typedef __attribute__((ext_vector_type(8))) short s8;   // 8 bf16 (4 VGPRs)
typedef __attribute__((ext_vector_type(4))) float f4;   // 4 fp32 acc

DEV unsigned short f2bf(float f) {  // RNE float->bf16 bits (finite inputs)
  unsigned u = __float_as_uint(f);
  return (unsigned short)((u + 0x7FFFu + ((u >> 16) & 1u)) >> 16);
}
DEV float bf2f(unsigned short h) { return __uint_as_float(((unsigned)h) << 16); }

// Edge tables from ADJ nonzeros: (src, dst) pairs in np.nonzero order
__constant__ int d_esrc[10] = {0,1,1,1,2,2,3,4,4,5};
__constant__ int d_inc[6][3] = {{1,-1,-1},{0,4,7},{2,6,-1},{5,-1,-1},{3,9,-1},{8,-1,-1}};
__constant__ int d_ne[6] = {1,3,2,1,2,1};

// Deformable tile geometry: 32x8 px, halo 4 -> 16 x 40 data, stride 41.
#define TW 32
#define TH 8
#define SW 41
#define SDC 40
#define SH 16
#define SN 656

// ---------------------------------------------------------------------------
// Merged weight prep: one launch does all 4 transposes.
//  prep_w semantics (r6): src [e][OC][C][3][3]
//   tap_major=0: dst [e][C][9][OC]   tap_major=1: dst [e][9][C][OC]
//  aprep1 semantics: bf16 hi/lo A-fragments for offconv1 MFMA.
// Block ranges: [0,1871) wm1 | [1871,2061) wf2 | [2061,2132) wm2 |
//               [2132,2797) aprep1
// ---------------------------------------------------------------------------
DEV void prep_w_body(const float* src, float* dst, int OC, int C,
                     int tap_major, int total, int i) {
  if (i >= total) return;
  int t = i % 9; int n = i / 9;
  int c = n % C; n /= C;
  int oc = n % OC; int e = n / OC;
  float v = src[i];
  int inner = tap_major ? (t * C + c) : (c * 9 + t);
  dst[(e * C * 9 + inner) * OC + oc] = v;
}

__global__ void prep_all_k(const float* __restrict__ dp_w1, float* __restrict__ wm1,
                           const float* __restrict__ dp_ow2, float* __restrict__ wf2,
                           const float* __restrict__ dp_w2, float* __restrict__ wm2,
                           const float* __restrict__ dp_ow1,
                           unsigned short* __restrict__ aw1) {
  int b = blockIdx.x;
  if (b < 1871) {
    prep_w_body(dp_w1, wm1, 20, 266, 1, 478800, b * 256 + threadIdx.x);
  } else if (b < 2061) {
    prep_w_body(dp_ow2, wf2, 27, 20, 0, 48600, (b - 1871) * 256 + threadIdx.x);
  } else if (b < 2132) {
    prep_w_body(dp_w2, wm2, 10, 20, 1, 18000, (b - 2061) * 256 + threadIdx.x);
  } else {
    int i = (b - 2132) * 256 + threadIdx.x;       // 170240 total
    int lane = i & 63;
    int tile = (i >> 6) & 1;
    int cg = (i >> 7) % 133;
    int e = (i >> 7) / 133;
    int m = lane & 15, quad = lane >> 4;
    int oc = tile * 16 + m;
    unsigned short* out = aw1 + ((e * 133 + cg) * 2 + tile) * 1024 + lane * 16;
#pragma unroll
    for (int j = 0; j < 8; ++j) {
      int k = quad * 8 + j;
      int csel = k >> 4, t = k & 15;
      int c = 2 * cg + csel;
      float w = (oc < 27 && t < 9) ? dp_ow1[((e * 27 + oc) * 266 + c) * 9 + t] : 0.f;
      unsigned short h = f2bf(w);
      float fl = w - bf2f(h);
      out[j] = h;
      out[8 + j] = f2bf(fl);
    }
  }
}

// o2 = bias broadcast; h2 = 0.
__global__ void init2_k(const float* __restrict__ ob, float* __restrict__ o2,
                        float* __restrict__ h2) {
  int i = blockIdx.x * 256 + threadIdx.x;
  if (i < 2488320) o2[i] = ob[i / 9216];
  else h2[i - 2488320] = 0.f;
}

// Staging address for deformable halo-4 window (clamped), element i of 16x41.
DEV int stage_goff(int i, int ty0, int tx0) {
  int r = i / SW, cl = i % SW;
  cl = min(cl, SDC - 1);
  int gy = min(max(ty0 - 4 + r, 0), 95);
  int gx = min(max(tx0 - 4 + cl, 0), 95);
  return gy * 96 + gx;
}

// ---------------------------------------------------------------------------
// Offset conv 1 via MFMA. grid (10, 36, 4). o1 is zero-inited; bias added by
// the z==0 block in the epilogue.
// ---------------------------------------------------------------------------
#define OSWB 35
#define OSEC 384
#define OBUF 896

__global__ __launch_bounds__(256) void offconv1_mfma_k(
    const float* __restrict__ pfea, const float* __restrict__ xp,
    const unsigned short* __restrict__ aw, const float* __restrict__ ob,
    float* __restrict__ o1) {
  __shared__ float sbuf[2][OBUF];
  const int e = blockIdx.x, m = blockIdx.y, z = blockIdx.z;
  const int tid = threadIdx.x;
  const int lane = tid & 63, wv = tid >> 6;
  const int quad = lane >> 4, n16 = lane & 15;
  const int tx0 = (m % 3) * 32, ty0 = (m / 3) * 8;
  const float* xpe = xp + d_esrc[e] * 10 * 9216;
  const int cg_lo = (z * 133) / 4, cg_hi = ((z + 1) * 133) / 4;

  int g[3]; bool oks[3];
#pragma unroll
  for (int i = 0; i < 3; ++i) {
    int s = tid + i * 256;
    int sec = s / OSEC, off = s - sec * OSEC;
    int r = off / OSWB, cl = off % OSWB;
    int gy = ty0 - 1 + r, gx = tx0 - 1 + cl;
    bool ok = (off < 350) && (cl < 34) && (gy >= 0) && (gy < 96) &&
              (gx >= 0) && (gx < 96);
    oks[i] = ok;
    g[i] = sec * 9216 + (ok ? (gy * 96 + gx) : 0);
  }
  if (tid < OBUF - 768) { sbuf[0][768 + tid] = 0.f; sbuf[1][768 + tid] = 0.f; }

  const int tbase = (quad & 1) * 8;
  const int csel = quad >> 1;
  int bdelta[8];
#pragma unroll
  for (int j = 0; j < 8; ++j) {
    int t = tbase + j;
    int dy = t / 3 - 1, dx = t % 3 - 1;
    bdelta[j] = csel * OSEC + dy * OSWB + dx;
  }
  int bidx[4];
#pragma unroll
  for (int nt = 0; nt < 4; ++nt) {
    int r = 2 * wv + (nt >> 1), h = nt & 1;
    bidx[nt] = (r + 1) * OSWB + (h * 16 + n16 + 1);
  }

  f4 acc[4][2] = {};

  int c0 = 2 * cg_lo;
  const float* base = (c0 < 256) ? (pfea + c0 * 9216) : (xpe + (c0 - 256) * 9216);
  float pv0 = oks[0] ? base[g[0]] : 0.f;
  float pv1 = oks[1] ? base[g[1]] : 0.f;
  float pv2 = oks[2] ? base[g[2]] : 0.f;

  int bsel = 0;
  for (int cg = cg_lo; cg < cg_hi; ++cg, bsel ^= 1) {
    float* buf = sbuf[bsel];
    buf[tid] = pv0; buf[tid + 256] = pv1; buf[tid + 512] = pv2;
    if (cg + 1 < cg_hi) {
      int c0n = 2 * (cg + 1);
      const float* nb = (c0n < 256) ? (pfea + c0n * 9216)
                                    : (xpe + (c0n - 256) * 9216);
      pv0 = oks[0] ? nb[g[0]] : 0.f;
      pv1 = oks[1] ? nb[g[1]] : 0.f;
      pv2 = oks[2] ? nb[g[2]] : 0.f;
    }
    const unsigned short* apc = aw + (e * 133 + cg) * 2048 + lane * 16;
    s8 Ah0 = *(const s8*)(apc);
    s8 Al0 = *(const s8*)(apc + 8);
    s8 Ah1 = *(const s8*)(apc + 1024);
    s8 Al1 = *(const s8*)(apc + 1024 + 8);
    __syncthreads();
#pragma unroll
    for (int nt = 0; nt < 4; ++nt) {
      union { s8 v; unsigned short u[8]; } Bh, Bl;
#pragma unroll
      for (int j = 0; j < 8; ++j) {
        float v = buf[bidx[nt] + bdelta[j]];
        unsigned short h = f2bf(v);
        Bh.u[j] = h;
        Bl.u[j] = f2bf(v - bf2f(h));
      }
      acc[nt][0] = __builtin_amdgcn_mfma_f32_16x16x32_bf16(Ah0, Bh.v, acc[nt][0], 0, 0, 0);
      acc[nt][0] = __builtin_amdgcn_mfma_f32_16x16x32_bf16(Ah0, Bl.v, acc[nt][0], 0, 0, 0);
      acc[nt][0] = __builtin_amdgcn_mfma_f32_16x16x32_bf16(Al0, Bh.v, acc[nt][0], 0, 0, 0);
      acc[nt][1] = __builtin_amdgcn_mfma_f32_16x16x32_bf16(Ah1, Bh.v, acc[nt][1], 0, 0, 0);
      acc[nt][1] = __builtin_amdgcn_mfma_f32_16x16x32_bf16(Ah1, Bl.v, acc[nt][1], 0, 0, 0);
      acc[nt][1] = __builtin_amdgcn_mfma_f32_16x16x32_bf16(Al1, Bh.v, acc[nt][1], 0, 0, 0);
    }
  }
#pragma unroll
  for (int nt = 0; nt < 4; ++nt) {
    int y = ty0 + 2 * wv + (nt >> 1);
    int xx = tx0 + (nt & 1) * 16 + n16;
    int p = y * 96 + xx;
#pragma unroll
    for (int t2 = 0; t2 < 2; ++t2)
#pragma unroll
      for (int r = 0; r < 4; ++r) {
        int oc = t2 * 16 + quad * 4 + r;
        if (oc < 27) {
          float v = acc[nt][t2][r];
          if (z == 0) v += ob[e * 27 + oc];
          atomicAdd(&o1[(e * 27 + oc) * 9216 + p], v);
        }
      }
  }
}

// ---------------------------------------------------------------------------
// Deformable main conv 1 (r6 version: b32 pair-staged LDS bilinear,
// split z=8, atomic). grid (10, 36, 8)
// ---------------------------------------------------------------------------
#define IMG1(c) (((c) < 256) ? (pfea + (c) * 9216) : (xpe + ((c) - 256) * 9216))

__global__ __launch_bounds__(256) void dfmain1_k(
    const float* __restrict__ pfea, const float* __restrict__ xp,
    const float* __restrict__ o1, const float* __restrict__ wm,
    float* __restrict__ hacc) {
  __shared__ float sbuf[2][2 * SN];
  const int e = blockIdx.x, m = blockIdx.y, z = blockIdx.z;
  const int tid = threadIdx.x;
  const int tx = tid % TW, ty = tid / TW;
  const int tx0 = (m % 3) * TW, ty0 = (m / 3) * TH;
  const int y = ty0 + ty, x = tx0 + tx;
  const int p = y * 96 + x;
  const float* xpe = xp + d_esrc[e] * 10 * 9216;
  const int c_lo = (z * 266) / 8, c_hi = ((z + 1) * 266) / 8;

  const int g0 = stage_goff(tid, ty0, tx0);
  const int g1 = stage_goff(tid + 256, ty0, tx0);
  const int g2 = (tid < SN - 512) ? stage_goff(tid + 512, ty0, tx0) : 0;

  int iob[9]; float cw[9][4];
  bool oob = false;
#pragma unroll
  for (int k = 0; k < 9; ++k) {
    float offy = o1[(e * 27 + 2 * k) * 9216 + p];
    float offx = o1[(e * 27 + 2 * k + 1) * 9216 + p];
    float mk = sigm(o1[(e * 27 + 18 + k) * 9216 + p]);
    float py = (float)(y + k / 3 - 1) + offy;
    float px = (float)(x + k % 3 - 1) + offx;
    float fy = floorf(py), fx = floorf(px);
    float wy = py - fy, wx = px - fx;
    int iy = (int)fy, ix = (int)fx;
#pragma unroll
    for (int dy = 0; dy < 2; ++dy)
#pragma unroll
      for (int dx = 0; dx < 2; ++dx) {
        bool ok = (iy + dy >= 0) && (iy + dy < 96) && (ix + dx >= 0) && (ix + dx < 96);
        cw[k][dy * 2 + dx] =
            (ok ? mk : 0.f) * (dy ? wy : (1.f - wy)) * (dx ? wx : (1.f - wx));
      }
    int ir = iy - (ty0 - 4), ic = ix - (tx0 - 4);
    oob |= ((unsigned)ir > (unsigned)(SH - 2)) | ((unsigned)ic > (unsigned)(SDC - 2));
    iob[k] = min(max(ir, 0), SH - 2) * SW + min(max(ic, 0), SDC - 2);
  }

  float acc[20];
#pragma unroll
  for (int oc = 0; oc < 20; ++oc) acc[oc] = 0.f;

  const float* ia = IMG1(c_lo);
  const float* ib = IMG1(min(c_lo + 1, c_hi - 1));
  float pa0 = ia[g0], pa1 = ia[g1], pa2 = (tid < SN - 512) ? ia[g2] : 0.f;
  float pb0 = ib[g0], pb1 = ib[g1], pb2 = (tid < SN - 512) ? ib[g2] : 0.f;

  int bsel = 0;
  for (int c = c_lo; c < c_hi; c += 2, bsel ^= 1) {
    float* buf = sbuf[bsel];
    buf[tid] = pa0; buf[tid + 256] = pa1;
    if (tid < SN - 512) buf[tid + 512] = pa2;
    buf[SN + tid] = pb0; buf[SN + tid + 256] = pb1;
    if (tid < SN - 512) buf[SN + tid + 512] = pb2;
    if (c + 2 < c_hi) {
      const float* na = IMG1(c + 2);
      const float* nb = IMG1(min(c + 3, c_hi - 1));
      pa0 = na[g0]; pa1 = na[g1]; if (tid < SN - 512) pa2 = na[g2];
      pb0 = nb[g0]; pb1 = nb[g1]; if (tid < SN - 512) pb2 = nb[g2];
    }
    __syncthreads();
    {
#pragma unroll
      for (int k = 0; k < 9; ++k) {
        const float* bk = buf + iob[k];
        float sv = cw[k][0] * bk[0] + cw[k][1] * bk[1] +
                   cw[k][2] * bk[SW] + cw[k][3] * bk[SW + 1];
        const float* wc = wm + ((e * 9 + k) * 266 + c) * 20;
#pragma unroll
        for (int oc = 0; oc < 20; ++oc) acc[oc] = fmaf(sv, wc[oc], acc[oc]);
      }
    }
    if (c + 1 < c_hi) {
      const float* bufb = buf + SN;
#pragma unroll
      for (int k = 0; k < 9; ++k) {
        const float* bk = bufb + iob[k];
        float sv = cw[k][0] * bk[0] + cw[k][1] * bk[1] +
                   cw[k][2] * bk[SW] + cw[k][3] * bk[SW + 1];
        const float* wc = wm + ((e * 9 + k) * 266 + c + 1) * 20;
#pragma unroll
        for (int oc = 0; oc < 20; ++oc) acc[oc] = fmaf(sv, wc[oc], acc[oc]);
      }
    }
  }

  if (oob) {
#pragma unroll
    for (int oc = 0; oc < 20; ++oc) acc[oc] = 0.f;
    for (int k = 0; k < 9; ++k) {
      float offy = o1[(e * 27 + 2 * k) * 9216 + p];
      float offx = o1[(e * 27 + 2 * k + 1) * 9216 + p];
      float mk = sigm(o1[(e * 27 + 18 + k) * 9216 + p]);
      float py = (float)(y + k / 3 - 1) + offy;
      float px = (float)(x + k % 3 - 1) + offx;
      float fy = floorf(py), fx = floorf(px);
      float wy = py - fy, wx = px - fx;
      int iy = (int)fy, ix = (int)fx;
      int go[4]; float gw[4];
#pragma unroll
      for (int dy = 0; dy < 2; ++dy)
#pragma unroll
        for (int dx = 0; dx < 2; ++dx) {
          bool ok = (iy + dy >= 0) && (iy + dy < 96) && (ix + dx >= 0) && (ix + dx < 96);
          int yc = min(max(iy + dy, 0), 95), xc = min(max(ix + dx, 0), 95);
          go[dy * 2 + dx] = yc * 96 + xc;
          gw[dy * 2 + dx] =
              (ok ? mk : 0.f) * (dy ? wy : (1.f - wy)) * (dx ? wx : (1.f - wx));
        }
      for (int c = c_lo; c < c_hi; ++c) {
        const float* ptr = IMG1(c);
        float sv = gw[0] * ptr[go[0]] + gw[1] * ptr[go[1]] +
                   gw[2] * ptr[go[2]] + gw[3] * ptr[go[3]];
        const float* wc = wm + ((e * 9 + k) * 266 + c) * 20;
#pragma unroll
        for (int oc = 0; oc < 20; ++oc) acc[oc] = fmaf(sv, wc[oc], acc[oc]);
      }
    }
  }
#pragma unroll
  for (int oc = 0; oc < 20; ++oc)
    atomicAdd(&hacc[(e * 20 + oc) * 9216 + p], acc[oc]);
}

// ---------------------------------------------------------------------------
// Offset conv 2 (r6 version): pair-staged, affine+relu at staging, split z=2,
// atomic into bias-inited o2. grid (10, 36, 2)
// ---------------------------------------------------------------------------
__global__ __launch_bounds__(256) void offconv2_k(
    const float* __restrict__ h1a, const float* __restrict__ wf,
    const float* __restrict__ s1, const float* __restrict__ b1,
    float* __restrict__ o2) {
  __shared__ float sbuf[2][2 * SN];
  const int e = blockIdx.x, m = blockIdx.y;
  const int c_lo = blockIdx.z * 10;
  const int tid = threadIdx.x;
  const int tx = tid % TW, ty = tid / TW;
  const int tx0 = (m % 3) * TW, ty0 = (m / 3) * TH;
  const int y = ty0 + ty, x = tx0 + tx;
  const int p = y * 96 + x;
  const float* base = h1a + e * 20 * 9216;

  const int g0 = stage_goff(tid, ty0, tx0);
  const int g1 = stage_goff(tid + 256, ty0, tx0);
  const int g2 = (tid < SN - 512) ? stage_goff(tid + 512, ty0, tx0) : 0;

  float vmask[9];
#pragma unroll
  for (int t = 0; t < 9; ++t) {
    int yy = y + t / 3 - 1, xx = x + t % 3 - 1;
    vmask[t] = ((yy >= 0) && (yy < 96) && (xx >= 0) && (xx < 96)) ? 1.f : 0.f;
  }
  const int vbase = (ty + 3) * SW + (tx + 3);

  float acc[27];
#pragma unroll
  for (int oc = 0; oc < 27; ++oc) acc[oc] = 0.f;

  const float* ia = base + c_lo * 9216;
  const float* ib = ia + 9216;
  float pa0 = ia[g0], pa1 = ia[g1], pa2 = (tid < SN - 512) ? ia[g2] : 0.f;
  float pb0 = ib[g0], pb1 = ib[g1], pb2 = (tid < SN - 512) ? ib[g2] : 0.f;

  int bsel = 0;
  for (int c = c_lo; c < c_lo + 10; c += 2, bsel ^= 1) {
    float sa = s1[e * 20 + c], ba = b1[e * 20 + c];
    float sb = s1[e * 20 + c + 1], bb2 = b1[e * 20 + c + 1];
    float* buf = sbuf[bsel];
    buf[tid] = fmaxf(fmaf(sa, pa0, ba), 0.f);
    buf[tid + 256] = fmaxf(fmaf(sa, pa1, ba), 0.f);
    if (tid < SN - 512) buf[tid + 512] = fmaxf(fmaf(sa, pa2, ba), 0.f);
    buf[SN + tid] = fmaxf(fmaf(sb, pb0, bb2), 0.f);
    buf[SN + tid + 256] = fmaxf(fmaf(sb, pb1, bb2), 0.f);
    if (tid < SN - 512) buf[SN + tid + 512] = fmaxf(fmaf(sb, pb2, bb2), 0.f);
    if (c + 2 < c_lo + 10) {
      const float* na = base + (c + 2) * 9216;
      const float* nb = base + (c + 3) * 9216;
      pa0 = na[g0]; pa1 = na[g1]; if (tid < SN - 512) pa2 = na[g2];
      pb0 = nb[g0]; pb1 = nb[g1]; if (tid < SN - 512) pb2 = nb[g2];
    }
    __syncthreads();
#pragma unroll
    for (int cc = 0; cc < 2; ++cc) {
      const float* wc = wf + (e * 20 + c + cc) * 243;
      const float* bp = buf + cc * SN;
#pragma unroll
      for (int t = 0; t < 9; ++t) {
        float v = vmask[t] * bp[vbase + (t / 3) * SW + (t % 3)];
#pragma unroll
        for (int oc = 0; oc < 27; ++oc)
          acc[oc] = fmaf(v, wc[t * 27 + oc], acc[oc]);
      }
    }
  }
#pragma unroll
  for (int oc = 0; oc < 27; ++oc)
    atomicAdd(&o2[(e * 27 + oc) * 9216 + p], acc[oc]);
}

// ---------------------------------------------------------------------------
// Deformable main conv 2 (r6 version): pair staging (affine+relu fused),
// split z=2, atomic raw into zero-inited h2. grid (10, 36, 2)
// ---------------------------------------------------------------------------
__global__ __launch_bounds__(256) void dfmain2_k(
    const float* __restrict__ h1a, const float* __restrict__ o2,
    const float* __restrict__ wm, const float* __restrict__ s1,
    const float* __restrict__ b1, float* __restrict__ hout) {
  __shared__ float sbuf[2][2 * SN];
  const int e = blockIdx.x, m = blockIdx.y;
  const int c_lo = blockIdx.z * 10;
  const int tid = threadIdx.x;
  const int tx = tid % TW, ty = tid / TW;
  const int tx0 = (m % 3) * TW, ty0 = (m / 3) * TH;
  const int y = ty0 + ty, x = tx0 + tx;
  const int p = y * 96 + x;
  const float* base = h1a + e * 20 * 9216;

  const int g0 = stage_goff(tid, ty0, tx0);
  const int g1 = stage_goff(tid + 256, ty0, tx0);
  const int g2 = (tid < SN - 512) ? stage_goff(tid + 512, ty0, tx0) : 0;

  int iob[9]; float cw[9][4];
  bool oob = false;
#pragma unroll
  for (int k = 0; k < 9; ++k) {
    float offy = o2[(e * 27 + 2 * k) * 9216 + p];
    float offx = o2[(e * 27 + 2 * k + 1) * 9216 + p];
    float mk = sigm(o2[(e * 27 + 18 + k) * 9216 + p]);
    float py = (float)(y + k / 3 - 1) + offy;
    float px = (float)(x + k % 3 - 1) + offx;
    float fy = floorf(py), fx = floorf(px);
    float wy = py - fy, wx = px - fx;
    int iy = (int)fy, ix = (int)fx;
#pragma unroll
    for (int dy = 0; dy < 2; ++dy)
#pragma unroll
      for (int dx = 0; dx < 2; ++dx) {
        bool ok = (iy + dy >= 0) && (iy + dy < 96) && (ix + dx >= 0) && (ix + dx < 96);
        cw[k][dy * 2 + dx] =
            (ok ? mk : 0.f) * (dy ? wy : (1.f - wy)) * (dx ? wx : (1.f - wx));
      }
    int ir = iy - (ty0 - 4), ic = ix - (tx0 - 4);
    oob |= ((unsigned)ir > (unsigned)(SH - 2)) | ((unsigned)ic > (unsigned)(SDC - 2));
    iob[k] = min(max(ir, 0), SH - 2) * SW + min(max(ic, 0), SDC - 2);
  }

  float acc[10];
#pragma unroll
  for (int oc = 0; oc < 10; ++oc) acc[oc] = 0.f;

  const float* ia = base + c_lo * 9216;
  const float* ib = ia + 9216;
  float pa0 = ia[g0], pa1 = ia[g1], pa2 = (tid < SN - 512) ? ia[g2] : 0.f;
  float pb0 = ib[g0], pb1 = ib[g1], pb2 = (tid < SN - 512) ? ib[g2] : 0.f;

  int bsel = 0;
  for (int c = c_lo; c < c_lo + 10; c += 2, bsel ^= 1) {
    float sa = s1[e * 20 + c], ba = b1[e * 20 + c];
    float sb = s1[e * 20 + c + 1], bb2 = b1[e * 20 + c + 1];
    float* buf = sbuf[bsel];
    buf[tid] = fmaxf(fmaf(sa, pa0, ba), 0.f);
    buf[tid + 256] = fmaxf(fmaf(sa, pa1, ba), 0.f);
    if (tid < SN - 512) buf[tid + 512] = fmaxf(fmaf(sa, pa2, ba), 0.f);
    buf[SN + tid] = fmaxf(fmaf(sb, pb0, bb2), 0.f);
    buf[SN + tid + 256] = fmaxf(fmaf(sb, pb1, bb2), 0.f);
    if (tid < SN - 512) buf[SN + tid + 512] = fmaxf(fmaf(sb, pb2, bb2), 0.f);
    if (c + 2 < c_lo + 10) {
      const float* na = base + (c + 2) * 9216;
      const float* nb = base + (c + 3) * 9216;
      pa0 = na[g0]; pa1 = na[g1]; if (tid < SN - 512) pa2 = na[g2];
      pb0 = nb[g0]; pb1 = nb[g1]; if (tid < SN - 512) pb2 = nb[g2];
    }
    __syncthreads();
#pragma unroll
    for (int cc = 0; cc < 2; ++cc) {
      const float* bp = buf + cc * SN;
#pragma unroll
      for (int k = 0; k < 9; ++k) {
        const float* bk = bp + iob[k];
        float sv = cw[k][0] * bk[0] + cw[k][1] * bk[1] +
                   cw[k][2] * bk[SW] + cw[k][3] * bk[SW + 1];
        const float* wc = wm + ((e * 9 + k) * 20 + c + cc) * 10;
#pragma unroll
        for (int oc = 0; oc < 10; ++oc) acc[oc] = fmaf(sv, wc[oc], acc[oc]);
      }
    }
  }

  if (oob) {
#pragma unroll
    for (int oc = 0; oc < 10; ++oc) acc[oc] = 0.f;
    for (int k = 0; k < 9; ++k) {
      float offy = o2[(e * 27 + 2 * k) * 9216 + p];
      float offx = o2[(e * 27 + 2 * k + 1) * 9216 + p];
      float mk = sigm(o2[(e * 27 + 18 + k) * 9216 + p]);
      float py = (float)(y + k / 3 - 1) + offy;
      float px = (float)(x + k % 3 - 1) + offx;
      float fy = floorf(py), fx = floorf(px);
      float wy = py - fy, wx = px - fx;
      int iy = (int)fy, ix = (int)fx;
      int go[4]; float gw[4];
#pragma unroll
      for (int dy = 0; dy < 2; ++dy)
#pragma unroll
        for (int dx = 0; dx < 2; ++dx) {
          bool ok = (iy + dy >= 0) && (iy + dy < 96) && (ix + dx >= 0) && (ix + dx < 96);
          int yc = min(max(iy + dy, 0), 95), xc = min(max(ix + dx, 0), 95);
          go[dy * 2 + dx] = yc * 96 + xc;
          gw[dy * 2 + dx] =
              (ok ? mk : 0.f) * (dy ? wy : (1.f - wy)) * (dx ? wx : (1.f - wx));
        }
      for (int c = c_lo; c < c_lo + 10; ++c) {
        float sc = s1[e * 20 + c], bc = b1[e * 20 + c];
        const float* ptr = base + c * 9216;
        float v0 = fmaxf(fmaf(sc, ptr[go[0]], bc), 0.f);
        float v1 = fmaxf(fmaf(sc, ptr[go[1]], bc), 0.f);
        float v2 = fmaxf(fmaf(sc, ptr[go[2]], bc), 0.f);
        float v3 = fmaxf(fmaf(sc, ptr[go[3]], bc), 0.f);
        float sv = gw[0] * v0 + gw[1] * v1 + gw[2] * v2 + gw[3] * v3;
        const float* wc = wm + ((e * 9 + k) * 20 + c) * 10;
#pragma unroll
        for (int oc = 0; oc < 10; ++oc) acc[oc] = fmaf(sv, wc[oc], acc[oc]);
      }
    }
  }
#pragma unroll
  for (int oc = 0; oc < 10; ++oc)
    atomicAdd(&hout[(e * 10 + oc) * 9216 + p], acc[oc]);
}

// 1x1 conv p_fea (256ch) -> accfh[j][10][9216], split-K atomic. grid (36,6,4)
__global__ __launch_bounds__(256) void conv_fh_k(
    const float* __restrict__ pfea, const float* __restrict__ wfh,
    float* __restrict__ accfh) {
  const int j = blockIdx.y;
  const int z = blockIdx.z;
  const int p = blockIdx.x * 256 + threadIdx.x;
  const int c_lo = z * 64;
  float acc[10];
#pragma unroll
  for (int c = 0; c < 10; ++c) acc[c] = 0.f;
  for (int ci = c_lo; ci < c_lo + 64; ci += 4) {
    float pv0 = pfea[ci * 9216 + p];
    float pv1 = pfea[(ci + 1) * 9216 + p];
    float pv2 = pfea[(ci + 2) * 9216 + p];
    float pv3 = pfea[(ci + 3) * 9216 + p];
#pragma unroll
    for (int c = 0; c < 10; ++c) {
      acc[c] = fmaf(pv0, wfh[(j * 10 + c) * 256 + ci], acc[c]);
      acc[c] = fmaf(pv1, wfh[(j * 10 + c) * 256 + ci + 1], acc[c]);
      acc[c] = fmaf(pv2, wfh[(j * 10 + c) * 256 + ci + 2], acc[c]);
      acc[c] = fmaf(pv3, wfh[(j * 10 + c) * 256 + ci + 3], acc[c]);
    }
  }
#pragma unroll
  for (int c = 0; c < 10; ++c)
    atomicAdd(&accfh[(j * 10 + c) * 9216 + p], acc[c]);
}

// ---------------------------------------------------------------------------
// Fused node-message + GRU stage; applies h2 affine (s2,b2)+relu inline.
// grid (36, 6)
// ---------------------------------------------------------------------------
__global__ __launch_bounds__(256) void msggru_k(
    const float* __restrict__ xp, const float* __restrict__ xh,
    const float* __restrict__ h2, const float* __restrict__ accfh,
    const float* __restrict__ s2, const float* __restrict__ b2g,
    const float* __restrict__ aw, const float* __restrict__ ab,
    const float* __restrict__ bw, const float* __restrict__ bb,
    const float* __restrict__ w1, const float* __restrict__ s1,
    const float* __restrict__ b1, const float* __restrict__ w2,
    const float* __restrict__ b2, const float* __restrict__ sfh,
    const float* __restrict__ bfh,
    const float* __restrict__ wih1, const float* __restrict__ bih1,
    const float* __restrict__ bhh1, const float* __restrict__ wih2,
    const float* __restrict__ bih2, const float* __restrict__ bhh2,
    float* __restrict__ out_m, float* __restrict__ out_x) {
  const int j = blockIdx.y;
  const int p = blockIdx.x * 256 + threadIdx.x;
  float xj[10];
#pragma unroll
  for (int c = 0; c < 10; ++c) xj[c] = xp[(j * 10 + c) * 9216 + p];
  float xpp[10];
  int ne = d_ne[j];
  for (int ei = 0; ei < ne; ++ei) {
    int e = d_inc[j][ei];
    int a2 = d_esrc[e];
    float sA = ab[e];
#pragma unroll
    for (int c = 0; c < 10; ++c)
      sA = fmaf(xp[(a2 * 10 + c) * 9216 + p], aw[e * 10 + c], sA);
    float sB = bb[e];
#pragma unroll
    for (int c = 0; c < 10; ++c) sB = fmaf(xj[c], bw[e * 10 + c], sB);
    float f = (1.f - sigm(sA)) * sigm(sB);
#pragma unroll
    for (int c = 0; c < 10; ++c) {
      float raw = h2[(e * 10 + c) * 9216 + p];
      float hv = fmaxf(fmaf(s2[e * 10 + c], raw, b2g[e * 10 + c]), 0.f);
      float mm = f * hv;
      xpp[c] = (ei == 0) ? mm : fmaxf(xpp[c], mm);
    }
  }
  const float* hf = xh + ((j < 4) ? 0 : 1) * 10 * 9216;
  float cat[20];
#pragma unroll
  for (int c = 0; c < 10; ++c) cat[c] = hf[c * 9216 + p];
#pragma unroll
  for (int c = 0; c < 10; ++c) cat[10 + c] = xj[c];
  float at = b2[j];
#pragma unroll
  for (int oc = 0; oc < 20; ++oc) {
    float t = 0.f;
#pragma unroll
    for (int c = 0; c < 20; ++c)
      t = fmaf(cat[c], w1[(j * 20 + oc) * 20 + c], t);
    float av = fmaxf(s1[j * 20 + oc] * t + b1[j * 20 + oc], 0.f);
    at = fmaf(av, w2[j * 20 + oc], at);
  }
  at = sigm(at);
  float msg[10];
#pragma unroll
  for (int c = 0; c < 10; ++c) {
    float xhp = fmaxf(sfh[j * 10 + c] * (at * accfh[(j * 10 + c) * 9216 + p]) +
                          bfh[j * 10 + c], 0.f);
    msg[c] = xpp[c] + xhp;
    out_m[(j * 10 + c) * 9216 + p] = msg[c];
  }
  float gi[30];
#pragma unroll
  for (int r = 0; r < 30; ++r) gi[r] = bih1[j * 30 + r];
#pragma unroll
  for (int c = 0; c < 10; ++c) {
    float v = xj[c];
#pragma unroll
    for (int r = 0; r < 30; ++r)
      gi[r] = fmaf(v, wih1[(j * 30 + r) * 20 + c], gi[r]);
  }
#pragma unroll
  for (int c = 0; c < 10; ++c) {
    float v = msg[c];
#pragma unroll
    for (int r = 0; r < 30; ++r)
      gi[r] = fmaf(v, wih1[(j * 30 + r) * 20 + 10 + c], gi[r]);
  }
  float h1v[10];
#pragma unroll
  for (int c = 0; c < 10; ++c) {
    float r = sigm(gi[c] + bhh1[j * 30 + c]);
    float z = sigm(gi[10 + c] + bhh1[j * 30 + 10 + c]);
    float n = tanhf(gi[20 + c] + r * bhh1[j * 30 + 20 + c]);
    h1v[c] = (1.f - z) * n;
  }
  float g2v[30];
#pragma unroll
  for (int r = 0; r < 30; ++r) g2v[r] = bih2[j * 30 + r];
#pragma unroll
  for (int c = 0; c < 10; ++c) {
    float v = h1v[c];
#pragma unroll
    for (int r = 0; r < 30; ++r)
      g2v[r] = fmaf(v, wih2[(j * 30 + r) * 10 + c], g2v[r]);
  }
#pragma unroll
  for (int c = 0; c < 10; ++c) {
    float r = sigm(g2v[c] + bhh2[j * 30 + c]);
    float z = sigm(g2v[10 + c] + bhh2[j * 30 + 10 + c]);
    float n = tanhf(g2v[20 + c] + r * bhh2[j * 30 + 20 + c]);
    out_x[(j * 10 + c) * 9216 + p] = (1.f - z) * n;
  }
}

extern "C" void kernel_launch(void* const* d_in, const int* in_sizes, int n_in,
                              void* d_out, int out_size, void* d_ws, size_t ws_size,
                              hipStream_t stream) {
  const float* pfea   = (const float*)d_in[0];
  const float* xp     = (const float*)d_in[1];
  const float* xh     = (const float*)d_in[2];
  const float* dp_ow1 = (const float*)d_in[3];
  const float* dp_ob1 = (const float*)d_in[4];
  const float* dp_w1  = (const float*)d_in[5];
  const float* dp_s1  = (const float*)d_in[6];
  const float* dp_b1  = (const float*)d_in[7];
  const float* dp_ow2 = (const float*)d_in[8];
  const float* dp_ob2 = (const float*)d_in[9];
  const float* dp_w2  = (const float*)d_in[10];
  const float* dp_s2  = (const float*)d_in[11];
  const float* dp_b2  = (const float*)d_in[12];
  const float* dp_aw  = (const float*)d_in[13];
  const float* dp_ab  = (const float*)d_in[14];
  const float* dp_bw  = (const float*)d_in[15];
  const float* dp_bb  = (const float*)d_in[16];
  const float* dc_w1  = (const float*)d_in[17];
  const float* dc_s1  = (const float*)d_in[18];
  const float* dc_b1  = (const float*)d_in[19];
  const float* dc_w2  = (const float*)d_in[20];
  const float* dc_b2  = (const float*)d_in[21];
  const float* dc_wfh = (const float*)d_in[22];
  const float* dc_sfh = (const float*)d_in[23];
  const float* dc_bfh = (const float*)d_in[24];
  const float* g_wih1 = (const float*)d_in[25];
  const float* g_bih1 = (const float*)d_in[26];
  const float* g_bhh1 = (const float*)d_in[28];
  const float* g_wih2 = (const float*)d_in[29];
  const float* g_bih2 = (const float*)d_in[30];
  const float* g_bhh2 = (const float*)d_in[32];

  float* ws = (float*)d_ws;
  unsigned short* aw1 = (unsigned short*)ws;   // phase 1 (1,361,920 f)
  float* accfh = ws;                           // phase 2
  float* h2    = ws + 552960;
  float* wf2 = ws + 1474560;    // 48600  [e][C][9][OC]
  float* wm1 = wf2 + 48600;     // 478800 [e][9][C][OC]
  float* wm2 = wm1 + 478800;    // 18000  [e][9][C][OC]
  float* o1  = wm2 + 18000;     // 2488320 (o2 aliases after dfmain1)
  float* o2  = o1;
  float* h1a = o1 + 2488320;    // 1843200 (contiguous after o1)
  // total: 6,351,480 floats = 25.4 MB

  float* out_x = (float*)d_out;        // xp_out: 6*10*9216
  float* out_m = out_x + 552960;       // msgs:   6*10*9216

  // One merged prep launch (wm1 | wf2 | wm2 | aw1)
  prep_all_k<<<dim3(2797), 256, 0, stream>>>(dp_w1, wm1, dp_ow2, wf2,
                                             dp_w2, wm2, dp_ow1, aw1);

  // o1 and h1a are contiguous: zero both in one memset (bias folded into
  // offconv1 epilogue at z==0).
  hipMemsetAsync(o1, 0, (2488320 + 1843200) * sizeof(float), stream);

  dim3 blk(256);
  offconv1_mfma_k<<<dim3(10, 36, 4), blk, 0, stream>>>(pfea, xp, aw1, dp_ob1, o1);
  dfmain1_k<<<dim3(10, 36, 8), blk, 0, stream>>>(pfea, xp, o1, wm1, h1a);

  init2_k<<<dim3(13320), 256, 0, stream>>>(dp_ob2, o2, h2);
  offconv2_k<<<dim3(10, 36, 2), blk, 0, stream>>>(h1a, wf2, dp_s1, dp_b1, o2);
  dfmain2_k<<<dim3(10, 36, 2), blk, 0, stream>>>(h1a, o2, wm2, dp_s1, dp_b1, h2);

  hipMemsetAsync(accfh, 0, 552960 * sizeof(float), stream);
  conv_fh_k<<<dim3(36, 6, 4), blk, 0, stream>>>(pfea, dc_wfh, accfh);

  msggru_k<<<dim3(36, 6), blk, 0, stream>>>(
      xp, xh, h2, accfh, dp_s2, dp_b2, dp_aw, dp_ab, dp_bw, dp_bb,
      dc_w1, dc_s1, dc_b1, dc_w2, dc_b2, dc_sfh, dc_bfh,
      g_wih1, g_bih1, g_bhh1, g_wih2, g_bih2, g_bhh2, out_m, out_x);
}

// Round 9
// 520.028 us; speedup vs baseline: 1.3955x; 1.1882x over previous
//
#include <hip/hip_runtime.h>
#include <hip/hip_bf16.h>

#define DEV static __device__ __forceinline__

DEV float sigm(float x) { return 1.f / (1.f + __expf(-x)); }

typedef __attribute__((ext_vector_type(8))) short s8;       // 8 bf16 (4 VGPRs)
typedef __attribute__((ext_vector_type(4))) float f4;       // 4 fp32 acc
typedef _Float16 h4 __attribute__((ext_vector_type(4)));    // 4 fp16 (8B)

DEV unsigned short f2bf(float f) {  // RNE float->bf16 bits (finite inputs)
  unsigned u = __float_as_uint(f);
  return (unsigned short)((u + 0x7FFFu + ((u >> 16) & 1u)) >> 16);
}
DEV float bf2f(unsigned short h) { return __uint_as_float(((unsigned)h) << 16); }

// Edge tables from ADJ nonzeros: (src, dst) pairs in np.nonzero order
__constant__ int d_esrc[10] = {0,1,1,1,2,2,3,4,4,5};
__constant__ int d_inc[6][3] = {{1,-1,-1},{0,4,7},{2,6,-1},{5,-1,-1},{3,9,-1},{8,-1,-1}};
__constant__ int d_ne[6] = {1,3,2,1,2,1};

// Deformable tile geometry (offconv2/dfmain2): 32x8 px, halo 4, stride 41.
#define TW 32
#define TH 8
#define SW 41
#define SDC 40
#define SH 16
#define SN 656

// ---------------------------------------------------------------------------
// Merged weight prep.
//  wf2: dp_ow2 [e][27][20][3][3] -> [e][C][9][27]   (offconv2 window weights)
//  wm2: dp_w2  [e][10][20][3][3] -> [e][9][C][10]   (dfmain2 einsum weights)
//  aw1: bf16 hi/lo A-frags for offconv1 MFMA
//  awY: bf16 hi/lo A-frags for the Y-GEMM (dfconv1 main weights)
// Block ranges: [0,190) wf2 | [190,261) wm2 | [261,926) aw1 | [926,1196) awY
// ---------------------------------------------------------------------------
DEV void prep_w_body(const float* src, float* dst, int OC, int C,
                     int tap_major, int total, int i) {
  if (i >= total) return;
  int t = i % 9; int n = i / 9;
  int c = n % C; n /= C;
  int oc = n % OC; int e = n / OC;
  float v = src[i];
  int inner = tap_major ? (t * C + c) : (c * 9 + t);
  dst[(e * C * 9 + inner) * OC + oc] = v;
}

__global__ void prep_all_k(const float* __restrict__ dp_ow2, float* __restrict__ wf2,
                           const float* __restrict__ dp_w2, float* __restrict__ wm2,
                           const float* __restrict__ dp_ow1,
                           unsigned short* __restrict__ aw1,
                           const float* __restrict__ dp_w1,
                           unsigned short* __restrict__ awY) {
  int b = blockIdx.x;
  if (b < 190) {
    prep_w_body(dp_ow2, wf2, 27, 20, 0, 48600, b * 256 + threadIdx.x);
  } else if (b < 261) {
    prep_w_body(dp_w2, wm2, 10, 20, 1, 18000, (b - 190) * 256 + threadIdx.x);
  } else if (b < 926) {
    int i = (b - 261) * 256 + threadIdx.x;        // 170240 total
    if (i >= 170240) return;
    int lane = i & 63;
    int tile = (i >> 6) & 1;
    int cg = (i >> 7) % 133;
    int e = (i >> 7) / 133;
    int m = lane & 15, quad = lane >> 4;
    int oc = tile * 16 + m;
    unsigned short* out = aw1 + ((e * 133 + cg) * 2 + tile) * 1024 + lane * 16;
#pragma unroll
    for (int j = 0; j < 8; ++j) {
      int k = quad * 8 + j;
      int csel = k >> 4, t = k & 15;
      int c = 2 * cg + csel;
      float w = (oc < 27 && t < 9) ? dp_ow1[((e * 27 + oc) * 266 + c) * 9 + t] : 0.f;
      unsigned short h = f2bf(w);
      out[j] = h;
      out[8 + j] = f2bf(w - bf2f(h));
    }
  } else {
    int i = (b - 926) * 256 + threadIdx.x;        // 69120 total
    int lane = i & 63;
    int grp = i >> 6;                              // 1080 = 10e * 9ks * 12mt
    int mt = grp % 12;
    int ks = (grp / 12) % 9;
    int e = grp / 108;
    int m16 = lane & 15, quad = lane >> 4;
    int M = mt * 16 + m16;                         // 0..191 (tap*20+oc)
    unsigned short* out = awY + ((e * 9 + ks) * 12 + mt) * 1024 + lane * 16;
#pragma unroll
    for (int j = 0; j < 8; ++j) {
      int c = ks * 32 + quad * 8 + j;              // channel
      float w = 0.f;
      if (M < 180 && c < 266) {
        int tap = M / 20, oc = M % 20;
        w = dp_w1[((e * 20 + oc) * 266 + c) * 9 + tap];
      }
      unsigned short h = f2bf(w);
      out[j] = h;
      out[8 + j] = f2bf(w - bf2f(h));
    }
  }
}

// o2 = bias broadcast; h2 = 0.
__global__ void init2_k(const float* __restrict__ ob, float* __restrict__ o2,
                        float* __restrict__ h2) {
  int i = blockIdx.x * 256 + threadIdx.x;
  if (i < 2488320) o2[i] = ob[i / 9216];
  else h2[i - 2488320] = 0.f;
}

// Staging address for halo-4 window (clamped), element i of 16x41.
DEV int stage_goff(int i, int ty0, int tx0) {
  int r = i / SW, cl = i % SW;
  cl = min(cl, SDC - 1);
  int gy = min(max(ty0 - 4 + r, 0), 95);
  int gx = min(max(tx0 - 4 + cl, 0), 95);
  return gy * 96 + gx;
}

// ---------------------------------------------------------------------------
// Offset conv 1 via MFMA (r8, unchanged). grid (10, 36, 4). o1 zero-inited;
// bias added by z==0 block.
// ---------------------------------------------------------------------------
#define OSWB 35
#define OSEC 384
#define OBUF 896

__global__ __launch_bounds__(256) void offconv1_mfma_k(
    const float* __restrict__ pfea, const float* __restrict__ xp,
    const unsigned short* __restrict__ aw, const float* __restrict__ ob,
    float* __restrict__ o1) {
  __shared__ float sbuf[2][OBUF];
  const int e = blockIdx.x, m = blockIdx.y, z = blockIdx.z;
  const int tid = threadIdx.x;
  const int lane = tid & 63, wv = tid >> 6;
  const int quad = lane >> 4, n16 = lane & 15;
  const int tx0 = (m % 3) * 32, ty0 = (m / 3) * 8;
  const float* xpe = xp + d_esrc[e] * 10 * 9216;
  const int cg_lo = (z * 133) / 4, cg_hi = ((z + 1) * 133) / 4;

  int g[3]; bool oks[3];
#pragma unroll
  for (int i = 0; i < 3; ++i) {
    int s = tid + i * 256;
    int sec = s / OSEC, off = s - sec * OSEC;
    int r = off / OSWB, cl = off % OSWB;
    int gy = ty0 - 1 + r, gx = tx0 - 1 + cl;
    bool ok = (off < 350) && (cl < 34) && (gy >= 0) && (gy < 96) &&
              (gx >= 0) && (gx < 96);
    oks[i] = ok;
    g[i] = sec * 9216 + (ok ? (gy * 96 + gx) : 0);
  }
  if (tid < OBUF - 768) { sbuf[0][768 + tid] = 0.f; sbuf[1][768 + tid] = 0.f; }

  const int tbase = (quad & 1) * 8;
  const int csel = quad >> 1;
  int bdelta[8];
#pragma unroll
  for (int j = 0; j < 8; ++j) {
    int t = tbase + j;
    int dy = t / 3 - 1, dx = t % 3 - 1;
    bdelta[j] = csel * OSEC + dy * OSWB + dx;
  }
  int bidx[4];
#pragma unroll
  for (int nt = 0; nt < 4; ++nt) {
    int r = 2 * wv + (nt >> 1), h = nt & 1;
    bidx[nt] = (r + 1) * OSWB + (h * 16 + n16 + 1);
  }

  f4 acc[4][2] = {};

  int c0 = 2 * cg_lo;
  const float* base = (c0 < 256) ? (pfea + c0 * 9216) : (xpe + (c0 - 256) * 9216);
  float pv0 = oks[0] ? base[g[0]] : 0.f;
  float pv1 = oks[1] ? base[g[1]] : 0.f;
  float pv2 = oks[2] ? base[g[2]] : 0.f;

  int bsel = 0;
  for (int cg = cg_lo; cg < cg_hi; ++cg, bsel ^= 1) {
    float* buf = sbuf[bsel];
    buf[tid] = pv0; buf[tid + 256] = pv1; buf[tid + 512] = pv2;
    if (cg + 1 < cg_hi) {
      int c0n = 2 * (cg + 1);
      const float* nb = (c0n < 256) ? (pfea + c0n * 9216)
                                    : (xpe + (c0n - 256) * 9216);
      pv0 = oks[0] ? nb[g[0]] : 0.f;
      pv1 = oks[1] ? nb[g[1]] : 0.f;
      pv2 = oks[2] ? nb[g[2]] : 0.f;
    }
    const unsigned short* apc = aw + (e * 133 + cg) * 2048 + lane * 16;
    s8 Ah0 = *(const s8*)(apc);
    s8 Al0 = *(const s8*)(apc + 8);
    s8 Ah1 = *(const s8*)(apc + 1024);
    s8 Al1 = *(const s8*)(apc + 1024 + 8);
    __syncthreads();
#pragma unroll
    for (int nt = 0; nt < 4; ++nt) {
      union { s8 v; unsigned short u[8]; } Bh, Bl;
#pragma unroll
      for (int j = 0; j < 8; ++j) {
        float v = buf[bidx[nt] + bdelta[j]];
        unsigned short h = f2bf(v);
        Bh.u[j] = h;
        Bl.u[j] = f2bf(v - bf2f(h));
      }
      acc[nt][0] = __builtin_amdgcn_mfma_f32_16x16x32_bf16(Ah0, Bh.v, acc[nt][0], 0, 0, 0);
      acc[nt][0] = __builtin_amdgcn_mfma_f32_16x16x32_bf16(Ah0, Bl.v, acc[nt][0], 0, 0, 0);
      acc[nt][0] = __builtin_amdgcn_mfma_f32_16x16x32_bf16(Al0, Bh.v, acc[nt][0], 0, 0, 0);
      acc[nt][1] = __builtin_amdgcn_mfma_f32_16x16x32_bf16(Ah1, Bh.v, acc[nt][1], 0, 0, 0);
      acc[nt][1] = __builtin_amdgcn_mfma_f32_16x16x32_bf16(Ah1, Bl.v, acc[nt][1], 0, 0, 0);
      acc[nt][1] = __builtin_amdgcn_mfma_f32_16x16x32_bf16(Al1, Bh.v, acc[nt][1], 0, 0, 0);
    }
  }
#pragma unroll
  for (int nt = 0; nt < 4; ++nt) {
    int y = ty0 + 2 * wv + (nt >> 1);
    int xx = tx0 + (nt & 1) * 16 + n16;
    int p = y * 96 + xx;
#pragma unroll
    for (int t2 = 0; t2 < 2; ++t2)
#pragma unroll
      for (int r = 0; r < 4; ++r) {
        int oc = t2 * 16 + quad * 4 + r;
        if (oc < 27) {
          float v = acc[nt][t2][r];
          if (z == 0) v += ob[e * 27 + oc];
          atomicAdd(&o1[(e * 27 + oc) * 9216 + p], v);
        }
      }
  }
}

// ---------------------------------------------------------------------------
// Y-GEMM: Y[e][tap][oc][q... layout [e][tap][q][oc]] = sum_c X[c][q]*W1[...]
// M=180(pad192), K=266(pad288), N=9216 per edge. bf16 hi/lo (3 MFMA).
// No LDS, B-frags read straight from global. Output fp16.
// grid (36 pxg, 4 mgrp, 10 e), 256 thr.
// ---------------------------------------------------------------------------
__global__ __launch_bounds__(256) void ygemm_k(
    const float* __restrict__ pfea, const float* __restrict__ xp,
    const unsigned short* __restrict__ awY, unsigned short* __restrict__ Yg) {
  const int pxg = blockIdx.x, z = blockIdx.y, e = blockIdx.z;
  const int tid = threadIdx.x;
  const int lane = tid & 63, wv = tid >> 6;
  const int quad = lane >> 4, n16 = lane & 15;
  const float* xpe = xp + d_esrc[e] * 10 * 9216;
  const int qbase = pxg * 256 + wv * 64;

  f4 acc[4][3] = {};

  for (int ks = 0; ks < 9; ++ks) {
    const int cq = ks * 32 + quad * 8;
    s8 Ah[3], Al[3];
#pragma unroll
    for (int mt = 0; mt < 3; ++mt) {
      const unsigned short* ap =
          awY + ((e * 9 + ks) * 12 + z * 3 + mt) * 1024 + lane * 16;
      Ah[mt] = *(const s8*)ap;
      Al[mt] = *(const s8*)(ap + 8);
    }
#pragma unroll
    for (int nt = 0; nt < 4; ++nt) {
      const int q = qbase + nt * 16 + n16;
      union { s8 v; unsigned short u[8]; } Bh, Bl;
#pragma unroll
      for (int j = 0; j < 8; ++j) {
        int c = cq + j;
        float v = 0.f;
        if (c < 256) v = pfea[c * 9216 + q];
        else if (c < 266) v = xpe[(c - 256) * 9216 + q];
        unsigned short h = f2bf(v);
        Bh.u[j] = h;
        Bl.u[j] = f2bf(v - bf2f(h));
      }
#pragma unroll
      for (int mt = 0; mt < 3; ++mt) {
        acc[nt][mt] = __builtin_amdgcn_mfma_f32_16x16x32_bf16(Ah[mt], Bh.v, acc[nt][mt], 0, 0, 0);
        acc[nt][mt] = __builtin_amdgcn_mfma_f32_16x16x32_bf16(Ah[mt], Bl.v, acc[nt][mt], 0, 0, 0);
        acc[nt][mt] = __builtin_amdgcn_mfma_f32_16x16x32_bf16(Al[mt], Bh.v, acc[nt][mt], 0, 0, 0);
      }
    }
  }
  // Epilogue: D[m=quad*4+r][n=n16]; m_glob = z*48+mt*16+quad*4+r = tap*20+oc
  _Float16* Yh = (_Float16*)Yg;
#pragma unroll
  for (int nt = 0; nt < 4; ++nt) {
    const int q = qbase + nt * 16 + n16;
#pragma unroll
    for (int mt = 0; mt < 3; ++mt)
#pragma unroll
      for (int r = 0; r < 4; ++r) {
        int m = z * 48 + mt * 16 + quad * 4 + r;
        if (m < 180) {
          int tap = m / 20, oc = m - tap * 20;
          Yh[((e * 9 + tap) * 9216 + q) * 20 + oc] = (_Float16)acc[nt][mt][r];
        }
      }
  }
}

// ---------------------------------------------------------------------------
// Deformable gather: h1a[e][oc][p] += sum_k bilinear(Y[e][k][oc])(pos_k)
// with per-corner validity mask * sigmoid gate. Offsets from o1.
// grid (36 px, 3 tapgrp, 10 e), 256 thr, no LDS, no slow path.
// ---------------------------------------------------------------------------
__global__ __launch_bounds__(256) void dfgather_k(
    const float* __restrict__ o1, const unsigned short* __restrict__ Yg,
    float* __restrict__ h1a) {
  const int p = blockIdx.x * 256 + threadIdx.x;
  const int zt = blockIdx.y, e = blockIdx.z;
  const int y = p / 96, x = p % 96;
  float acc[20];
#pragma unroll
  for (int oc = 0; oc < 20; ++oc) acc[oc] = 0.f;

  const _Float16* Yh = (const _Float16*)Yg;
#pragma unroll
  for (int t = 0; t < 3; ++t) {
    const int k = zt * 3 + t;
    float offy = o1[(e * 27 + 2 * k) * 9216 + p];
    float offx = o1[(e * 27 + 2 * k + 1) * 9216 + p];
    float mk = sigm(o1[(e * 27 + 18 + k) * 9216 + p]);
    float py = (float)(y + k / 3 - 1) + offy;
    float px = (float)(x + k % 3 - 1) + offx;
    float fy = floorf(py), fx = floorf(px);
    float wy = py - fy, wx = px - fx;
    int iy = (int)fy, ix = (int)fx;
    const _Float16* yk = Yh + (e * 9 + k) * 9216 * 20;
#pragma unroll
    for (int dy = 0; dy < 2; ++dy)
#pragma unroll
      for (int dx = 0; dx < 2; ++dx) {
        bool ok = (iy + dy >= 0) && (iy + dy < 96) && (ix + dx >= 0) && (ix + dx < 96);
        float cwc = (ok ? mk : 0.f) * (dy ? wy : (1.f - wy)) * (dx ? wx : (1.f - wx));
        int yc = min(max(iy + dy, 0), 95), xc = min(max(ix + dx, 0), 95);
        const h4* yp = (const h4*)(yk + (yc * 96 + xc) * 20);
#pragma unroll
        for (int g = 0; g < 5; ++g) {
          h4 v = yp[g];
#pragma unroll
          for (int u = 0; u < 4; ++u)
            acc[g * 4 + u] = fmaf(cwc, (float)v[u], acc[g * 4 + u]);
        }
      }
  }
#pragma unroll
  for (int oc = 0; oc < 20; ++oc)
    atomicAdd(&h1a[(e * 20 + oc) * 9216 + p], acc[oc]);
}

// ---------------------------------------------------------------------------
// Offset conv 2 (r8, unchanged): pair-staged, affine+relu at staging,
// split z=2, atomic into bias-inited o2. grid (10, 36, 2)
// ---------------------------------------------------------------------------
__global__ __launch_bounds__(256) void offconv2_k(
    const float* __restrict__ h1a, const float* __restrict__ wf,
    const float* __restrict__ s1, const float* __restrict__ b1,
    float* __restrict__ o2) {
  __shared__ float sbuf[2][2 * SN];
  const int e = blockIdx.x, m = blockIdx.y;
  const int c_lo = blockIdx.z * 10;
  const int tid = threadIdx.x;
  const int tx = tid % TW, ty = tid / TW;
  const int tx0 = (m % 3) * TW, ty0 = (m / 3) * TH;
  const int y = ty0 + ty, x = tx0 + tx;
  const int p = y * 96 + x;
  const float* base = h1a + e * 20 * 9216;

  const int g0 = stage_goff(tid, ty0, tx0);
  const int g1 = stage_goff(tid + 256, ty0, tx0);
  const int g2 = (tid < SN - 512) ? stage_goff(tid + 512, ty0, tx0) : 0;

  float vmask[9];
#pragma unroll
  for (int t = 0; t < 9; ++t) {
    int yy = y + t / 3 - 1, xx = x + t % 3 - 1;
    vmask[t] = ((yy >= 0) && (yy < 96) && (xx >= 0) && (xx < 96)) ? 1.f : 0.f;
  }
  const int vbase = (ty + 3) * SW + (tx + 3);

  float acc[27];
#pragma unroll
  for (int oc = 0; oc < 27; ++oc) acc[oc] = 0.f;

  const float* ia = base + c_lo * 9216;
  const float* ib = ia + 9216;
  float pa0 = ia[g0], pa1 = ia[g1], pa2 = (tid < SN - 512) ? ia[g2] : 0.f;
  float pb0 = ib[g0], pb1 = ib[g1], pb2 = (tid < SN - 512) ? ib[g2] : 0.f;

  int bsel = 0;
  for (int c = c_lo; c < c_lo + 10; c += 2, bsel ^= 1) {
    float sa = s1[e * 20 + c], ba = b1[e * 20 + c];
    float sb = s1[e * 20 + c + 1], bb2 = b1[e * 20 + c + 1];
    float* buf = sbuf[bsel];
    buf[tid] = fmaxf(fmaf(sa, pa0, ba), 0.f);
    buf[tid + 256] = fmaxf(fmaf(sa, pa1, ba), 0.f);
    if (tid < SN - 512) buf[tid + 512] = fmaxf(fmaf(sa, pa2, ba), 0.f);
    buf[SN + tid] = fmaxf(fmaf(sb, pb0, bb2), 0.f);
    buf[SN + tid + 256] = fmaxf(fmaf(sb, pb1, bb2), 0.f);
    if (tid < SN - 512) buf[SN + tid + 512] = fmaxf(fmaf(sb, pb2, bb2), 0.f);
    if (c + 2 < c_lo + 10) {
      const float* na = base + (c + 2) * 9216;
      const float* nb = base + (c + 3) * 9216;
      pa0 = na[g0]; pa1 = na[g1]; if (tid < SN - 512) pa2 = na[g2];
      pb0 = nb[g0]; pb1 = nb[g1]; if (tid < SN - 512) pb2 = nb[g2];
    }
    __syncthreads();
#pragma unroll
    for (int cc = 0; cc < 2; ++cc) {
      const float* wc = wf + (e * 20 + c + cc) * 243;
      const float* bp = buf + cc * SN;
#pragma unroll
      for (int t = 0; t < 9; ++t) {
        float v = vmask[t] * bp[vbase + (t / 3) * SW + (t % 3)];
#pragma unroll
        for (int oc = 0; oc < 27; ++oc)
          acc[oc] = fmaf(v, wc[t * 27 + oc], acc[oc]);
      }
    }
  }
#pragma unroll
  for (int oc = 0; oc < 27; ++oc)
    atomicAdd(&o2[(e * 27 + oc) * 9216 + p], acc[oc]);
}

// ---------------------------------------------------------------------------
// Deformable main conv 2 (r8, unchanged): pair staging (affine+relu fused),
// split z=2, atomic raw into zero-inited h2. grid (10, 36, 2)
// ---------------------------------------------------------------------------
__global__ __launch_bounds__(256) void dfmain2_k(
    const float* __restrict__ h1a, const float* __restrict__ o2,
    const float* __restrict__ wm, const float* __restrict__ s1,
    const float* __restrict__ b1, float* __restrict__ hout) {
  __shared__ float sbuf[2][2 * SN];
  const int e = blockIdx.x, m = blockIdx.y;
  const int c_lo = blockIdx.z * 10;
  const int tid = threadIdx.x;
  const int tx = tid % TW, ty = tid / TW;
  const int tx0 = (m % 3) * TW, ty0 = (m / 3) * TH;
  const int y = ty0 + ty, x = tx0 + tx;
  const int p = y * 96 + x;
  const float* base = h1a + e * 20 * 9216;

  const int g0 = stage_goff(tid, ty0, tx0);
  const int g1 = stage_goff(tid + 256, ty0, tx0);
  const int g2 = (tid < SN - 512) ? stage_goff(tid + 512, ty0, tx0) : 0;

  int iob[9]; float cw[9][4];
  bool oob = false;
#pragma unroll
  for (int k = 0; k < 9; ++k) {
    float offy = o2[(e * 27 + 2 * k) * 9216 + p];
    float offx = o2[(e * 27 + 2 * k + 1) * 9216 + p];
    float mk = sigm(o2[(e * 27 + 18 + k) * 9216 + p]);
    float py = (float)(y + k / 3 - 1) + offy;
    float px = (float)(x + k % 3 - 1) + offx;
    float fy = floorf(py), fx = floorf(px);
    float wy = py - fy, wx = px - fx;
    int iy = (int)fy, ix = (int)fx;
#pragma unroll
    for (int dy = 0; dy < 2; ++dy)
#pragma unroll
      for (int dx = 0; dx < 2; ++dx) {
        bool ok = (iy + dy >= 0) && (iy + dy < 96) && (ix + dx >= 0) && (ix + dx < 96);
        cw[k][dy * 2 + dx] =
            (ok ? mk : 0.f) * (dy ? wy : (1.f - wy)) * (dx ? wx : (1.f - wx));
      }
    int ir = iy - (ty0 - 4), ic = ix - (tx0 - 4);
    oob |= ((unsigned)ir > (unsigned)(SH - 2)) | ((unsigned)ic > (unsigned)(SDC - 2));
    iob[k] = min(max(ir, 0), SH - 2) * SW + min(max(ic, 0), SDC - 2);
  }

  float acc[10];
#pragma unroll
  for (int oc = 0; oc < 10; ++oc) acc[oc] = 0.f;

  const float* ia = base + c_lo * 9216;
  const float* ib = ia + 9216;
  float pa0 = ia[g0], pa1 = ia[g1], pa2 = (tid < SN - 512) ? ia[g2] : 0.f;
  float pb0 = ib[g0], pb1 = ib[g1], pb2 = (tid < SN - 512) ? ib[g2] : 0.f;

  int bsel = 0;
  for (int c = c_lo; c < c_lo + 10; c += 2, bsel ^= 1) {
    float sa = s1[e * 20 + c], ba = b1[e * 20 + c];
    float sb = s1[e * 20 + c + 1], bb2 = b1[e * 20 + c + 1];
    float* buf = sbuf[bsel];
    buf[tid] = fmaxf(fmaf(sa, pa0, ba), 0.f);
    buf[tid + 256] = fmaxf(fmaf(sa, pa1, ba), 0.f);
    if (tid < SN - 512) buf[tid + 512] = fmaxf(fmaf(sa, pa2, ba), 0.f);
    buf[SN + tid] = fmaxf(fmaf(sb, pb0, bb2), 0.f);
    buf[SN + tid + 256] = fmaxf(fmaf(sb, pb1, bb2), 0.f);
    if (tid < SN - 512) buf[SN + tid + 512] = fmaxf(fmaf(sb, pb2, bb2), 0.f);
    if (c + 2 < c_lo + 10) {
      const float* na = base + (c + 2) * 9216;
      const float* nb = base + (c + 3) * 9216;
      pa0 = na[g0]; pa1 = na[g1]; if (tid < SN - 512) pa2 = na[g2];
      pb0 = nb[g0]; pb1 = nb[g1]; if (tid < SN - 512) pb2 = nb[g2];
    }
    __syncthreads();
#pragma unroll
    for (int cc = 0; cc < 2; ++cc) {
      const float* bp = buf + cc * SN;
#pragma unroll
      for (int k = 0; k < 9; ++k) {
        const float* bk = bp + iob[k];
        float sv = cw[k][0] * bk[0] + cw[k][1] * bk[1] +
                   cw[k][2] * bk[SW] + cw[k][3] * bk[SW + 1];
        const float* wc = wm + ((e * 9 + k) * 20 + c + cc) * 10;
#pragma unroll
        for (int oc = 0; oc < 10; ++oc) acc[oc] = fmaf(sv, wc[oc], acc[oc]);
      }
    }
  }

  if (oob) {
#pragma unroll
    for (int oc = 0; oc < 10; ++oc) acc[oc] = 0.f;
    for (int k = 0; k < 9; ++k) {
      float offy = o2[(e * 27 + 2 * k) * 9216 + p];
      float offx = o2[(e * 27 + 2 * k + 1) * 9216 + p];
      float mk = sigm(o2[(e * 27 + 18 + k) * 9216 + p]);
      float py = (float)(y + k / 3 - 1) + offy;
      float px = (float)(x + k % 3 - 1) + offx;
      float fy = floorf(py), fx = floorf(px);
      float wy = py - fy, wx = px - fx;
      int iy = (int)fy, ix = (int)fx;
      int go[4]; float gw[4];
#pragma unroll
      for (int dy = 0; dy < 2; ++dy)
#pragma unroll
        for (int dx = 0; dx < 2; ++dx) {
          bool ok = (iy + dy >= 0) && (iy + dy < 96) && (ix + dx >= 0) && (ix + dx < 96);
          int yc = min(max(iy + dy, 0), 95), xc = min(max(ix + dx, 0), 95);
          go[dy * 2 + dx] = yc * 96 + xc;
          gw[dy * 2 + dx] =
              (ok ? mk : 0.f) * (dy ? wy : (1.f - wy)) * (dx ? wx : (1.f - wx));
        }
      for (int c = c_lo; c < c_lo + 10; ++c) {
        float sc = s1[e * 20 + c], bc = b1[e * 20 + c];
        const float* ptr = base + c * 9216;
        float v0 = fmaxf(fmaf(sc, ptr[go[0]], bc), 0.f);
        float v1 = fmaxf(fmaf(sc, ptr[go[1]], bc), 0.f);
        float v2 = fmaxf(fmaf(sc, ptr[go[2]], bc), 0.f);
        float v3 = fmaxf(fmaf(sc, ptr[go[3]], bc), 0.f);
        float sv = gw[0] * v0 + gw[1] * v1 + gw[2] * v2 + gw[3] * v3;
        const float* wc = wm + ((e * 9 + k) * 20 + c) * 10;
#pragma unroll
        for (int oc = 0; oc < 10; ++oc) acc[oc] = fmaf(sv, wc[oc], acc[oc]);
      }
    }
  }
#pragma unroll
  for (int oc = 0; oc < 10; ++oc)
    atomicAdd(&hout[(e * 10 + oc) * 9216 + p], acc[oc]);
}

// 1x1 conv p_fea (256ch) -> accfh[j][10][9216], split-K atomic. grid (36,6,4)
__global__ __launch_bounds__(256) void conv_fh_k(
    const float* __restrict__ pfea, const float* __restrict__ wfh,
    float* __restrict__ accfh) {
  const int j = blockIdx.y;
  const int z = blockIdx.z;
  const int p = blockIdx.x * 256 + threadIdx.x;
  const int c_lo = z * 64;
  float acc[10];
#pragma unroll
  for (int c = 0; c < 10; ++c) acc[c] = 0.f;
  for (int ci = c_lo; ci < c_lo + 64; ci += 4) {
    float pv0 = pfea[ci * 9216 + p];
    float pv1 = pfea[(ci + 1) * 9216 + p];
    float pv2 = pfea[(ci + 2) * 9216 + p];
    float pv3 = pfea[(ci + 3) * 9216 + p];
#pragma unroll
    for (int c = 0; c < 10; ++c) {
      acc[c] = fmaf(pv0, wfh[(j * 10 + c) * 256 + ci], acc[c]);
      acc[c] = fmaf(pv1, wfh[(j * 10 + c) * 256 + ci + 1], acc[c]);
      acc[c] = fmaf(pv2, wfh[(j * 10 + c) * 256 + ci + 2], acc[c]);
      acc[c] = fmaf(pv3, wfh[(j * 10 + c) * 256 + ci + 3], acc[c]);
    }
  }
#pragma unroll
  for (int c = 0; c < 10; ++c)
    atomicAdd(&accfh[(j * 10 + c) * 9216 + p], acc[c]);
}

// ---------------------------------------------------------------------------
// Fused node-message + GRU stage; applies h2 affine (s2,b2)+relu inline.
// grid (36, 6)
// ---------------------------------------------------------------------------
__global__ __launch_bounds__(256) void msggru_k(
    const float* __restrict__ xp, const float* __restrict__ xh,
    const float* __restrict__ h2, const float* __restrict__ accfh,
    const float* __restrict__ s2, const float* __restrict__ b2g,
    const float* __restrict__ aw, const float* __restrict__ ab,
    const float* __restrict__ bw, const float* __restrict__ bb,
    const float* __restrict__ w1, const float* __restrict__ s1,
    const float* __restrict__ b1, const float* __restrict__ w2,
    const float* __restrict__ b2, const float* __restrict__ sfh,
    const float* __restrict__ bfh,
    const float* __restrict__ wih1, const float* __restrict__ bih1,
    const float* __restrict__ bhh1, const float* __restrict__ wih2,
    const float* __restrict__ bih2, const float* __restrict__ bhh2,
    float* __restrict__ out_m, float* __restrict__ out_x) {
  const int j = blockIdx.y;
  const int p = blockIdx.x * 256 + threadIdx.x;
  float xj[10];
#pragma unroll
  for (int c = 0; c < 10; ++c) xj[c] = xp[(j * 10 + c) * 9216 + p];
  float xpp[10];
  int ne = d_ne[j];
  for (int ei = 0; ei < ne; ++ei) {
    int e = d_inc[j][ei];
    int a2 = d_esrc[e];
    float sA = ab[e];
#pragma unroll
    for (int c = 0; c < 10; ++c)
      sA = fmaf(xp[(a2 * 10 + c) * 9216 + p], aw[e * 10 + c], sA);
    float sB = bb[e];
#pragma unroll
    for (int c = 0; c < 10; ++c) sB = fmaf(xj[c], bw[e * 10 + c], sB);
    float f = (1.f - sigm(sA)) * sigm(sB);
#pragma unroll
    for (int c = 0; c < 10; ++c) {
      float raw = h2[(e * 10 + c) * 9216 + p];
      float hv = fmaxf(fmaf(s2[e * 10 + c], raw, b2g[e * 10 + c]), 0.f);
      float mm = f * hv;
      xpp[c] = (ei == 0) ? mm : fmaxf(xpp[c], mm);
    }
  }
  const float* hf = xh + ((j < 4) ? 0 : 1) * 10 * 9216;
  float cat[20];
#pragma unroll
  for (int c = 0; c < 10; ++c) cat[c] = hf[c * 9216 + p];
#pragma unroll
  for (int c = 0; c < 10; ++c) cat[10 + c] = xj[c];
  float at = b2[j];
#pragma unroll
  for (int oc = 0; oc < 20; ++oc) {
    float t = 0.f;
#pragma unroll
    for (int c = 0; c < 20; ++c)
      t = fmaf(cat[c], w1[(j * 20 + oc) * 20 + c], t);
    float av = fmaxf(s1[j * 20 + oc] * t + b1[j * 20 + oc], 0.f);
    at = fmaf(av, w2[j * 20 + oc], at);
  }
  at = sigm(at);
  float msg[10];
#pragma unroll
  for (int c = 0; c < 10; ++c) {
    float xhp = fmaxf(sfh[j * 10 + c] * (at * accfh[(j * 10 + c) * 9216 + p]) +
                          bfh[j * 10 + c], 0.f);
    msg[c] = xpp[c] + xhp;
    out_m[(j * 10 + c) * 9216 + p] = msg[c];
  }
  float gi[30];
#pragma unroll
  for (int r = 0; r < 30; ++r) gi[r] = bih1[j * 30 + r];
#pragma unroll
  for (int c = 0; c < 10; ++c) {
    float v = xj[c];
#pragma unroll
    for (int r = 0; r < 30; ++r)
      gi[r] = fmaf(v, wih1[(j * 30 + r) * 20 + c], gi[r]);
  }
#pragma unroll
  for (int c = 0; c < 10; ++c) {
    float v = msg[c];
#pragma unroll
    for (int r = 0; r < 30; ++r)
      gi[r] = fmaf(v, wih1[(j * 30 + r) * 20 + 10 + c], gi[r]);
  }
  float h1v[10];
#pragma unroll
  for (int c = 0; c < 10; ++c) {
    float r = sigm(gi[c] + bhh1[j * 30 + c]);
    float z = sigm(gi[10 + c] + bhh1[j * 30 + 10 + c]);
    float n = tanhf(gi[20 + c] + r * bhh1[j * 30 + 20 + c]);
    h1v[c] = (1.f - z) * n;
  }
  float g2v[30];
#pragma unroll
  for (int r = 0; r < 30; ++r) g2v[r] = bih2[j * 30 + r];
#pragma unroll
  for (int c = 0; c < 10; ++c) {
    float v = h1v[c];
#pragma unroll
    for (int r = 0; r < 30; ++r)
      g2v[r] = fmaf(v, wih2[(j * 30 + r) * 10 + c], g2v[r]);
  }
#pragma unroll
  for (int c = 0; c < 10; ++c) {
    float r = sigm(g2v[c] + bhh2[j * 30 + c]);
    float z = sigm(g2v[10 + c] + bhh2[j * 30 + 10 + c]);
    float n = tanhf(g2v[20 + c] + r * bhh2[j * 30 + 20 + c]);
    out_x[(j * 10 + c) * 9216 + p] = (1.f - z) * n;
  }
}

extern "C" void kernel_launch(void* const* d_in, const int* in_sizes, int n_in,
                              void* d_out, int out_size, void* d_ws, size_t ws_size,
                              hipStream_t stream) {
  const float* pfea   = (const float*)d_in[0];
  const float* xp     = (const float*)d_in[1];
  const float* xh     = (const float*)d_in[2];
  const float* dp_ow1 = (const float*)d_in[3];
  const float* dp_ob1 = (const float*)d_in[4];
  const float* dp_w1  = (const float*)d_in[5];
  const float* dp_s1  = (const float*)d_in[6];
  const float* dp_b1  = (const float*)d_in[7];
  const float* dp_ow2 = (const float*)d_in[8];
  const float* dp_ob2 = (const float*)d_in[9];
  const float* dp_w2  = (const float*)d_in[10];
  const float* dp_s2  = (const float*)d_in[11];
  const float* dp_b2  = (const float*)d_in[12];
  const float* dp_aw  = (const float*)d_in[13];
  const float* dp_ab  = (const float*)d_in[14];
  const float* dp_bw  = (const float*)d_in[15];
  const float* dp_bb  = (const float*)d_in[16];
  const float* dc_w1  = (const float*)d_in[17];
  const float* dc_s1  = (const float*)d_in[18];
  const float* dc_b1  = (const float*)d_in[19];
  const float* dc_w2  = (const float*)d_in[20];
  const float* dc_b2  = (const float*)d_in[21];
  const float* dc_wfh = (const float*)d_in[22];
  const float* dc_sfh = (const float*)d_in[23];
  const float* dc_bfh = (const float*)d_in[24];
  const float* g_wih1 = (const float*)d_in[25];
  const float* g_bih1 = (const float*)d_in[26];
  const float* g_bhh1 = (const float*)d_in[28];
  const float* g_wih2 = (const float*)d_in[29];
  const float* g_bih2 = (const float*)d_in[30];
  const float* g_bhh2 = (const float*)d_in[32];

  float* ws = (float*)d_ws;
  // region0 [0, 1,914,880): phase1 aw1 + awY; phase2 accfh + h2
  unsigned short* aw1 = (unsigned short*)ws;               // 2,723,840 ushort
  unsigned short* awY = (unsigned short*)(ws + 1361920);   // 1,105,920 ushort
  float* accfh = ws;                                       // 552,960
  float* h2    = ws + 552960;                              // 921,600
  float* wf2 = ws + 1914880;    // 48,600
  float* wm2 = wf2 + 48600;     // 18,000
  float* o1  = wm2 + 18000;     // 2,488,320 (o2 aliases after dfgather)
  float* o2  = o1;
  float* h1a = o1 + 2488320;    // 1,843,200 (contiguous after o1)
  unsigned short* Yg = (unsigned short*)(ws + 6313000);    // 16,588,800 ushort
  // total: 14,607,400 floats = 58.4 MB

  float* out_x = (float*)d_out;        // xp_out: 6*10*9216
  float* out_m = out_x + 552960;       // msgs:   6*10*9216

  prep_all_k<<<dim3(1196), 256, 0, stream>>>(dp_ow2, wf2, dp_w2, wm2,
                                             dp_ow1, aw1, dp_w1, awY);

  // zero o1 + h1a in one memset (o1 bias folded into offconv1 z==0 epilogue)
  hipMemsetAsync(o1, 0, (2488320 + 1843200) * sizeof(float), stream);

  dim3 blk(256);
  offconv1_mfma_k<<<dim3(10, 36, 4), blk, 0, stream>>>(pfea, xp, aw1, dp_ob1, o1);
  ygemm_k<<<dim3(36, 4, 10), blk, 0, stream>>>(pfea, xp, awY, Yg);
  dfgather_k<<<dim3(36, 3, 10), blk, 0, stream>>>(o1, Yg, h1a);

  init2_k<<<dim3(13320), 256, 0, stream>>>(dp_ob2, o2, h2);
  offconv2_k<<<dim3(10, 36, 2), blk, 0, stream>>>(h1a, wf2, dp_s1, dp_b1, o2);
  dfmain2_k<<<dim3(10, 36, 2), blk, 0, stream>>>(h1a, o2, wm2, dp_s1, dp_b1, h2);

  hipMemsetAsync(accfh, 0, 552960 * sizeof(float), stream);
  conv_fh_k<<<dim3(36, 6, 4), blk, 0, stream>>>(pfea, dc_wfh, accfh);

  msggru_k<<<dim3(36, 6), blk, 0, stream>>>(
      xp, xh, h2, accfh, dp_s2, dp_b2, dp_aw, dp_ab, dp_bw, dp_bb,
      dc_w1, dc_s1, dc_b1, dc_w2, dc_b2, dc_sfh, dc_bfh,
      g_wih1, g_bih1, g_bhh1, g_wih2, g_bih2, g_bhh2, out_m, out_x);
}

// Round 10
// 417.646 us; speedup vs baseline: 1.7376x; 1.2451x over previous
//
#include <hip/hip_runtime.h>
#include <hip/hip_bf16.h>

#define DEV static __device__ __forceinline__

DEV float sigm(float x) { return 1.f / (1.f + __expf(-x)); }

typedef __attribute__((ext_vector_type(8))) short s8;       // 8 bf16 (4 VGPRs)
typedef __attribute__((ext_vector_type(4))) float f4;       // 4 fp32 acc
typedef _Float16 h4 __attribute__((ext_vector_type(4)));    // 4 fp16 (8B)

DEV unsigned short f2bf(float f) {  // RNE float->bf16 bits (finite inputs)
  unsigned u = __float_as_uint(f);
  return (unsigned short)((u + 0x7FFFu + ((u >> 16) & 1u)) >> 16);
}
DEV float bf2f(unsigned short h) { return __uint_as_float(((unsigned)h) << 16); }

// Edge tables from ADJ nonzeros: (src, dst) pairs in np.nonzero order
__constant__ int d_esrc[10] = {0,1,1,1,2,2,3,4,4,5};
__constant__ int d_inc[6][3] = {{1,-1,-1},{0,4,7},{2,6,-1},{5,-1,-1},{3,9,-1},{8,-1,-1}};
__constant__ int d_ne[6] = {1,3,2,1,2,1};

// Deformable tile geometry (offconv2/dfmain2): 32x8 px, halo 4, stride 41.
#define TW 32
#define TH 8
#define SW 41
#define SDC 40
#define SH 16
#define SN 656

// ---------------------------------------------------------------------------
// Merged weight prep.
//  [0,190)    wf2: dp_ow2 -> [e][C][9][27]
//  [190,261)  wm2: dp_w2  -> [e][9][C][10]
//  [261,926)  aw1: offconv1 MFMA A-frags (fallback path only)
//  [926,1196) awY: 12-tile Y A-frags (fallback path only)
//  [1196,1826) awU: 28-tile unified A-frags (U path only)
// ---------------------------------------------------------------------------
DEV void prep_w_body(const float* src, float* dst, int OC, int C,
                     int tap_major, int total, int i) {
  if (i >= total) return;
  int t = i % 9; int n = i / 9;
  int c = n % C; n /= C;
  int oc = n % OC; int e = n / OC;
  float v = src[i];
  int inner = tap_major ? (t * C + c) : (c * 9 + t);
  dst[(e * C * 9 + inner) * OC + oc] = v;
}

__global__ void prep_all_k(const float* __restrict__ dp_ow2, float* __restrict__ wf2,
                           const float* __restrict__ dp_w2, float* __restrict__ wm2,
                           const float* __restrict__ dp_ow1,
                           unsigned short* __restrict__ aw1,
                           const float* __restrict__ dp_w1,
                           unsigned short* __restrict__ awY,
                           unsigned short* __restrict__ awU, int use_u) {
  int b = blockIdx.x;
  if (b < 190) {
    prep_w_body(dp_ow2, wf2, 27, 20, 0, 48600, b * 256 + threadIdx.x);
  } else if (b < 261) {
    prep_w_body(dp_w2, wm2, 10, 20, 1, 18000, (b - 190) * 256 + threadIdx.x);
  } else if (b < 926) {
    if (use_u) return;
    int i = (b - 261) * 256 + threadIdx.x;        // 170240 total
    if (i >= 170240) return;
    int lane = i & 63;
    int tile = (i >> 6) & 1;
    int cg = (i >> 7) % 133;
    int e = (i >> 7) / 133;
    int m = lane & 15, quad = lane >> 4;
    int oc = tile * 16 + m;
    unsigned short* out = aw1 + ((e * 133 + cg) * 2 + tile) * 1024 + lane * 16;
#pragma unroll
    for (int j = 0; j < 8; ++j) {
      int k = quad * 8 + j;
      int csel = k >> 4, t = k & 15;
      int c = 2 * cg + csel;
      float w = (oc < 27 && t < 9) ? dp_ow1[((e * 27 + oc) * 266 + c) * 9 + t] : 0.f;
      unsigned short h = f2bf(w);
      out[j] = h;
      out[8 + j] = f2bf(w - bf2f(h));
    }
  } else if (b < 1196) {
    if (use_u) return;
    int i = (b - 926) * 256 + threadIdx.x;        // 69120 total
    int lane = i & 63;
    int grp = i >> 6;                              // 1080 = 10e * 9ks * 12mt
    int mt = grp % 12;
    int ks = (grp / 12) % 9;
    int e = grp / 108;
    int m16 = lane & 15, quad = lane >> 4;
    int M = mt * 16 + m16;
    unsigned short* out = awY + ((e * 9 + ks) * 12 + mt) * 1024 + lane * 16;
#pragma unroll
    for (int j = 0; j < 8; ++j) {
      int c = ks * 32 + quad * 8 + j;
      float w = 0.f;
      if (M < 180 && c < 266) {
        int tap = M / 20, oc = M % 20;
        w = dp_w1[((e * 20 + oc) * 266 + c) * 9 + tap];
      }
      unsigned short h = f2bf(w);
      out[j] = h;
      out[8 + j] = f2bf(w - bf2f(h));
    }
  } else {
    if (!use_u) return;
    int i = (b - 1196) * 256 + threadIdx.x;       // 161280 total
    int lane = i & 63;
    int grp = i >> 6;                              // 2520 = 10e * 9ks * 28mt
    int mt = grp % 28;
    int ks = (grp / 28) % 9;
    int e = grp / 252;
    int m16 = lane & 15, quad = lane >> 4;
    int M = mt * 16 + m16;                         // [0,180) Y | [192,435) U
    unsigned short* out = awU + ((e * 9 + ks) * 28 + mt) * 1024 + lane * 16;
#pragma unroll
    for (int j = 0; j < 8; ++j) {
      int c = ks * 32 + quad * 8 + j;
      float w = 0.f;
      if (c < 266) {
        if (M < 180) {
          int tap = M / 20, oc = M % 20;
          w = dp_w1[((e * 20 + oc) * 266 + c) * 9 + tap];
        } else if (M >= 192 && M < 435) {
          int u = M - 192, tap = u / 27, oc = u % 27;
          w = dp_ow1[((e * 27 + oc) * 266 + c) * 9 + tap];
        }
      }
      unsigned short h = f2bf(w);
      out[j] = h;
      out[8 + j] = f2bf(w - bf2f(h));
    }
  }
}

// o2 = bias broadcast; h2 = 0.
__global__ void init2_k(const float* __restrict__ ob, float* __restrict__ o2,
                        float* __restrict__ h2) {
  int i = blockIdx.x * 256 + threadIdx.x;
  if (i < 2488320) o2[i] = ob[i / 9216];
  else h2[i - 2488320] = 0.f;
}

// Staging address for halo-4 window (clamped), element i of 16x41.
DEV int stage_goff(int i, int ty0, int tx0) {
  int r = i / SW, cl = i % SW;
  cl = min(cl, SDC - 1);
  int gy = min(max(ty0 - 4 + r, 0), 95);
  int gx = min(max(tx0 - 4 + cl, 0), 95);
  return gy * 96 + gx;
}

// ---------------------------------------------------------------------------
// Unified GEMM (U path): C[M=448][N=9216] per edge; rows [0,180)=Y (fp16
// interleaved), [192,435)=U (fp16 plane-major). A hi/lo bf16, B hi-only.
// grid (36 pxg, 7 z, 10 e), 256 thr; wave = 4 nt x 4 mt.
// ---------------------------------------------------------------------------
__global__ __launch_bounds__(256) void uni_gemm_k(
    const float* __restrict__ pfea, const float* __restrict__ xp,
    const unsigned short* __restrict__ awU, unsigned short* __restrict__ Yg,
    unsigned short* __restrict__ Ug) {
  const int pxg = blockIdx.x, z = blockIdx.y, e = blockIdx.z;
  const int tid = threadIdx.x;
  const int lane = tid & 63, wv = tid >> 6;
  const int quad = lane >> 4, n16 = lane & 15;
  const float* xpe = xp + d_esrc[e] * 10 * 9216;
  const int qbase = pxg * 256 + wv * 64;

  f4 acc[4][4] = {};  // [nt][mt]

  for (int ks = 0; ks < 9; ++ks) {
    const int cq = ks * 32 + quad * 8;
    s8 Ah[4], Al[4];
#pragma unroll
    for (int mt = 0; mt < 4; ++mt) {
      const unsigned short* ap =
          awU + ((e * 9 + ks) * 28 + z * 4 + mt) * 1024 + lane * 16;
      Ah[mt] = *(const s8*)ap;
      Al[mt] = *(const s8*)(ap + 8);
    }
#pragma unroll
    for (int nt = 0; nt < 4; ++nt) {
      const int q = qbase + nt * 16 + n16;
      union { s8 v; unsigned short u[8]; } Bh;
#pragma unroll
      for (int j = 0; j < 8; ++j) {
        int c = cq + j;
        float v = 0.f;
        if (c < 256) v = pfea[c * 9216 + q];
        else if (c < 266) v = xpe[(c - 256) * 9216 + q];
        Bh.u[j] = f2bf(v);
      }
#pragma unroll
      for (int mt = 0; mt < 4; ++mt) {
        acc[nt][mt] = __builtin_amdgcn_mfma_f32_16x16x32_bf16(Ah[mt], Bh.v, acc[nt][mt], 0, 0, 0);
        acc[nt][mt] = __builtin_amdgcn_mfma_f32_16x16x32_bf16(Al[mt], Bh.v, acc[nt][mt], 0, 0, 0);
      }
    }
  }
  _Float16* Yh = (_Float16*)Yg;
  _Float16* Uh = (_Float16*)Ug;
#pragma unroll
  for (int nt = 0; nt < 4; ++nt) {
    const int q = qbase + nt * 16 + n16;
#pragma unroll
    for (int mt = 0; mt < 4; ++mt)
#pragma unroll
      for (int r = 0; r < 4; ++r) {
        int m = (z * 4 + mt) * 16 + quad * 4 + r;
        if (m < 180) {
          int tap = m / 20, oc = m - tap * 20;
          Yh[((e * 9 + tap) * 9216 + q) * 20 + oc] = (_Float16)acc[nt][mt][r];
        } else if (m >= 192 && m < 435) {
          Uh[(e * 243 + (m - 192)) * 9216 + q] = (_Float16)acc[nt][mt][r];
        }
      }
  }
}

// ---------------------------------------------------------------------------
// Shift-add (U path): o1[e][oc][p] = ob[oc] + sum_t valid(p+dt) U[e][t*27+oc](p+dt)
// grid (36, 10), 256 thr. Coalesced fp16 reads, no atomics, full o1 write.
// ---------------------------------------------------------------------------
__global__ __launch_bounds__(256) void shiftadd_k(
    const unsigned short* __restrict__ Ug, const float* __restrict__ ob,
    float* __restrict__ o1) {
  const int p = blockIdx.x * 256 + threadIdx.x;
  const int e = blockIdx.y;
  const int y = p / 96, x = p % 96;
  const _Float16* Uh = (const _Float16*)Ug;
  float acc[27];
#pragma unroll
  for (int oc = 0; oc < 27; ++oc) acc[oc] = ob[e * 27 + oc];
#pragma unroll
  for (int t = 0; t < 9; ++t) {
    int yy = y + t / 3 - 1, xx = x + t % 3 - 1;
    if (yy >= 0 && yy < 96 && xx >= 0 && xx < 96) {
      int q = yy * 96 + xx;
      const _Float16* up = Uh + (e * 243 + t * 27) * 9216 + q;
#pragma unroll
      for (int oc = 0; oc < 27; ++oc)
        acc[oc] += (float)up[oc * 9216];
    }
  }
#pragma unroll
  for (int oc = 0; oc < 27; ++oc) o1[(e * 27 + oc) * 9216 + p] = acc[oc];
}

// ---------------------------------------------------------------------------
// Offset conv 1 via MFMA (fallback path, r9 verbatim). grid (10, 36, 4).
// ---------------------------------------------------------------------------
#define OSWB 35
#define OSEC 384
#define OBUF 896

__global__ __launch_bounds__(256) void offconv1_mfma_k(
    const float* __restrict__ pfea, const float* __restrict__ xp,
    const unsigned short* __restrict__ aw, const float* __restrict__ ob,
    float* __restrict__ o1) {
  __shared__ float sbuf[2][OBUF];
  const int e = blockIdx.x, m = blockIdx.y, z = blockIdx.z;
  const int tid = threadIdx.x;
  const int lane = tid & 63, wv = tid >> 6;
  const int quad = lane >> 4, n16 = lane & 15;
  const int tx0 = (m % 3) * 32, ty0 = (m / 3) * 8;
  const float* xpe = xp + d_esrc[e] * 10 * 9216;
  const int cg_lo = (z * 133) / 4, cg_hi = ((z + 1) * 133) / 4;

  int g[3]; bool oks[3];
#pragma unroll
  for (int i = 0; i < 3; ++i) {
    int s = tid + i * 256;
    int sec = s / OSEC, off = s - sec * OSEC;
    int r = off / OSWB, cl = off % OSWB;
    int gy = ty0 - 1 + r, gx = tx0 - 1 + cl;
    bool ok = (off < 350) && (cl < 34) && (gy >= 0) && (gy < 96) &&
              (gx >= 0) && (gx < 96);
    oks[i] = ok;
    g[i] = sec * 9216 + (ok ? (gy * 96 + gx) : 0);
  }
  if (tid < OBUF - 768) { sbuf[0][768 + tid] = 0.f; sbuf[1][768 + tid] = 0.f; }

  const int tbase = (quad & 1) * 8;
  const int csel = quad >> 1;
  int bdelta[8];
#pragma unroll
  for (int j = 0; j < 8; ++j) {
    int t = tbase + j;
    int dy = t / 3 - 1, dx = t % 3 - 1;
    bdelta[j] = csel * OSEC + dy * OSWB + dx;
  }
  int bidx[4];
#pragma unroll
  for (int nt = 0; nt < 4; ++nt) {
    int r = 2 * wv + (nt >> 1), h = nt & 1;
    bidx[nt] = (r + 1) * OSWB + (h * 16 + n16 + 1);
  }

  f4 acc[4][2] = {};

  int c0 = 2 * cg_lo;
  const float* base = (c0 < 256) ? (pfea + c0 * 9216) : (xpe + (c0 - 256) * 9216);
  float pv0 = oks[0] ? base[g[0]] : 0.f;
  float pv1 = oks[1] ? base[g[1]] : 0.f;
  float pv2 = oks[2] ? base[g[2]] : 0.f;

  int bsel = 0;
  for (int cg = cg_lo; cg < cg_hi; ++cg, bsel ^= 1) {
    float* buf = sbuf[bsel];
    buf[tid] = pv0; buf[tid + 256] = pv1; buf[tid + 512] = pv2;
    if (cg + 1 < cg_hi) {
      int c0n = 2 * (cg + 1);
      const float* nb = (c0n < 256) ? (pfea + c0n * 9216)
                                    : (xpe + (c0n - 256) * 9216);
      pv0 = oks[0] ? nb[g[0]] : 0.f;
      pv1 = oks[1] ? nb[g[1]] : 0.f;
      pv2 = oks[2] ? nb[g[2]] : 0.f;
    }
    const unsigned short* apc = aw + (e * 133 + cg) * 2048 + lane * 16;
    s8 Ah0 = *(const s8*)(apc);
    s8 Al0 = *(const s8*)(apc + 8);
    s8 Ah1 = *(const s8*)(apc + 1024);
    s8 Al1 = *(const s8*)(apc + 1024 + 8);
    __syncthreads();
#pragma unroll
    for (int nt = 0; nt < 4; ++nt) {
      union { s8 v; unsigned short u[8]; } Bh, Bl;
#pragma unroll
      for (int j = 0; j < 8; ++j) {
        float v = buf[bidx[nt] + bdelta[j]];
        unsigned short h = f2bf(v);
        Bh.u[j] = h;
        Bl.u[j] = f2bf(v - bf2f(h));
      }
      acc[nt][0] = __builtin_amdgcn_mfma_f32_16x16x32_bf16(Ah0, Bh.v, acc[nt][0], 0, 0, 0);
      acc[nt][0] = __builtin_amdgcn_mfma_f32_16x16x32_bf16(Ah0, Bl.v, acc[nt][0], 0, 0, 0);
      acc[nt][0] = __builtin_amdgcn_mfma_f32_16x16x32_bf16(Al0, Bh.v, acc[nt][0], 0, 0, 0);
      acc[nt][1] = __builtin_amdgcn_mfma_f32_16x16x32_bf16(Ah1, Bh.v, acc[nt][1], 0, 0, 0);
      acc[nt][1] = __builtin_amdgcn_mfma_f32_16x16x32_bf16(Ah1, Bl.v, acc[nt][1], 0, 0, 0);
      acc[nt][1] = __builtin_amdgcn_mfma_f32_16x16x32_bf16(Al1, Bh.v, acc[nt][1], 0, 0, 0);
    }
  }
#pragma unroll
  for (int nt = 0; nt < 4; ++nt) {
    int y = ty0 + 2 * wv + (nt >> 1);
    int xx = tx0 + (nt & 1) * 16 + n16;
    int p = y * 96 + xx;
#pragma unroll
    for (int t2 = 0; t2 < 2; ++t2)
#pragma unroll
      for (int r = 0; r < 4; ++r) {
        int oc = t2 * 16 + quad * 4 + r;
        if (oc < 27) {
          float v = acc[nt][t2][r];
          if (z == 0) v += ob[e * 27 + oc];
          atomicAdd(&o1[(e * 27 + oc) * 9216 + p], v);
        }
      }
  }
}

// ---------------------------------------------------------------------------
// Y-GEMM (fallback path, r9 verbatim). grid (36 pxg, 4 mgrp, 10 e).
// ---------------------------------------------------------------------------
__global__ __launch_bounds__(256) void ygemm_k(
    const float* __restrict__ pfea, const float* __restrict__ xp,
    const unsigned short* __restrict__ awY, unsigned short* __restrict__ Yg) {
  const int pxg = blockIdx.x, z = blockIdx.y, e = blockIdx.z;
  const int tid = threadIdx.x;
  const int lane = tid & 63, wv = tid >> 6;
  const int quad = lane >> 4, n16 = lane & 15;
  const float* xpe = xp + d_esrc[e] * 10 * 9216;
  const int qbase = pxg * 256 + wv * 64;

  f4 acc[4][3] = {};

  for (int ks = 0; ks < 9; ++ks) {
    const int cq = ks * 32 + quad * 8;
    s8 Ah[3], Al[3];
#pragma unroll
    for (int mt = 0; mt < 3; ++mt) {
      const unsigned short* ap =
          awY + ((e * 9 + ks) * 12 + z * 3 + mt) * 1024 + lane * 16;
      Ah[mt] = *(const s8*)ap;
      Al[mt] = *(const s8*)(ap + 8);
    }
#pragma unroll
    for (int nt = 0; nt < 4; ++nt) {
      const int q = qbase + nt * 16 + n16;
      union { s8 v; unsigned short u[8]; } Bh, Bl;
#pragma unroll
      for (int j = 0; j < 8; ++j) {
        int c = cq + j;
        float v = 0.f;
        if (c < 256) v = pfea[c * 9216 + q];
        else if (c < 266) v = xpe[(c - 256) * 9216 + q];
        unsigned short h = f2bf(v);
        Bh.u[j] = h;
        Bl.u[j] = f2bf(v - bf2f(h));
      }
#pragma unroll
      for (int mt = 0; mt < 3; ++mt) {
        acc[nt][mt] = __builtin_amdgcn_mfma_f32_16x16x32_bf16(Ah[mt], Bh.v, acc[nt][mt], 0, 0, 0);
        acc[nt][mt] = __builtin_amdgcn_mfma_f32_16x16x32_bf16(Ah[mt], Bl.v, acc[nt][mt], 0, 0, 0);
        acc[nt][mt] = __builtin_amdgcn_mfma_f32_16x16x32_bf16(Al[mt], Bh.v, acc[nt][mt], 0, 0, 0);
      }
    }
  }
  _Float16* Yh = (_Float16*)Yg;
#pragma unroll
  for (int nt = 0; nt < 4; ++nt) {
    const int q = qbase + nt * 16 + n16;
#pragma unroll
    for (int mt = 0; mt < 3; ++mt)
#pragma unroll
      for (int r = 0; r < 4; ++r) {
        int m = z * 48 + mt * 16 + quad * 4 + r;
        if (m < 180) {
          int tap = m / 20, oc = m - tap * 20;
          Yh[((e * 9 + tap) * 9216 + q) * 20 + oc] = (_Float16)acc[nt][mt][r];
        }
      }
  }
}

// ---------------------------------------------------------------------------
// Deformable gather (shared): h1a += sum_k bilinear(Y[e][k])(pos_k).
// grid (36 px, 3 tapgrp, 10 e).
// ---------------------------------------------------------------------------
__global__ __launch_bounds__(256) void dfgather_k(
    const float* __restrict__ o1, const unsigned short* __restrict__ Yg,
    float* __restrict__ h1a) {
  const int p = blockIdx.x * 256 + threadIdx.x;
  const int zt = blockIdx.y, e = blockIdx.z;
  const int y = p / 96, x = p % 96;
  float acc[20];
#pragma unroll
  for (int oc = 0; oc < 20; ++oc) acc[oc] = 0.f;

  const _Float16* Yh = (const _Float16*)Yg;
#pragma unroll
  for (int t = 0; t < 3; ++t) {
    const int k = zt * 3 + t;
    float offy = o1[(e * 27 + 2 * k) * 9216 + p];
    float offx = o1[(e * 27 + 2 * k + 1) * 9216 + p];
    float mk = sigm(o1[(e * 27 + 18 + k) * 9216 + p]);
    float py = (float)(y + k / 3 - 1) + offy;
    float px = (float)(x + k % 3 - 1) + offx;
    float fy = floorf(py), fx = floorf(px);
    float wy = py - fy, wx = px - fx;
    int iy = (int)fy, ix = (int)fx;
    const _Float16* yk = Yh + (e * 9 + k) * 9216 * 20;
#pragma unroll
    for (int dy = 0; dy < 2; ++dy)
#pragma unroll
      for (int dx = 0; dx < 2; ++dx) {
        bool ok = (iy + dy >= 0) && (iy + dy < 96) && (ix + dx >= 0) && (ix + dx < 96);
        float cwc = (ok ? mk : 0.f) * (dy ? wy : (1.f - wy)) * (dx ? wx : (1.f - wx));
        int yc = min(max(iy + dy, 0), 95), xc = min(max(ix + dx, 0), 95);
        const h4* yp = (const h4*)(yk + (yc * 96 + xc) * 20);
#pragma unroll
        for (int g = 0; g < 5; ++g) {
          h4 v = yp[g];
#pragma unroll
          for (int u = 0; u < 4; ++u)
            acc[g * 4 + u] = fmaf(cwc, (float)v[u], acc[g * 4 + u]);
        }
      }
  }
#pragma unroll
  for (int oc = 0; oc < 20; ++oc)
    atomicAdd(&h1a[(e * 20 + oc) * 9216 + p], acc[oc]);
}

// ---------------------------------------------------------------------------
// Offset conv 2 (shared, r8): pair-staged, affine+relu at staging, split z=2,
// atomic into bias-inited o2. grid (10, 36, 2)
// ---------------------------------------------------------------------------
__global__ __launch_bounds__(256) void offconv2_k(
    const float* __restrict__ h1a, const float* __restrict__ wf,
    const float* __restrict__ s1, const float* __restrict__ b1,
    float* __restrict__ o2) {
  __shared__ float sbuf[2][2 * SN];
  const int e = blockIdx.x, m = blockIdx.y;
  const int c_lo = blockIdx.z * 10;
  const int tid = threadIdx.x;
  const int tx = tid % TW, ty = tid / TW;
  const int tx0 = (m % 3) * TW, ty0 = (m / 3) * TH;
  const int y = ty0 + ty, x = tx0 + tx;
  const int p = y * 96 + x;
  const float* base = h1a + e * 20 * 9216;

  const int g0 = stage_goff(tid, ty0, tx0);
  const int g1 = stage_goff(tid + 256, ty0, tx0);
  const int g2 = (tid < SN - 512) ? stage_goff(tid + 512, ty0, tx0) : 0;

  float vmask[9];
#pragma unroll
  for (int t = 0; t < 9; ++t) {
    int yy = y + t / 3 - 1, xx = x + t % 3 - 1;
    vmask[t] = ((yy >= 0) && (yy < 96) && (xx >= 0) && (xx < 96)) ? 1.f : 0.f;
  }
  const int vbase = (ty + 3) * SW + (tx + 3);

  float acc[27];
#pragma unroll
  for (int oc = 0; oc < 27; ++oc) acc[oc] = 0.f;

  const float* ia = base + c_lo * 9216;
  const float* ib = ia + 9216;
  float pa0 = ia[g0], pa1 = ia[g1], pa2 = (tid < SN - 512) ? ia[g2] : 0.f;
  float pb0 = ib[g0], pb1 = ib[g1], pb2 = (tid < SN - 512) ? ib[g2] : 0.f;

  int bsel = 0;
  for (int c = c_lo; c < c_lo + 10; c += 2, bsel ^= 1) {
    float sa = s1[e * 20 + c], ba = b1[e * 20 + c];
    float sb = s1[e * 20 + c + 1], bb2 = b1[e * 20 + c + 1];
    float* buf = sbuf[bsel];
    buf[tid] = fmaxf(fmaf(sa, pa0, ba), 0.f);
    buf[tid + 256] = fmaxf(fmaf(sa, pa1, ba), 0.f);
    if (tid < SN - 512) buf[tid + 512] = fmaxf(fmaf(sa, pa2, ba), 0.f);
    buf[SN + tid] = fmaxf(fmaf(sb, pb0, bb2), 0.f);
    buf[SN + tid + 256] = fmaxf(fmaf(sb, pb1, bb2), 0.f);
    if (tid < SN - 512) buf[SN + tid + 512] = fmaxf(fmaf(sb, pb2, bb2), 0.f);
    if (c + 2 < c_lo + 10) {
      const float* na = base + (c + 2) * 9216;
      const float* nb = base + (c + 3) * 9216;
      pa0 = na[g0]; pa1 = na[g1]; if (tid < SN - 512) pa2 = na[g2];
      pb0 = nb[g0]; pb1 = nb[g1]; if (tid < SN - 512) pb2 = nb[g2];
    }
    __syncthreads();
#pragma unroll
    for (int cc = 0; cc < 2; ++cc) {
      const float* wc = wf + (e * 20 + c + cc) * 243;
      const float* bp = buf + cc * SN;
#pragma unroll
      for (int t = 0; t < 9; ++t) {
        float v = vmask[t] * bp[vbase + (t / 3) * SW + (t % 3)];
#pragma unroll
        for (int oc = 0; oc < 27; ++oc)
          acc[oc] = fmaf(v, wc[t * 27 + oc], acc[oc]);
      }
    }
  }
#pragma unroll
  for (int oc = 0; oc < 27; ++oc)
    atomicAdd(&o2[(e * 27 + oc) * 9216 + p], acc[oc]);
}

// ---------------------------------------------------------------------------
// Deformable main conv 2 (shared, r8): pair staging (affine+relu fused),
// split z=2, atomic raw into zero-inited h2. grid (10, 36, 2)
// ---------------------------------------------------------------------------
__global__ __launch_bounds__(256) void dfmain2_k(
    const float* __restrict__ h1a, const float* __restrict__ o2,
    const float* __restrict__ wm, const float* __restrict__ s1,
    const float* __restrict__ b1, float* __restrict__ hout) {
  __shared__ float sbuf[2][2 * SN];
  const int e = blockIdx.x, m = blockIdx.y;
  const int c_lo = blockIdx.z * 10;
  const int tid = threadIdx.x;
  const int tx = tid % TW, ty = tid / TW;
  const int tx0 = (m % 3) * TW, ty0 = (m / 3) * TH;
  const int y = ty0 + ty, x = tx0 + tx;
  const int p = y * 96 + x;
  const float* base = h1a + e * 20 * 9216;

  const int g0 = stage_goff(tid, ty0, tx0);
  const int g1 = stage_goff(tid + 256, ty0, tx0);
  const int g2 = (tid < SN - 512) ? stage_goff(tid + 512, ty0, tx0) : 0;

  int iob[9]; float cw[9][4];
  bool oob = false;
#pragma unroll
  for (int k = 0; k < 9; ++k) {
    float offy = o2[(e * 27 + 2 * k) * 9216 + p];
    float offx = o2[(e * 27 + 2 * k + 1) * 9216 + p];
    float mk = sigm(o2[(e * 27 + 18 + k) * 9216 + p]);
    float py = (float)(y + k / 3 - 1) + offy;
    float px = (float)(x + k % 3 - 1) + offx;
    float fy = floorf(py), fx = floorf(px);
    float wy = py - fy, wx = px - fx;
    int iy = (int)fy, ix = (int)fx;
#pragma unroll
    for (int dy = 0; dy < 2; ++dy)
#pragma unroll
      for (int dx = 0; dx < 2; ++dx) {
        bool ok = (iy + dy >= 0) && (iy + dy < 96) && (ix + dx >= 0) && (ix + dx < 96);
        cw[k][dy * 2 + dx] =
            (ok ? mk : 0.f) * (dy ? wy : (1.f - wy)) * (dx ? wx : (1.f - wx));
      }
    int ir = iy - (ty0 - 4), ic = ix - (tx0 - 4);
    oob |= ((unsigned)ir > (unsigned)(SH - 2)) | ((unsigned)ic > (unsigned)(SDC - 2));
    iob[k] = min(max(ir, 0), SH - 2) * SW + min(max(ic, 0), SDC - 2);
  }

  float acc[10];
#pragma unroll
  for (int oc = 0; oc < 10; ++oc) acc[oc] = 0.f;

  const float* ia = base + c_lo * 9216;
  const float* ib = ia + 9216;
  float pa0 = ia[g0], pa1 = ia[g1], pa2 = (tid < SN - 512) ? ia[g2] : 0.f;
  float pb0 = ib[g0], pb1 = ib[g1], pb2 = (tid < SN - 512) ? ib[g2] : 0.f;

  int bsel = 0;
  for (int c = c_lo; c < c_lo + 10; c += 2, bsel ^= 1) {
    float sa = s1[e * 20 + c], ba = b1[e * 20 + c];
    float sb = s1[e * 20 + c + 1], bb2 = b1[e * 20 + c + 1];
    float* buf = sbuf[bsel];
    buf[tid] = fmaxf(fmaf(sa, pa0, ba), 0.f);
    buf[tid + 256] = fmaxf(fmaf(sa, pa1, ba), 0.f);
    if (tid < SN - 512) buf[tid + 512] = fmaxf(fmaf(sa, pa2, ba), 0.f);
    buf[SN + tid] = fmaxf(fmaf(sb, pb0, bb2), 0.f);
    buf[SN + tid + 256] = fmaxf(fmaf(sb, pb1, bb2), 0.f);
    if (tid < SN - 512) buf[SN + tid + 512] = fmaxf(fmaf(sb, pb2, bb2), 0.f);
    if (c + 2 < c_lo + 10) {
      const float* na = base + (c + 2) * 9216;
      const float* nb = base + (c + 3) * 9216;
      pa0 = na[g0]; pa1 = na[g1]; if (tid < SN - 512) pa2 = na[g2];
      pb0 = nb[g0]; pb1 = nb[g1]; if (tid < SN - 512) pb2 = nb[g2];
    }
    __syncthreads();
#pragma unroll
    for (int cc = 0; cc < 2; ++cc) {
      const float* bp = buf + cc * SN;
#pragma unroll
      for (int k = 0; k < 9; ++k) {
        const float* bk = bp + iob[k];
        float sv = cw[k][0] * bk[0] + cw[k][1] * bk[1] +
                   cw[k][2] * bk[SW] + cw[k][3] * bk[SW + 1];
        const float* wc = wm + ((e * 9 + k) * 20 + c + cc) * 10;
#pragma unroll
        for (int oc = 0; oc < 10; ++oc) acc[oc] = fmaf(sv, wc[oc], acc[oc]);
      }
    }
  }

  if (oob) {
#pragma unroll
    for (int oc = 0; oc < 10; ++oc) acc[oc] = 0.f;
    for (int k = 0; k < 9; ++k) {
      float offy = o2[(e * 27 + 2 * k) * 9216 + p];
      float offx = o2[(e * 27 + 2 * k + 1) * 9216 + p];
      float mk = sigm(o2[(e * 27 + 18 + k) * 9216 + p]);
      float py = (float)(y + k / 3 - 1) + offy;
      float px = (float)(x + k % 3 - 1) + offx;
      float fy = floorf(py), fx = floorf(px);
      float wy = py - fy, wx = px - fx;
      int iy = (int)fy, ix = (int)fx;
      int go[4]; float gw[4];
#pragma unroll
      for (int dy = 0; dy < 2; ++dy)
#pragma unroll
        for (int dx = 0; dx < 2; ++dx) {
          bool ok = (iy + dy >= 0) && (iy + dy < 96) && (ix + dx >= 0) && (ix + dx < 96);
          int yc = min(max(iy + dy, 0), 95), xc = min(max(ix + dx, 0), 95);
          go[dy * 2 + dx] = yc * 96 + xc;
          gw[dy * 2 + dx] =
              (ok ? mk : 0.f) * (dy ? wy : (1.f - wy)) * (dx ? wx : (1.f - wx));
        }
      for (int c = c_lo; c < c_lo + 10; ++c) {
        float sc = s1[e * 20 + c], bc = b1[e * 20 + c];
        const float* ptr = base + c * 9216;
        float v0 = fmaxf(fmaf(sc, ptr[go[0]], bc), 0.f);
        float v1 = fmaxf(fmaf(sc, ptr[go[1]], bc), 0.f);
        float v2 = fmaxf(fmaf(sc, ptr[go[2]], bc), 0.f);
        float v3 = fmaxf(fmaf(sc, ptr[go[3]], bc), 0.f);
        float sv = gw[0] * v0 + gw[1] * v1 + gw[2] * v2 + gw[3] * v3;
        const float* wc = wm + ((e * 9 + k) * 20 + c) * 10;
#pragma unroll
        for (int oc = 0; oc < 10; ++oc) acc[oc] = fmaf(sv, wc[oc], acc[oc]);
      }
    }
  }
#pragma unroll
  for (int oc = 0; oc < 10; ++oc)
    atomicAdd(&hout[(e * 10 + oc) * 9216 + p], acc[oc]);
}

// 1x1 conv p_fea (256ch) -> accfh[j][10][9216], split-K atomic. grid (36,6,4)
__global__ __launch_bounds__(256) void conv_fh_k(
    const float* __restrict__ pfea, const float* __restrict__ wfh,
    float* __restrict__ accfh) {
  const int j = blockIdx.y;
  const int z = blockIdx.z;
  const int p = blockIdx.x * 256 + threadIdx.x;
  const int c_lo = z * 64;
  float acc[10];
#pragma unroll
  for (int c = 0; c < 10; ++c) acc[c] = 0.f;
  for (int ci = c_lo; ci < c_lo + 64; ci += 4) {
    float pv0 = pfea[ci * 9216 + p];
    float pv1 = pfea[(ci + 1) * 9216 + p];
    float pv2 = pfea[(ci + 2) * 9216 + p];
    float pv3 = pfea[(ci + 3) * 9216 + p];
#pragma unroll
    for (int c = 0; c < 10; ++c) {
      acc[c] = fmaf(pv0, wfh[(j * 10 + c) * 256 + ci], acc[c]);
      acc[c] = fmaf(pv1, wfh[(j * 10 + c) * 256 + ci + 1], acc[c]);
      acc[c] = fmaf(pv2, wfh[(j * 10 + c) * 256 + ci + 2], acc[c]);
      acc[c] = fmaf(pv3, wfh[(j * 10 + c) * 256 + ci + 3], acc[c]);
    }
  }
#pragma unroll
  for (int c = 0; c < 10; ++c)
    atomicAdd(&accfh[(j * 10 + c) * 9216 + p], acc[c]);
}

// ---------------------------------------------------------------------------
// Fused node-message + GRU stage; applies h2 affine (s2,b2)+relu inline.
// grid (36, 6)
// ---------------------------------------------------------------------------
__global__ __launch_bounds__(256) void msggru_k(
    const float* __restrict__ xp, const float* __restrict__ xh,
    const float* __restrict__ h2, const float* __restrict__ accfh,
    const float* __restrict__ s2, const float* __restrict__ b2g,
    const float* __restrict__ aw, const float* __restrict__ ab,
    const float* __restrict__ bw, const float* __restrict__ bb,
    const float* __restrict__ w1, const float* __restrict__ s1,
    const float* __restrict__ b1, const float* __restrict__ w2,
    const float* __restrict__ b2, const float* __restrict__ sfh,
    const float* __restrict__ bfh,
    const float* __restrict__ wih1, const float* __restrict__ bih1,
    const float* __restrict__ bhh1, const float* __restrict__ wih2,
    const float* __restrict__ bih2, const float* __restrict__ bhh2,
    float* __restrict__ out_m, float* __restrict__ out_x) {
  const int j = blockIdx.y;
  const int p = blockIdx.x * 256 + threadIdx.x;
  float xj[10];
#pragma unroll
  for (int c = 0; c < 10; ++c) xj[c] = xp[(j * 10 + c) * 9216 + p];
  float xpp[10];
  int ne = d_ne[j];
  for (int ei = 0; ei < ne; ++ei) {
    int e = d_inc[j][ei];
    int a2 = d_esrc[e];
    float sA = ab[e];
#pragma unroll
    for (int c = 0; c < 10; ++c)
      sA = fmaf(xp[(a2 * 10 + c) * 9216 + p], aw[e * 10 + c], sA);
    float sB = bb[e];
#pragma unroll
    for (int c = 0; c < 10; ++c) sB = fmaf(xj[c], bw[e * 10 + c], sB);
    float f = (1.f - sigm(sA)) * sigm(sB);
#pragma unroll
    for (int c = 0; c < 10; ++c) {
      float raw = h2[(e * 10 + c) * 9216 + p];
      float hv = fmaxf(fmaf(s2[e * 10 + c], raw, b2g[e * 10 + c]), 0.f);
      float mm = f * hv;
      xpp[c] = (ei == 0) ? mm : fmaxf(xpp[c], mm);
    }
  }
  const float* hf = xh + ((j < 4) ? 0 : 1) * 10 * 9216;
  float cat[20];
#pragma unroll
  for (int c = 0; c < 10; ++c) cat[c] = hf[c * 9216 + p];
#pragma unroll
  for (int c = 0; c < 10; ++c) cat[10 + c] = xj[c];
  float at = b2[j];
#pragma unroll
  for (int oc = 0; oc < 20; ++oc) {
    float t = 0.f;
#pragma unroll
    for (int c = 0; c < 20; ++c)
      t = fmaf(cat[c], w1[(j * 20 + oc) * 20 + c], t);
    float av = fmaxf(s1[j * 20 + oc] * t + b1[j * 20 + oc], 0.f);
    at = fmaf(av, w2[j * 20 + oc], at);
  }
  at = sigm(at);
  float msg[10];
#pragma unroll
  for (int c = 0; c < 10; ++c) {
    float xhp = fmaxf(sfh[j * 10 + c] * (at * accfh[(j * 10 + c) * 9216 + p]) +
                          bfh[j * 10 + c], 0.f);
    msg[c] = xpp[c] + xhp;
    out_m[(j * 10 + c) * 9216 + p] = msg[c];
  }
  float gi[30];
#pragma unroll
  for (int r = 0; r < 30; ++r) gi[r] = bih1[j * 30 + r];
#pragma unroll
  for (int c = 0; c < 10; ++c) {
    float v = xj[c];
#pragma unroll
    for (int r = 0; r < 30; ++r)
      gi[r] = fmaf(v, wih1[(j * 30 + r) * 20 + c], gi[r]);
  }
#pragma unroll
  for (int c = 0; c < 10; ++c) {
    float v = msg[c];
#pragma unroll
    for (int r = 0; r < 30; ++r)
      gi[r] = fmaf(v, wih1[(j * 30 + r) * 20 + 10 + c], gi[r]);
  }
  float h1v[10];
#pragma unroll
  for (int c = 0; c < 10; ++c) {
    float r = sigm(gi[c] + bhh1[j * 30 + c]);
    float z = sigm(gi[10 + c] + bhh1[j * 30 + 10 + c]);
    float n = tanhf(gi[20 + c] + r * bhh1[j * 30 + 20 + c]);
    h1v[c] = (1.f - z) * n;
  }
  float g2v[30];
#pragma unroll
  for (int r = 0; r < 30; ++r) g2v[r] = bih2[j * 30 + r];
#pragma unroll
  for (int c = 0; c < 10; ++c) {
    float v = h1v[c];
#pragma unroll
    for (int r = 0; r < 30; ++r)
      g2v[r] = fmaf(v, wih2[(j * 30 + r) * 10 + c], g2v[r]);
  }
#pragma unroll
  for (int c = 0; c < 10; ++c) {
    float r = sigm(g2v[c] + bhh2[j * 30 + c]);
    float z = sigm(g2v[10 + c] + bhh2[j * 30 + 10 + c]);
    float n = tanhf(g2v[20 + c] + r * bhh2[j * 30 + 20 + c]);
    out_x[(j * 10 + c) * 9216 + p] = (1.f - z) * n;
  }
}

extern "C" void kernel_launch(void* const* d_in, const int* in_sizes, int n_in,
                              void* d_out, int out_size, void* d_ws, size_t ws_size,
                              hipStream_t stream) {
  const float* pfea   = (const float*)d_in[0];
  const float* xp     = (const float*)d_in[1];
  const float* xh     = (const float*)d_in[2];
  const float* dp_ow1 = (const float*)d_in[3];
  const float* dp_ob1 = (const float*)d_in[4];
  const float* dp_w1  = (const float*)d_in[5];
  const float* dp_s1  = (const float*)d_in[6];
  const float* dp_b1  = (const float*)d_in[7];
  const float* dp_ow2 = (const float*)d_in[8];
  const float* dp_ob2 = (const float*)d_in[9];
  const float* dp_w2  = (const float*)d_in[10];
  const float* dp_s1x = dp_s1;
  const float* dp_s2  = (const float*)d_in[11];
  const float* dp_b2  = (const float*)d_in[12];
  const float* dp_aw  = (const float*)d_in[13];
  const float* dp_ab  = (const float*)d_in[14];
  const float* dp_bw  = (const float*)d_in[15];
  const float* dp_bb  = (const float*)d_in[16];
  const float* dc_w1  = (const float*)d_in[17];
  const float* dc_s1  = (const float*)d_in[18];
  const float* dc_b1  = (const float*)d_in[19];
  const float* dc_w2  = (const float*)d_in[20];
  const float* dc_b2  = (const float*)d_in[21];
  const float* dc_wfh = (const float*)d_in[22];
  const float* dc_sfh = (const float*)d_in[23];
  const float* dc_bfh = (const float*)d_in[24];
  const float* g_wih1 = (const float*)d_in[25];
  const float* g_bih1 = (const float*)d_in[26];
  const float* g_bhh1 = (const float*)d_in[28];
  const float* g_wih2 = (const float*)d_in[29];
  const float* g_bih2 = (const float*)d_in[30];
  const float* g_bhh2 = (const float*)d_in[32];
  (void)dp_s1x;

  float* ws = (float*)d_ws;
  const bool use_u = ws_size >= 26654760ull * sizeof(float);

  unsigned short *aw1, *awY = nullptr, *awU = nullptr, *Yg, *Ug = nullptr;
  float *accfh, *h2, *wf2, *wm2, *o1, *o2, *h1a;

  if (use_u) {
    // region0 [0, 1,474,560): phase1 aw1 (unused); phase2 accfh + h2
    aw1   = (unsigned short*)ws;
    accfh = ws;
    h2    = ws + 552960;
    awU   = (unsigned short*)(ws + 1474560);   // 2,580,480 ushort
    wf2   = ws + 1474560 + 1290240;
    wm2   = wf2 + 48600;
    o1    = wm2 + 18000;                        // 2,488,320 (o2 alias)
    o2    = o1;
    h1a   = o1 + 2488320;                       // 1,843,200
    Yg    = (unsigned short*)(h1a + 1843200);   // 16,588,800 ushort
    Ug    = (unsigned short*)(h1a + 1843200 + 8294400);  // 22,394,880 ushort
    // total: 26,654,760 floats = 106.6 MB
  } else {
    // r9 layout verbatim (proven at 58.4 MB)
    aw1   = (unsigned short*)ws;
    awY   = (unsigned short*)(ws + 1361920);
    accfh = ws;
    h2    = ws + 552960;
    wf2   = ws + 1914880;
    wm2   = wf2 + 48600;
    o1    = wm2 + 18000;
    o2    = o1;
    h1a   = o1 + 2488320;
    Yg    = (unsigned short*)(ws + 6313000);
  }

  float* out_x = (float*)d_out;        // xp_out: 6*10*9216
  float* out_m = out_x + 552960;       // msgs:   6*10*9216

  dim3 blk(256);
  prep_all_k<<<dim3(1826), blk, 0, stream>>>(dp_ow2, wf2, dp_w2, wm2,
                                             dp_ow1, aw1, dp_w1, awY ? awY : aw1,
                                             awU ? awU : aw1, use_u ? 1 : 0);

  if (use_u) {
    hipMemsetAsync(h1a, 0, 1843200 * sizeof(float), stream);
    uni_gemm_k<<<dim3(36, 7, 10), blk, 0, stream>>>(pfea, xp, awU, Yg, Ug);
    shiftadd_k<<<dim3(36, 10), blk, 0, stream>>>(Ug, dp_ob1, o1);
    dfgather_k<<<dim3(36, 3, 10), blk, 0, stream>>>(o1, Yg, h1a);
  } else {
    hipMemsetAsync(o1, 0, (2488320 + 1843200) * sizeof(float), stream);
    offconv1_mfma_k<<<dim3(10, 36, 4), blk, 0, stream>>>(pfea, xp, aw1, dp_ob1, o1);
    ygemm_k<<<dim3(36, 4, 10), blk, 0, stream>>>(pfea, xp, awY, Yg);
    dfgather_k<<<dim3(36, 3, 10), blk, 0, stream>>>(o1, Yg, h1a);
  }

  init2_k<<<dim3(13320), blk, 0, stream>>>(dp_ob2, o2, h2);
  offconv2_k<<<dim3(10, 36, 2), blk, 0, stream>>>(h1a, wf2, dp_s1, dp_b1, o2);
  dfmain2_k<<<dim3(10, 36, 2), blk, 0, stream>>>(h1a, o2, wm2, dp_s1, dp_b1, h2);

  hipMemsetAsync(accfh, 0, 552960 * sizeof(float), stream);
  conv_fh_k<<<dim3(36, 6, 4), blk, 0, stream>>>(pfea, dc_wfh, accfh);

  msggru_k<<<dim3(36, 6), blk, 0, stream>>>(
      xp, xh, h2, accfh, dp_s2, dp_b2, dp_aw, dp_ab, dp_bw, dp_bb,
      dc_w1, dc_s1, dc_b1, dc_w2, dc_b2, dc_sfh, dc_bfh,
      g_wih1, g_bih1, g_bhh1, g_wih2, g_bih2, g_bhh2, out_m, out_x);
}

// Round 11
// 396.506 us; speedup vs baseline: 1.8302x; 1.0533x over previous
//
#include <hip/hip_runtime.h>
#include <hip/hip_bf16.h>

#define DEV static __device__ __forceinline__

DEV float sigm(float x) { return 1.f / (1.f + __expf(-x)); }

typedef __attribute__((ext_vector_type(8))) short s8;       // 8 bf16 (4 VGPRs)
typedef __attribute__((ext_vector_type(4))) float f4;       // 4 fp32 acc
typedef _Float16 h4 __attribute__((ext_vector_type(4)));    // 4 fp16 (8B)

DEV unsigned short f2bf(float f) {  // RNE float->bf16 bits (finite inputs)
  unsigned u = __float_as_uint(f);
  return (unsigned short)((u + 0x7FFFu + ((u >> 16) & 1u)) >> 16);
}
DEV float bf2f(unsigned short h) { return __uint_as_float(((unsigned)h) << 16); }

// Edge tables from ADJ nonzeros: (src, dst) pairs in np.nonzero order
__constant__ int d_esrc[10] = {0,1,1,1,2,2,3,4,4,5};
__constant__ int d_inc[6][3] = {{1,-1,-1},{0,4,7},{2,6,-1},{5,-1,-1},{3,9,-1},{8,-1,-1}};
__constant__ int d_ne[6] = {1,3,2,1,2,1};

// Deformable tile geometry (offconv2/dfmain2): 32x8 px, halo 4, stride 41.
#define TW 32
#define TH 8
#define SW 41
#define SDC 40
#define SH 16
#define SN 656

// ---------------------------------------------------------------------------
// Merged weight prep (same as r10).
// ---------------------------------------------------------------------------
DEV void prep_w_body(const float* src, float* dst, int OC, int C,
                     int tap_major, int total, int i) {
  if (i >= total) return;
  int t = i % 9; int n = i / 9;
  int c = n % C; n /= C;
  int oc = n % OC; int e = n / OC;
  float v = src[i];
  int inner = tap_major ? (t * C + c) : (c * 9 + t);
  dst[(e * C * 9 + inner) * OC + oc] = v;
}

__global__ void prep_all_k(const float* __restrict__ dp_ow2, float* __restrict__ wf2,
                           const float* __restrict__ dp_w2, float* __restrict__ wm2,
                           const float* __restrict__ dp_ow1,
                           unsigned short* __restrict__ aw1,
                           const float* __restrict__ dp_w1,
                           unsigned short* __restrict__ awY,
                           unsigned short* __restrict__ awU, int use_u) {
  int b = blockIdx.x;
  if (b < 190) {
    prep_w_body(dp_ow2, wf2, 27, 20, 0, 48600, b * 256 + threadIdx.x);
  } else if (b < 261) {
    prep_w_body(dp_w2, wm2, 10, 20, 1, 18000, (b - 190) * 256 + threadIdx.x);
  } else if (b < 926) {
    if (use_u) return;
    int i = (b - 261) * 256 + threadIdx.x;        // 170240 total
    if (i >= 170240) return;
    int lane = i & 63;
    int tile = (i >> 6) & 1;
    int cg = (i >> 7) % 133;
    int e = (i >> 7) / 133;
    int m = lane & 15, quad = lane >> 4;
    int oc = tile * 16 + m;
    unsigned short* out = aw1 + ((e * 133 + cg) * 2 + tile) * 1024 + lane * 16;
#pragma unroll
    for (int j = 0; j < 8; ++j) {
      int k = quad * 8 + j;
      int csel = k >> 4, t = k & 15;
      int c = 2 * cg + csel;
      float w = (oc < 27 && t < 9) ? dp_ow1[((e * 27 + oc) * 266 + c) * 9 + t] : 0.f;
      unsigned short h = f2bf(w);
      out[j] = h;
      out[8 + j] = f2bf(w - bf2f(h));
    }
  } else if (b < 1196) {
    if (use_u) return;
    int i = (b - 926) * 256 + threadIdx.x;        // 69120 total
    int lane = i & 63;
    int grp = i >> 6;
    int mt = grp % 12;
    int ks = (grp / 12) % 9;
    int e = grp / 108;
    int m16 = lane & 15, quad = lane >> 4;
    int M = mt * 16 + m16;
    unsigned short* out = awY + ((e * 9 + ks) * 12 + mt) * 1024 + lane * 16;
#pragma unroll
    for (int j = 0; j < 8; ++j) {
      int c = ks * 32 + quad * 8 + j;
      float w = 0.f;
      if (M < 180 && c < 266) {
        int tap = M / 20, oc = M % 20;
        w = dp_w1[((e * 20 + oc) * 266 + c) * 9 + tap];
      }
      unsigned short h = f2bf(w);
      out[j] = h;
      out[8 + j] = f2bf(w - bf2f(h));
    }
  } else {
    if (!use_u) return;
    int i = (b - 1196) * 256 + threadIdx.x;       // 161280 total
    int lane = i & 63;
    int grp = i >> 6;                              // 2520 = 10e * 9ks * 28mt
    int mt = grp % 28;
    int ks = (grp / 28) % 9;
    int e = grp / 252;
    int m16 = lane & 15, quad = lane >> 4;
    int M = mt * 16 + m16;                         // [0,180) Y | [192,435) U
    unsigned short* out = awU + ((e * 9 + ks) * 28 + mt) * 1024 + lane * 16;
#pragma unroll
    for (int j = 0; j < 8; ++j) {
      int c = ks * 32 + quad * 8 + j;
      float w = 0.f;
      if (c < 266) {
        if (M < 180) {
          int tap = M / 20, oc = M % 20;
          w = dp_w1[((e * 20 + oc) * 266 + c) * 9 + tap];
        } else if (M >= 192 && M < 435) {
          int u = M - 192, tap = u / 27, oc = u % 27;
          w = dp_ow1[((e * 27 + oc) * 266 + c) * 9 + tap];
        }
      }
      unsigned short h = f2bf(w);
      out[j] = h;
      out[8 + j] = f2bf(w - bf2f(h));
    }
  }
}

// ---------------------------------------------------------------------------
// X transpose to bf16, K-contiguous (U path).
//  Xt_p[q][256c] bf16; Xt_x[node][q][32c] bf16 (10 real + 22 zero).
// grid (36 qg, 14): y<8 -> pfea cgroup y*32; y in [8,14) -> node y-8.
// ---------------------------------------------------------------------------
__global__ __launch_bounds__(256) void xt_k(
    const float* __restrict__ pfea, const float* __restrict__ xp,
    unsigned short* __restrict__ Xt_p, unsigned short* __restrict__ Xt_x) {
  __shared__ unsigned int lds[256][17];
  const int q0 = blockIdx.x * 256, yb = blockIdx.y;
  const int t = threadIdx.x;
  if (yb < 8) {
    const int c0 = yb * 32;
#pragma unroll
    for (int cc = 0; cc < 32; cc += 2) {
      float v0 = pfea[(c0 + cc) * 9216 + q0 + t];
      float v1 = pfea[(c0 + cc + 1) * 9216 + q0 + t];
      lds[t][cc >> 1] = (unsigned)f2bf(v0) | ((unsigned)f2bf(v1) << 16);
    }
    __syncthreads();
    unsigned int* dst = (unsigned int*)(Xt_p + (size_t)(q0 + t) * 256 + c0);
#pragma unroll
    for (int u = 0; u < 16; ++u) dst[u] = lds[t][u];
  } else {
    const int node = yb - 8;
#pragma unroll
    for (int cc = 0; cc < 32; cc += 2) {
      float v0 = (cc < 10) ? xp[(node * 10 + cc) * 9216 + q0 + t] : 0.f;
      float v1 = (cc + 1 < 10) ? xp[(node * 10 + cc + 1) * 9216 + q0 + t] : 0.f;
      lds[t][cc >> 1] = (unsigned)f2bf(v0) | ((unsigned)f2bf(v1) << 16);
    }
    __syncthreads();
    unsigned int* dst = (unsigned int*)(Xt_x + ((size_t)node * 9216 + q0 + t) * 32);
#pragma unroll
    for (int u = 0; u < 16; ++u) dst[u] = lds[t][u];
  }
}

// o2 = bias broadcast; h2 = 0.
__global__ void init2_k(const float* __restrict__ ob, float* __restrict__ o2,
                        float* __restrict__ h2) {
  int i = blockIdx.x * 256 + threadIdx.x;
  if (i < 2488320) o2[i] = ob[i / 9216];
  else h2[i - 2488320] = 0.f;
}

// Staging address for halo-4 window (clamped), element i of 16x41.
DEV int stage_goff(int i, int ty0, int tx0) {
  int r = i / SW, cl = i % SW;
  cl = min(cl, SDC - 1);
  int gy = min(max(ty0 - 4 + r, 0), 95);
  int gx = min(max(tx0 - 4 + cl, 0), 95);
  return gy * 96 + gx;
}

// ---------------------------------------------------------------------------
// Unified GEMM (U path, v2): B from pre-transposed bf16 Xt (1 b128 load per
// (ks,nt)); A hi/lo. Y rows packed h4 stores. grid (36 pxg, 7 z, 10 e).
// ---------------------------------------------------------------------------
__global__ __launch_bounds__(256) void uni_gemm_k(
    const unsigned short* __restrict__ Xt_p,
    const unsigned short* __restrict__ Xt_x,
    const unsigned short* __restrict__ awU, unsigned short* __restrict__ Yg,
    unsigned short* __restrict__ Ug) {
  const int pxg = blockIdx.x, z = blockIdx.y, e = blockIdx.z;
  const int tid = threadIdx.x;
  const int lane = tid & 63, wv = tid >> 6;
  const int quad = lane >> 4, n16 = lane & 15;
  const unsigned short* xtx = Xt_x + (size_t)d_esrc[e] * 9216 * 32;
  const int qbase = pxg * 256 + wv * 64;
  int q[4];
#pragma unroll
  for (int nt = 0; nt < 4; ++nt) q[nt] = qbase + nt * 16 + n16;

  f4 acc[4][4] = {};  // [nt][mt]

  for (int ks = 0; ks < 9; ++ks) {
    s8 Ah[4], Al[4];
#pragma unroll
    for (int mt = 0; mt < 4; ++mt) {
      const unsigned short* ap =
          awU + (((size_t)e * 9 + ks) * 28 + z * 4 + mt) * 1024 + lane * 16;
      Ah[mt] = *(const s8*)ap;
      Al[mt] = *(const s8*)(ap + 8);
    }
    s8 B[4];
    if (ks < 8) {
      const int co = ks * 32 + quad * 8;
#pragma unroll
      for (int nt = 0; nt < 4; ++nt)
        B[nt] = *(const s8*)(Xt_p + (size_t)q[nt] * 256 + co);
    } else {
      const int co = quad * 8;
#pragma unroll
      for (int nt = 0; nt < 4; ++nt)
        B[nt] = *(const s8*)(xtx + (size_t)q[nt] * 32 + co);
    }
#pragma unroll
    for (int nt = 0; nt < 4; ++nt)
#pragma unroll
      for (int mt = 0; mt < 4; ++mt) {
        acc[nt][mt] = __builtin_amdgcn_mfma_f32_16x16x32_bf16(Ah[mt], B[nt], acc[nt][mt], 0, 0, 0);
        acc[nt][mt] = __builtin_amdgcn_mfma_f32_16x16x32_bf16(Al[mt], B[nt], acc[nt][mt], 0, 0, 0);
      }
  }
  _Float16* Yh = (_Float16*)Yg;
  _Float16* Uh = (_Float16*)Ug;
#pragma unroll
  for (int nt = 0; nt < 4; ++nt) {
#pragma unroll
    for (int mt = 0; mt < 4; ++mt) {
      int m0 = (z * 4 + mt) * 16 + quad * 4;   // multiple of 4
      if (m0 < 180) {
        int tap = m0 / 20, oc0 = m0 - tap * 20;   // oc0 in {0,4,8,12,16}
        h4 v;
#pragma unroll
        for (int r = 0; r < 4; ++r) v[r] = (_Float16)acc[nt][mt][r];
        *(h4*)(Yh + (((size_t)(e * 9 + tap)) * 9216 + q[nt]) * 20 + oc0) = v;
      } else {
#pragma unroll
        for (int r = 0; r < 4; ++r) {
          int m = m0 + r;
          if (m >= 192 && m < 435)
            Uh[((size_t)e * 243 + (m - 192)) * 9216 + q[nt]] = (_Float16)acc[nt][mt][r];
        }
      }
    }
  }
}

// ---------------------------------------------------------------------------
// Shift-add (U path): o1 = bias + sum_t valid U planes. grid (36, 10).
// ---------------------------------------------------------------------------
__global__ __launch_bounds__(256) void shiftadd_k(
    const unsigned short* __restrict__ Ug, const float* __restrict__ ob,
    float* __restrict__ o1) {
  const int p = blockIdx.x * 256 + threadIdx.x;
  const int e = blockIdx.y;
  const int y = p / 96, x = p % 96;
  const _Float16* Uh = (const _Float16*)Ug;
  float acc[27];
#pragma unroll
  for (int oc = 0; oc < 27; ++oc) acc[oc] = ob[e * 27 + oc];
#pragma unroll
  for (int t = 0; t < 9; ++t) {
    int yy = y + t / 3 - 1, xx = x + t % 3 - 1;
    if (yy >= 0 && yy < 96 && xx >= 0 && xx < 96) {
      int q = yy * 96 + xx;
      const _Float16* up = Uh + ((size_t)e * 243 + t * 27) * 9216 + q;
#pragma unroll
      for (int oc = 0; oc < 27; ++oc)
        acc[oc] += (float)up[oc * 9216];
    }
  }
#pragma unroll
  for (int oc = 0; oc < 27; ++oc) o1[(e * 27 + oc) * 9216 + p] = acc[oc];
}

// ---------------------------------------------------------------------------
// Offset conv 1 via MFMA (fallback path, r9 verbatim). grid (10, 36, 4).
// ---------------------------------------------------------------------------
#define OSWB 35
#define OSEC 384
#define OBUF 896

__global__ __launch_bounds__(256) void offconv1_mfma_k(
    const float* __restrict__ pfea, const float* __restrict__ xp,
    const unsigned short* __restrict__ aw, const float* __restrict__ ob,
    float* __restrict__ o1) {
  __shared__ float sbuf[2][OBUF];
  const int e = blockIdx.x, m = blockIdx.y, z = blockIdx.z;
  const int tid = threadIdx.x;
  const int lane = tid & 63, wv = tid >> 6;
  const int quad = lane >> 4, n16 = lane & 15;
  const int tx0 = (m % 3) * 32, ty0 = (m / 3) * 8;
  const float* xpe = xp + d_esrc[e] * 10 * 9216;
  const int cg_lo = (z * 133) / 4, cg_hi = ((z + 1) * 133) / 4;

  int g[3]; bool oks[3];
#pragma unroll
  for (int i = 0; i < 3; ++i) {
    int s = tid + i * 256;
    int sec = s / OSEC, off = s - sec * OSEC;
    int r = off / OSWB, cl = off % OSWB;
    int gy = ty0 - 1 + r, gx = tx0 - 1 + cl;
    bool ok = (off < 350) && (cl < 34) && (gy >= 0) && (gy < 96) &&
              (gx >= 0) && (gx < 96);
    oks[i] = ok;
    g[i] = sec * 9216 + (ok ? (gy * 96 + gx) : 0);
  }
  if (tid < OBUF - 768) { sbuf[0][768 + tid] = 0.f; sbuf[1][768 + tid] = 0.f; }

  const int tbase = (quad & 1) * 8;
  const int csel = quad >> 1;
  int bdelta[8];
#pragma unroll
  for (int j = 0; j < 8; ++j) {
    int t = tbase + j;
    int dy = t / 3 - 1, dx = t % 3 - 1;
    bdelta[j] = csel * OSEC + dy * OSWB + dx;
  }
  int bidx[4];
#pragma unroll
  for (int nt = 0; nt < 4; ++nt) {
    int r = 2 * wv + (nt >> 1), h = nt & 1;
    bidx[nt] = (r + 1) * OSWB + (h * 16 + n16 + 1);
  }

  f4 acc[4][2] = {};

  int c0 = 2 * cg_lo;
  const float* base = (c0 < 256) ? (pfea + c0 * 9216) : (xpe + (c0 - 256) * 9216);
  float pv0 = oks[0] ? base[g[0]] : 0.f;
  float pv1 = oks[1] ? base[g[1]] : 0.f;
  float pv2 = oks[2] ? base[g[2]] : 0.f;

  int bsel = 0;
  for (int cg = cg_lo; cg < cg_hi; ++cg, bsel ^= 1) {
    float* buf = sbuf[bsel];
    buf[tid] = pv0; buf[tid + 256] = pv1; buf[tid + 512] = pv2;
    if (cg + 1 < cg_hi) {
      int c0n = 2 * (cg + 1);
      const float* nb = (c0n < 256) ? (pfea + c0n * 9216)
                                    : (xpe + (c0n - 256) * 9216);
      pv0 = oks[0] ? nb[g[0]] : 0.f;
      pv1 = oks[1] ? nb[g[1]] : 0.f;
      pv2 = oks[2] ? nb[g[2]] : 0.f;
    }
    const unsigned short* apc = aw + (e * 133 + cg) * 2048 + lane * 16;
    s8 Ah0 = *(const s8*)(apc);
    s8 Al0 = *(const s8*)(apc + 8);
    s8 Ah1 = *(const s8*)(apc + 1024);
    s8 Al1 = *(const s8*)(apc + 1024 + 8);
    __syncthreads();
#pragma unroll
    for (int nt = 0; nt < 4; ++nt) {
      union { s8 v; unsigned short u[8]; } Bh, Bl;
#pragma unroll
      for (int j = 0; j < 8; ++j) {
        float v = buf[bidx[nt] + bdelta[j]];
        unsigned short h = f2bf(v);
        Bh.u[j] = h;
        Bl.u[j] = f2bf(v - bf2f(h));
      }
      acc[nt][0] = __builtin_amdgcn_mfma_f32_16x16x32_bf16(Ah0, Bh.v, acc[nt][0], 0, 0, 0);
      acc[nt][0] = __builtin_amdgcn_mfma_f32_16x16x32_bf16(Ah0, Bl.v, acc[nt][0], 0, 0, 0);
      acc[nt][0] = __builtin_amdgcn_mfma_f32_16x16x32_bf16(Al0, Bh.v, acc[nt][0], 0, 0, 0);
      acc[nt][1] = __builtin_amdgcn_mfma_f32_16x16x32_bf16(Ah1, Bh.v, acc[nt][1], 0, 0, 0);
      acc[nt][1] = __builtin_amdgcn_mfma_f32_16x16x32_bf16(Ah1, Bl.v, acc[nt][1], 0, 0, 0);
      acc[nt][1] = __builtin_amdgcn_mfma_f32_16x16x32_bf16(Al1, Bh.v, acc[nt][1], 0, 0, 0);
    }
  }
#pragma unroll
  for (int nt = 0; nt < 4; ++nt) {
    int y = ty0 + 2 * wv + (nt >> 1);
    int xx = tx0 + (nt & 1) * 16 + n16;
    int p = y * 96 + xx;
#pragma unroll
    for (int t2 = 0; t2 < 2; ++t2)
#pragma unroll
      for (int r = 0; r < 4; ++r) {
        int oc = t2 * 16 + quad * 4 + r;
        if (oc < 27) {
          float v = acc[nt][t2][r];
          if (z == 0) v += ob[e * 27 + oc];
          atomicAdd(&o1[(e * 27 + oc) * 9216 + p], v);
        }
      }
  }
}

// ---------------------------------------------------------------------------
// Y-GEMM (fallback path, r9 verbatim). grid (36 pxg, 4 mgrp, 10 e).
// ---------------------------------------------------------------------------
__global__ __launch_bounds__(256) void ygemm_k(
    const float* __restrict__ pfea, const float* __restrict__ xp,
    const unsigned short* __restrict__ awY, unsigned short* __restrict__ Yg) {
  const int pxg = blockIdx.x, z = blockIdx.y, e = blockIdx.z;
  const int tid = threadIdx.x;
  const int lane = tid & 63, wv = tid >> 6;
  const int quad = lane >> 4, n16 = lane & 15;
  const float* xpe = xp + d_esrc[e] * 10 * 9216;
  const int qbase = pxg * 256 + wv * 64;

  f4 acc[4][3] = {};

  for (int ks = 0; ks < 9; ++ks) {
    const int cq = ks * 32 + quad * 8;
    s8 Ah[3], Al[3];
#pragma unroll
    for (int mt = 0; mt < 3; ++mt) {
      const unsigned short* ap =
          awY + ((e * 9 + ks) * 12 + z * 3 + mt) * 1024 + lane * 16;
      Ah[mt] = *(const s8*)ap;
      Al[mt] = *(const s8*)(ap + 8);
    }
#pragma unroll
    for (int nt = 0; nt < 4; ++nt) {
      const int q = qbase + nt * 16 + n16;
      union { s8 v; unsigned short u[8]; } Bh, Bl;
#pragma unroll
      for (int j = 0; j < 8; ++j) {
        int c = cq + j;
        float v = 0.f;
        if (c < 256) v = pfea[c * 9216 + q];
        else if (c < 266) v = xpe[(c - 256) * 9216 + q];
        unsigned short h = f2bf(v);
        Bh.u[j] = h;
        Bl.u[j] = f2bf(v - bf2f(h));
      }
#pragma unroll
      for (int mt = 0; mt < 3; ++mt) {
        acc[nt][mt] = __builtin_amdgcn_mfma_f32_16x16x32_bf16(Ah[mt], Bh.v, acc[nt][mt], 0, 0, 0);
        acc[nt][mt] = __builtin_amdgcn_mfma_f32_16x16x32_bf16(Ah[mt], Bl.v, acc[nt][mt], 0, 0, 0);
        acc[nt][mt] = __builtin_amdgcn_mfma_f32_16x16x32_bf16(Al[mt], Bh.v, acc[nt][mt], 0, 0, 0);
      }
    }
  }
  _Float16* Yh = (_Float16*)Yg;
#pragma unroll
  for (int nt = 0; nt < 4; ++nt) {
    const int q = qbase + nt * 16 + n16;
#pragma unroll
    for (int mt = 0; mt < 3; ++mt)
#pragma unroll
      for (int r = 0; r < 4; ++r) {
        int m = z * 48 + mt * 16 + quad * 4 + r;
        if (m < 180) {
          int tap = m / 20, oc = m - tap * 20;
          Yh[((e * 9 + tap) * 9216 + q) * 20 + oc] = (_Float16)acc[nt][mt][r];
        }
      }
  }
}

// ---------------------------------------------------------------------------
// Deformable gather (shared): h1a += sum_k bilinear(Y[e][k])(pos_k).
// grid (36 px, 3 tapgrp, 10 e).
// ---------------------------------------------------------------------------
__global__ __launch_bounds__(256) void dfgather_k(
    const float* __restrict__ o1, const unsigned short* __restrict__ Yg,
    float* __restrict__ h1a) {
  const int p = blockIdx.x * 256 + threadIdx.x;
  const int zt = blockIdx.y, e = blockIdx.z;
  const int y = p / 96, x = p % 96;
  float acc[20];
#pragma unroll
  for (int oc = 0; oc < 20; ++oc) acc[oc] = 0.f;

  const _Float16* Yh = (const _Float16*)Yg;
#pragma unroll
  for (int t = 0; t < 3; ++t) {
    const int k = zt * 3 + t;
    float offy = o1[(e * 27 + 2 * k) * 9216 + p];
    float offx = o1[(e * 27 + 2 * k + 1) * 9216 + p];
    float mk = sigm(o1[(e * 27 + 18 + k) * 9216 + p]);
    float py = (float)(y + k / 3 - 1) + offy;
    float px = (float)(x + k % 3 - 1) + offx;
    float fy = floorf(py), fx = floorf(px);
    float wy = py - fy, wx = px - fx;
    int iy = (int)fy, ix = (int)fx;
    const _Float16* yk = Yh + (size_t)(e * 9 + k) * 9216 * 20;
#pragma unroll
    for (int dy = 0; dy < 2; ++dy)
#pragma unroll
      for (int dx = 0; dx < 2; ++dx) {
        bool ok = (iy + dy >= 0) && (iy + dy < 96) && (ix + dx >= 0) && (ix + dx < 96);
        float cwc = (ok ? mk : 0.f) * (dy ? wy : (1.f - wy)) * (dx ? wx : (1.f - wx));
        int yc = min(max(iy + dy, 0), 95), xc = min(max(ix + dx, 0), 95);
        const h4* yp = (const h4*)(yk + (yc * 96 + xc) * 20);
#pragma unroll
        for (int g = 0; g < 5; ++g) {
          h4 v = yp[g];
#pragma unroll
          for (int u = 0; u < 4; ++u)
            acc[g * 4 + u] = fmaf(cwc, (float)v[u], acc[g * 4 + u]);
        }
      }
  }
#pragma unroll
  for (int oc = 0; oc < 20; ++oc)
    atomicAdd(&h1a[(e * 20 + oc) * 9216 + p], acc[oc]);
}

// ---------------------------------------------------------------------------
// Offset conv 2 (shared, r8). grid (10, 36, 2)
// ---------------------------------------------------------------------------
__global__ __launch_bounds__(256) void offconv2_k(
    const float* __restrict__ h1a, const float* __restrict__ wf,
    const float* __restrict__ s1, const float* __restrict__ b1,
    float* __restrict__ o2) {
  __shared__ float sbuf[2][2 * SN];
  const int e = blockIdx.x, m = blockIdx.y;
  const int c_lo = blockIdx.z * 10;
  const int tid = threadIdx.x;
  const int tx = tid % TW, ty = tid / TW;
  const int tx0 = (m % 3) * TW, ty0 = (m / 3) * TH;
  const int y = ty0 + ty, x = tx0 + tx;
  const int p = y * 96 + x;
  const float* base = h1a + e * 20 * 9216;

  const int g0 = stage_goff(tid, ty0, tx0);
  const int g1 = stage_goff(tid + 256, ty0, tx0);
  const int g2 = (tid < SN - 512) ? stage_goff(tid + 512, ty0, tx0) : 0;

  float vmask[9];
#pragma unroll
  for (int t = 0; t < 9; ++t) {
    int yy = y + t / 3 - 1, xx = x + t % 3 - 1;
    vmask[t] = ((yy >= 0) && (yy < 96) && (xx >= 0) && (xx < 96)) ? 1.f : 0.f;
  }
  const int vbase = (ty + 3) * SW + (tx + 3);

  float acc[27];
#pragma unroll
  for (int oc = 0; oc < 27; ++oc) acc[oc] = 0.f;

  const float* ia = base + c_lo * 9216;
  const float* ib = ia + 9216;
  float pa0 = ia[g0], pa1 = ia[g1], pa2 = (tid < SN - 512) ? ia[g2] : 0.f;
  float pb0 = ib[g0], pb1 = ib[g1], pb2 = (tid < SN - 512) ? ib[g2] : 0.f;

  int bsel = 0;
  for (int c = c_lo; c < c_lo + 10; c += 2, bsel ^= 1) {
    float sa = s1[e * 20 + c], ba = b1[e * 20 + c];
    float sb = s1[e * 20 + c + 1], bb2 = b1[e * 20 + c + 1];
    float* buf = sbuf[bsel];
    buf[tid] = fmaxf(fmaf(sa, pa0, ba), 0.f);
    buf[tid + 256] = fmaxf(fmaf(sa, pa1, ba), 0.f);
    if (tid < SN - 512) buf[tid + 512] = fmaxf(fmaf(sa, pa2, ba), 0.f);
    buf[SN + tid] = fmaxf(fmaf(sb, pb0, bb2), 0.f);
    buf[SN + tid + 256] = fmaxf(fmaf(sb, pb1, bb2), 0.f);
    if (tid < SN - 512) buf[SN + tid + 512] = fmaxf(fmaf(sb, pb2, bb2), 0.f);
    if (c + 2 < c_lo + 10) {
      const float* na = base + (c + 2) * 9216;
      const float* nb = base + (c + 3) * 9216;
      pa0 = na[g0]; pa1 = na[g1]; if (tid < SN - 512) pa2 = na[g2];
      pb0 = nb[g0]; pb1 = nb[g1]; if (tid < SN - 512) pb2 = nb[g2];
    }
    __syncthreads();
#pragma unroll
    for (int cc = 0; cc < 2; ++cc) {
      const float* wc = wf + (e * 20 + c + cc) * 243;
      const float* bp = buf + cc * SN;
#pragma unroll
      for (int t = 0; t < 9; ++t) {
        float v = vmask[t] * bp[vbase + (t / 3) * SW + (t % 3)];
#pragma unroll
        for (int oc = 0; oc < 27; ++oc)
          acc[oc] = fmaf(v, wc[t * 27 + oc], acc[oc]);
      }
    }
  }
#pragma unroll
  for (int oc = 0; oc < 27; ++oc)
    atomicAdd(&o2[(e * 27 + oc) * 9216 + p], acc[oc]);
}

// ---------------------------------------------------------------------------
// Deformable main conv 2 (shared, r8). grid (10, 36, 2)
// ---------------------------------------------------------------------------
__global__ __launch_bounds__(256) void dfmain2_k(
    const float* __restrict__ h1a, const float* __restrict__ o2,
    const float* __restrict__ wm, const float* __restrict__ s1,
    const float* __restrict__ b1, float* __restrict__ hout) {
  __shared__ float sbuf[2][2 * SN];
  const int e = blockIdx.x, m = blockIdx.y;
  const int c_lo = blockIdx.z * 10;
  const int tid = threadIdx.x;
  const int tx = tid % TW, ty = tid / TW;
  const int tx0 = (m % 3) * TW, ty0 = (m / 3) * TH;
  const int y = ty0 + ty, x = tx0 + tx;
  const int p = y * 96 + x;
  const float* base = h1a + e * 20 * 9216;

  const int g0 = stage_goff(tid, ty0, tx0);
  const int g1 = stage_goff(tid + 256, ty0, tx0);
  const int g2 = (tid < SN - 512) ? stage_goff(tid + 512, ty0, tx0) : 0;

  int iob[9]; float cw[9][4];
  bool oob = false;
#pragma unroll
  for (int k = 0; k < 9; ++k) {
    float offy = o2[(e * 27 + 2 * k) * 9216 + p];
    float offx = o2[(e * 27 + 2 * k + 1) * 9216 + p];
    float mk = sigm(o2[(e * 27 + 18 + k) * 9216 + p]);
    float py = (float)(y + k / 3 - 1) + offy;
    float px = (float)(x + k % 3 - 1) + offx;
    float fy = floorf(py), fx = floorf(px);
    float wy = py - fy, wx = px - fx;
    int iy = (int)fy, ix = (int)fx;
#pragma unroll
    for (int dy = 0; dy < 2; ++dy)
#pragma unroll
      for (int dx = 0; dx < 2; ++dx) {
        bool ok = (iy + dy >= 0) && (iy + dy < 96) && (ix + dx >= 0) && (ix + dx < 96);
        cw[k][dy * 2 + dx] =
            (ok ? mk : 0.f) * (dy ? wy : (1.f - wy)) * (dx ? wx : (1.f - wx));
      }
    int ir = iy - (ty0 - 4), ic = ix - (tx0 - 4);
    oob |= ((unsigned)ir > (unsigned)(SH - 2)) | ((unsigned)ic > (unsigned)(SDC - 2));
    iob[k] = min(max(ir, 0), SH - 2) * SW + min(max(ic, 0), SDC - 2);
  }

  float acc[10];
#pragma unroll
  for (int oc = 0; oc < 10; ++oc) acc[oc] = 0.f;

  const float* ia = base + c_lo * 9216;
  const float* ib = ia + 9216;
  float pa0 = ia[g0], pa1 = ia[g1], pa2 = (tid < SN - 512) ? ia[g2] : 0.f;
  float pb0 = ib[g0], pb1 = ib[g1], pb2 = (tid < SN - 512) ? ib[g2] : 0.f;

  int bsel = 0;
  for (int c = c_lo; c < c_lo + 10; c += 2, bsel ^= 1) {
    float sa = s1[e * 20 + c], ba = b1[e * 20 + c];
    float sb = s1[e * 20 + c + 1], bb2 = b1[e * 20 + c + 1];
    float* buf = sbuf[bsel];
    buf[tid] = fmaxf(fmaf(sa, pa0, ba), 0.f);
    buf[tid + 256] = fmaxf(fmaf(sa, pa1, ba), 0.f);
    if (tid < SN - 512) buf[tid + 512] = fmaxf(fmaf(sa, pa2, ba), 0.f);
    buf[SN + tid] = fmaxf(fmaf(sb, pb0, bb2), 0.f);
    buf[SN + tid + 256] = fmaxf(fmaf(sb, pb1, bb2), 0.f);
    if (tid < SN - 512) buf[SN + tid + 512] = fmaxf(fmaf(sb, pb2, bb2), 0.f);
    if (c + 2 < c_lo + 10) {
      const float* na = base + (c + 2) * 9216;
      const float* nb = base + (c + 3) * 9216;
      pa0 = na[g0]; pa1 = na[g1]; if (tid < SN - 512) pa2 = na[g2];
      pb0 = nb[g0]; pb1 = nb[g1]; if (tid < SN - 512) pb2 = nb[g2];
    }
    __syncthreads();
#pragma unroll
    for (int cc = 0; cc < 2; ++cc) {
      const float* bp = buf + cc * SN;
#pragma unroll
      for (int k = 0; k < 9; ++k) {
        const float* bk = bp + iob[k];
        float sv = cw[k][0] * bk[0] + cw[k][1] * bk[1] +
                   cw[k][2] * bk[SW] + cw[k][3] * bk[SW + 1];
        const float* wc = wm + ((e * 9 + k) * 20 + c + cc) * 10;
#pragma unroll
        for (int oc = 0; oc < 10; ++oc) acc[oc] = fmaf(sv, wc[oc], acc[oc]);
      }
    }
  }

  if (oob) {
#pragma unroll
    for (int oc = 0; oc < 10; ++oc) acc[oc] = 0.f;
    for (int k = 0; k < 9; ++k) {
      float offy = o2[(e * 27 + 2 * k) * 9216 + p];
      float offx = o2[(e * 27 + 2 * k + 1) * 9216 + p];
      float mk = sigm(o2[(e * 27 + 18 + k) * 9216 + p]);
      float py = (float)(y + k / 3 - 1) + offy;
      float px = (float)(x + k % 3 - 1) + offx;
      float fy = floorf(py), fx = floorf(px);
      float wy = py - fy, wx = px - fx;
      int iy = (int)fy, ix = (int)fx;
      int go[4]; float gw[4];
#pragma unroll
      for (int dy = 0; dy < 2; ++dy)
#pragma unroll
        for (int dx = 0; dx < 2; ++dx) {
          bool ok = (iy + dy >= 0) && (iy + dy < 96) && (ix + dx >= 0) && (ix + dx < 96);
          int yc = min(max(iy + dy, 0), 95), xc = min(max(ix + dx, 0), 95);
          go[dy * 2 + dx] = yc * 96 + xc;
          gw[dy * 2 + dx] =
              (ok ? mk : 0.f) * (dy ? wy : (1.f - wy)) * (dx ? wx : (1.f - wx));
        }
      for (int c = c_lo; c < c_lo + 10; ++c) {
        float sc = s1[e * 20 + c], bc = b1[e * 20 + c];
        const float* ptr = base + c * 9216;
        float v0 = fmaxf(fmaf(sc, ptr[go[0]], bc), 0.f);
        float v1 = fmaxf(fmaf(sc, ptr[go[1]], bc), 0.f);
        float v2 = fmaxf(fmaf(sc, ptr[go[2]], bc), 0.f);
        float v3 = fmaxf(fmaf(sc, ptr[go[3]], bc), 0.f);
        float sv = gw[0] * v0 + gw[1] * v1 + gw[2] * v2 + gw[3] * v3;
        const float* wc = wm + ((e * 9 + k) * 20 + c) * 10;
#pragma unroll
        for (int oc = 0; oc < 10; ++oc) acc[oc] = fmaf(sv, wc[oc], acc[oc]);
      }
    }
  }
#pragma unroll
  for (int oc = 0; oc < 10; ++oc)
    atomicAdd(&hout[(e * 10 + oc) * 9216 + p], acc[oc]);
}

// 1x1 conv p_fea (256ch) -> accfh[j][10][9216], split-K atomic. grid (36,6,4)
__global__ __launch_bounds__(256) void conv_fh_k(
    const float* __restrict__ pfea, const float* __restrict__ wfh,
    float* __restrict__ accfh) {
  const int j = blockIdx.y;
  const int z = blockIdx.z;
  const int p = blockIdx.x * 256 + threadIdx.x;
  const int c_lo = z * 64;
  float acc[10];
#pragma unroll
  for (int c = 0; c < 10; ++c) acc[c] = 0.f;
  for (int ci = c_lo; ci < c_lo + 64; ci += 4) {
    float pv0 = pfea[ci * 9216 + p];
    float pv1 = pfea[(ci + 1) * 9216 + p];
    float pv2 = pfea[(ci + 2) * 9216 + p];
    float pv3 = pfea[(ci + 3) * 9216 + p];
#pragma unroll
    for (int c = 0; c < 10; ++c) {
      acc[c] = fmaf(pv0, wfh[(j * 10 + c) * 256 + ci], acc[c]);
      acc[c] = fmaf(pv1, wfh[(j * 10 + c) * 256 + ci + 1], acc[c]);
      acc[c] = fmaf(pv2, wfh[(j * 10 + c) * 256 + ci + 2], acc[c]);
      acc[c] = fmaf(pv3, wfh[(j * 10 + c) * 256 + ci + 3], acc[c]);
    }
  }
#pragma unroll
  for (int c = 0; c < 10; ++c)
    atomicAdd(&accfh[(j * 10 + c) * 9216 + p], acc[c]);
}

// ---------------------------------------------------------------------------
// Fused node-message + GRU stage; applies h2 affine (s2,b2)+relu inline.
// grid (36, 6)
// ---------------------------------------------------------------------------
__global__ __launch_bounds__(256) void msggru_k(
    const float* __restrict__ xp, const float* __restrict__ xh,
    const float* __restrict__ h2, const float* __restrict__ accfh,
    const float* __restrict__ s2, const float* __restrict__ b2g,
    const float* __restrict__ aw, const float* __restrict__ ab,
    const float* __restrict__ bw, const float* __restrict__ bb,
    const float* __restrict__ w1, const float* __restrict__ s1,
    const float* __restrict__ b1, const float* __restrict__ w2,
    const float* __restrict__ b2, const float* __restrict__ sfh,
    const float* __restrict__ bfh,
    const float* __restrict__ wih1, const float* __restrict__ bih1,
    const float* __restrict__ bhh1, const float* __restrict__ wih2,
    const float* __restrict__ bih2, const float* __restrict__ bhh2,
    float* __restrict__ out_m, float* __restrict__ out_x) {
  const int j = blockIdx.y;
  const int p = blockIdx.x * 256 + threadIdx.x;
  float xj[10];
#pragma unroll
  for (int c = 0; c < 10; ++c) xj[c] = xp[(j * 10 + c) * 9216 + p];
  float xpp[10];
  int ne = d_ne[j];
  for (int ei = 0; ei < ne; ++ei) {
    int e = d_inc[j][ei];
    int a2 = d_esrc[e];
    float sA = ab[e];
#pragma unroll
    for (int c = 0; c < 10; ++c)
      sA = fmaf(xp[(a2 * 10 + c) * 9216 + p], aw[e * 10 + c], sA);
    float sB = bb[e];
#pragma unroll
    for (int c = 0; c < 10; ++c) sB = fmaf(xj[c], bw[e * 10 + c], sB);
    float f = (1.f - sigm(sA)) * sigm(sB);
#pragma unroll
    for (int c = 0; c < 10; ++c) {
      float raw = h2[(e * 10 + c) * 9216 + p];
      float hv = fmaxf(fmaf(s2[e * 10 + c], raw, b2g[e * 10 + c]), 0.f);
      float mm = f * hv;
      xpp[c] = (ei == 0) ? mm : fmaxf(xpp[c], mm);
    }
  }
  const float* hf = xh + ((j < 4) ? 0 : 1) * 10 * 9216;
  float cat[20];
#pragma unroll
  for (int c = 0; c < 10; ++c) cat[c] = hf[c * 9216 + p];
#pragma unroll
  for (int c = 0; c < 10; ++c) cat[10 + c] = xj[c];
  float at = b2[j];
#pragma unroll
  for (int oc = 0; oc < 20; ++oc) {
    float t = 0.f;
#pragma unroll
    for (int c = 0; c < 20; ++c)
      t = fmaf(cat[c], w1[(j * 20 + oc) * 20 + c], t);
    float av = fmaxf(s1[j * 20 + oc] * t + b1[j * 20 + oc], 0.f);
    at = fmaf(av, w2[j * 20 + oc], at);
  }
  at = sigm(at);
  float msg[10];
#pragma unroll
  for (int c = 0; c < 10; ++c) {
    float xhp = fmaxf(sfh[j * 10 + c] * (at * accfh[(j * 10 + c) * 9216 + p]) +
                          bfh[j * 10 + c], 0.f);
    msg[c] = xpp[c] + xhp;
    out_m[(j * 10 + c) * 9216 + p] = msg[c];
  }
  float gi[30];
#pragma unroll
  for (int r = 0; r < 30; ++r) gi[r] = bih1[j * 30 + r];
#pragma unroll
  for (int c = 0; c < 10; ++c) {
    float v = xj[c];
#pragma unroll
    for (int r = 0; r < 30; ++r)
      gi[r] = fmaf(v, wih1[(j * 30 + r) * 20 + c], gi[r]);
  }
#pragma unroll
  for (int c = 0; c < 10; ++c) {
    float v = msg[c];
#pragma unroll
    for (int r = 0; r < 30; ++r)
      gi[r] = fmaf(v, wih1[(j * 30 + r) * 20 + 10 + c], gi[r]);
  }
  float h1v[10];
#pragma unroll
  for (int c = 0; c < 10; ++c) {
    float r = sigm(gi[c] + bhh1[j * 30 + c]);
    float z = sigm(gi[10 + c] + bhh1[j * 30 + 10 + c]);
    float n = tanhf(gi[20 + c] + r * bhh1[j * 30 + 20 + c]);
    h1v[c] = (1.f - z) * n;
  }
  float g2v[30];
#pragma unroll
  for (int r = 0; r < 30; ++r) g2v[r] = bih2[j * 30 + r];
#pragma unroll
  for (int c = 0; c < 10; ++c) {
    float v = h1v[c];
#pragma unroll
    for (int r = 0; r < 30; ++r)
      g2v[r] = fmaf(v, wih2[(j * 30 + r) * 10 + c], g2v[r]);
  }
#pragma unroll
  for (int c = 0; c < 10; ++c) {
    float r = sigm(g2v[c] + bhh2[j * 30 + c]);
    float z = sigm(g2v[10 + c] + bhh2[j * 30 + 10 + c]);
    float n = tanhf(g2v[20 + c] + r * bhh2[j * 30 + 20 + c]);
    out_x[(j * 10 + c) * 9216 + p] = (1.f - z) * n;
  }
}

extern "C" void kernel_launch(void* const* d_in, const int* in_sizes, int n_in,
                              void* d_out, int out_size, void* d_ws, size_t ws_size,
                              hipStream_t stream) {
  const float* pfea   = (const float*)d_in[0];
  const float* xp     = (const float*)d_in[1];
  const float* xh     = (const float*)d_in[2];
  const float* dp_ow1 = (const float*)d_in[3];
  const float* dp_ob1 = (const float*)d_in[4];
  const float* dp_w1  = (const float*)d_in[5];
  const float* dp_s1  = (const float*)d_in[6];
  const float* dp_b1  = (const float*)d_in[7];
  const float* dp_ow2 = (const float*)d_in[8];
  const float* dp_ob2 = (const float*)d_in[9];
  const float* dp_w2  = (const float*)d_in[10];
  const float* dp_s2  = (const float*)d_in[11];
  const float* dp_b2  = (const float*)d_in[12];
  const float* dp_aw  = (const float*)d_in[13];
  const float* dp_ab  = (const float*)d_in[14];
  const float* dp_bw  = (const float*)d_in[15];
  const float* dp_bb  = (const float*)d_in[16];
  const float* dc_w1  = (const float*)d_in[17];
  const float* dc_s1  = (const float*)d_in[18];
  const float* dc_b1  = (const float*)d_in[19];
  const float* dc_w2  = (const float*)d_in[20];
  const float* dc_b2  = (const float*)d_in[21];
  const float* dc_wfh = (const float*)d_in[22];
  const float* dc_sfh = (const float*)d_in[23];
  const float* dc_bfh = (const float*)d_in[24];
  const float* g_wih1 = (const float*)d_in[25];
  const float* g_bih1 = (const float*)d_in[26];
  const float* g_bhh1 = (const float*)d_in[28];
  const float* g_wih2 = (const float*)d_in[29];
  const float* g_bih2 = (const float*)d_in[30];
  const float* g_bhh2 = (const float*)d_in[32];

  float* ws = (float*)d_ws;
  const bool use_u = ws_size >= 26654760ull * sizeof(float);

  unsigned short *aw1, *awY = nullptr, *awU = nullptr, *Yg, *Ug = nullptr;
  unsigned short *Xt_p = nullptr, *Xt_x = nullptr;
  float *accfh, *h2, *wf2, *wm2, *o1, *o2, *h1a;

  if (use_u) {
    aw1   = (unsigned short*)ws;               // unused in U path
    accfh = ws;
    h2    = ws + 552960;
    awU   = (unsigned short*)(ws + 1474560);   // 2,580,480 ushort
    wf2   = ws + 1474560 + 1290240;
    wm2   = wf2 + 48600;
    o1    = wm2 + 18000;                        // 2,488,320 (o2 alias)
    o2    = o1;
    // Xt aliases o1 during phase 1 (dead before shiftadd writes o1):
    //   Xt_p 2,359,296 ushort + Xt_x 1,769,472 ushort = 2,064,384 f <= o1
    Xt_p  = (unsigned short*)o1;
    Xt_x  = Xt_p + 2359296;
    h1a   = o1 + 2488320;                       // 1,843,200
    Yg    = (unsigned short*)(h1a + 1843200);   // 16,588,800 ushort
    Ug    = (unsigned short*)(h1a + 1843200 + 8294400);  // 22,394,880 ushort
    // total: 26,654,760 floats = 106.6 MB (same as r10)
  } else {
    aw1   = (unsigned short*)ws;
    awY   = (unsigned short*)(ws + 1361920);
    accfh = ws;
    h2    = ws + 552960;
    wf2   = ws + 1914880;
    wm2   = wf2 + 48600;
    o1    = wm2 + 18000;
    o2    = o1;
    h1a   = o1 + 2488320;
    Yg    = (unsigned short*)(ws + 6313000);
  }

  float* out_x = (float*)d_out;        // xp_out: 6*10*9216
  float* out_m = out_x + 552960;       // msgs:   6*10*9216

  dim3 blk(256);
  prep_all_k<<<dim3(1826), blk, 0, stream>>>(dp_ow2, wf2, dp_w2, wm2,
                                             dp_ow1, aw1, dp_w1, awY ? awY : aw1,
                                             awU ? awU : aw1, use_u ? 1 : 0);

  if (use_u) {
    xt_k<<<dim3(36, 14), blk, 0, stream>>>(pfea, xp, Xt_p, Xt_x);
    hipMemsetAsync(h1a, 0, 1843200 * sizeof(float), stream);
    uni_gemm_k<<<dim3(36, 7, 10), blk, 0, stream>>>(Xt_p, Xt_x, awU, Yg, Ug);
    shiftadd_k<<<dim3(36, 10), blk, 0, stream>>>(Ug, dp_ob1, o1);
    dfgather_k<<<dim3(36, 3, 10), blk, 0, stream>>>(o1, Yg, h1a);
  } else {
    hipMemsetAsync(o1, 0, (2488320 + 1843200) * sizeof(float), stream);
    offconv1_mfma_k<<<dim3(10, 36, 4), blk, 0, stream>>>(pfea, xp, aw1, dp_ob1, o1);
    ygemm_k<<<dim3(36, 4, 10), blk, 0, stream>>>(pfea, xp, awY, Yg);
    dfgather_k<<<dim3(36, 3, 10), blk, 0, stream>>>(o1, Yg, h1a);
  }

  init2_k<<<dim3(13320), blk, 0, stream>>>(dp_ob2, o2, h2);
  offconv2_k<<<dim3(10, 36, 2), blk, 0, stream>>>(h1a, wf2, dp_s1, dp_b1, o2);
  dfmain2_k<<<dim3(10, 36, 2), blk, 0, stream>>>(h1a, o2, wm2, dp_s1, dp_b1, h2);

  hipMemsetAsync(accfh, 0, 552960 * sizeof(float), stream);
  conv_fh_k<<<dim3(36, 6, 4), blk, 0, stream>>>(pfea, dc_wfh, accfh);

  msggru_k<<<dim3(36, 6), blk, 0, stream>>>(
      xp, xh, h2, accfh, dp_s2, dp_b2, dp_aw, dp_ab, dp_bw, dp_bb,
      dc_w1, dc_s1, dc_b1, dc_w2, dc_b2, dc_sfh, dc_bfh,
      g_wih1, g_bih1, g_bhh1, g_wih2, g_bih2, g_bhh2, out_m, out_x);
}